// Round 1
// baseline (1032.762 us; speedup 1.0000x reference)
//
#include <hip/hip_runtime.h>
#include <hip/hip_bf16.h>

constexpr int B = 512, N = 64, E = 512, NE = B * E;

// ---------------- degree / dinv ----------------
__global__ __launch_bounds__(256) void deg_kernel(const int* __restrict__ edges,
                                                  float* __restrict__ dinv) {
  __shared__ int cnt[N];
  int g = blockIdx.x, t = threadIdx.x;
  if (t < N) cnt[t] = 1;  // self loop
  __syncthreads();
  const int* dst = edges + NE + (size_t)g * E;
  for (int j = t; j < E; j += 256) atomicAdd(&cnt[dst[j] & (N - 1)], 1);
  __syncthreads();
  if (t < N) dinv[g * N + t] = rsqrtf((float)cnt[t]);
}

// ---------------- fused GCN layer (matmul + normalized scatter) ----------------
template <int DIN, int DOUT, bool RELU_IN>
__global__ __launch_bounds__(256) void gcn_kernel(
    const float* __restrict__ x, const float* __restrict__ W,
    const float* __restrict__ bias, const int* __restrict__ edges,
    const float* __restrict__ dinv, float* __restrict__ out) {
  __shared__ float Xs[N * DIN];
  __shared__ float Hs[N * DOUT];
  __shared__ float acc[N * DOUT];
  __shared__ float Wls[DIN * DOUT];
  __shared__ float dl[N];
  __shared__ int es[E];
  __shared__ int ed[E];
  __shared__ float ec[E];
  int g = blockIdx.x, t = threadIdx.x;
  for (int i = t; i < N * DIN; i += 256) {
    float v = x[(size_t)g * N * DIN + i];
    Xs[i] = RELU_IN ? fmaxf(v, 0.f) : v;
  }
  for (int i = t; i < DIN * DOUT; i += 256) Wls[i] = W[i];
  if (t < N) dl[t] = dinv[g * N + t];
  __syncthreads();
  // H = X @ W ; acc = H * dinv^2 + bias (self term)
  for (int i = t; i < N * DOUT; i += 256) {
    int n = i / DOUT, oc = i % DOUT;
    float s = 0.f;
#pragma unroll
    for (int k = 0; k < DIN; ++k) s += Xs[n * DIN + k] * Wls[k * DOUT + oc];
    Hs[i] = s;
    acc[i] = s * dl[n] * dl[n] + bias[oc];
  }
  const int* srcp = edges + (size_t)g * E;
  const int* dstp = edges + NE + (size_t)g * E;
  for (int j = t; j < E; j += 256) {
    int s = srcp[j] & (N - 1), d = dstp[j] & (N - 1);
    es[j] = s;
    ed[j] = d;
    ec[j] = dl[s] * dl[d];
  }
  __syncthreads();
  for (int wk = t; wk < E * DOUT; wk += 256) {
    int e = wk / DOUT, c = wk % DOUT;
    atomicAdd(&acc[ed[e] * DOUT + c], Hs[es[e] * DOUT + c] * ec[e]);
  }
  __syncthreads();
  for (int i = t; i < N * DOUT; i += 256) out[(size_t)g * N * DOUT + i] = acc[i];
}

// ---------------- per-graph similarity: sim[b,n,m] = q[b,n,:].c[b,m,:] ----------------
template <int D>
__global__ __launch_bounds__(256) void sim_kernel(const float* __restrict__ fq,
                                                  const float* __restrict__ fc,
                                                  float* __restrict__ so) {
  constexpr int DP = D + 1;  // odd stride -> conflict-free
  __shared__ float Qs[N * DP];
  __shared__ float Cs[N * DP];
  int b = blockIdx.x, t = threadIdx.x;
  for (int i = t; i < N * D; i += 256) {
    int n = i / D, k = i % D;
    Qs[n * DP + k] = fq[(size_t)b * N * D + i];
    Cs[n * DP + k] = fc[(size_t)b * N * D + i];
  }
  __syncthreads();
  for (int i = t; i < N * N; i += 256) {
    int n = i >> 6, mm = i & 63;
    float s = 0.f;
#pragma unroll
    for (int k = 0; k < D; ++k) s += Qs[n * DP + k] * Cs[mm * DP + k];
    so[(size_t)b * N * N + i] = s;
  }
}

// ---------------- fused conv5x5(SAME) + ReLU + maxpool2 ----------------
// grid (B, 3, COUT/COC); block handles one (b,m, oc-block)
template <int CIN, int COUT, int COC, int OCC, int S>
__global__ __launch_bounds__(256) void conv_kernel(
    const float* __restrict__ in, const float* __restrict__ w,
    const float* __restrict__ bias, float* __restrict__ out,
    int ib, int im, int ob, int om) {
  constexpr int PS = S + 4, HP = S / 2, POS = HP * HP;
  constexpr int CHUNKS = COC / OCC;
  constexpr int ITEMS = CHUNKS * POS;
  constexpr int ITER = ITEMS / 256;
  __shared__ float ins[CIN * PS * PS];
  __shared__ float wls[COC * CIN * 25];
  __shared__ float bls[COC];
  int b = blockIdx.x, m = blockIdx.y, t = threadIdx.x;
  int ocb = blockIdx.z * COC;
  for (int i = t; i < CIN * PS * PS; i += 256) ins[i] = 0.f;
  for (int i = t; i < COC * CIN * 25; i += 256)
    wls[i] = w[((size_t)m * COUT + ocb) * CIN * 25 + i];
  if (t < COC) bls[t] = bias[m * COUT + ocb + t];
  __syncthreads();
  const float* ip = in + (size_t)b * ib + (size_t)m * im;
  for (int i = t; i < CIN * S * S; i += 256) {
    int ci = i / (S * S), r = i % (S * S), y = r / S, xx = r % S;
    ins[ci * PS * PS + (y + 2) * PS + (xx + 2)] = ip[i];
  }
  __syncthreads();
  for (int it = 0; it < ITER; ++it) {
    int idx = t + it * 256;
    int pos = idx % POS;
    int chunk = idx / POS;
    int py = pos / HP, px = pos % HP;
    float acc[OCC][4];
#pragma unroll
    for (int o = 0; o < OCC; ++o) {
      float bv = bls[chunk * OCC + o];
      acc[o][0] = bv; acc[o][1] = bv; acc[o][2] = bv; acc[o][3] = bv;
    }
#pragma unroll 1
    for (int ci = 0; ci < CIN; ++ci) {
      float reg[6][6];
      const float* rp = &ins[ci * PS * PS + (2 * py) * PS + 2 * px];
#pragma unroll
      for (int yy = 0; yy < 6; ++yy)
#pragma unroll
        for (int xx = 0; xx < 6; ++xx) reg[yy][xx] = rp[yy * PS + xx];
#pragma unroll
      for (int o = 0; o < OCC; ++o) {
        const float* wp = &wls[((chunk * OCC + o) * CIN + ci) * 25];
#pragma unroll
        for (int ky = 0; ky < 5; ++ky)
#pragma unroll
          for (int kx = 0; kx < 5; ++kx) {
            float wv = wp[ky * 5 + kx];
            acc[o][0] += reg[ky][kx] * wv;
            acc[o][1] += reg[ky][kx + 1] * wv;
            acc[o][2] += reg[ky + 1][kx] * wv;
            acc[o][3] += reg[ky + 1][kx + 1] * wv;
          }
      }
    }
#pragma unroll
    for (int o = 0; o < OCC; ++o) {
      float v = fmaxf(fmaxf(fmaxf(acc[o][0], acc[o][1]),
                            fmaxf(acc[o][2], acc[o][3])), 0.f);
      out[(size_t)b * ob + (size_t)m * om +
          (size_t)(ocb + chunk * OCC + o) * POS + pos] = v;
    }
  }
}

// ---------------- MLP ----------------
__global__ void init_h1(const float* __restrict__ bias, float* __restrict__ h1) {
  int i = blockIdx.x * 256 + threadIdx.x;
  h1[i] = bias[i & 255];
}

__global__ __launch_bounds__(256) void lin1_kernel(const float* __restrict__ feat,
                                                   const float* __restrict__ W,
                                                   float* __restrict__ h1) {
  constexpr int RB = 32, KC = 384;
  __shared__ float fs[RB * KC];
  int rb = blockIdx.x, ks = blockIdx.y, t = threadIdx.x;
  for (int i = t; i < RB * KC; i += 256) {
    int r = i / KC, k = i % KC;
    fs[i] = feat[(size_t)(rb * RB + r) * 6144 + ks * KC + k];
  }
  __syncthreads();
  float accv[RB];
#pragma unroll
  for (int r = 0; r < RB; ++r) accv[r] = 0.f;
#pragma unroll 4
  for (int k = 0; k < KC; ++k) {
    float wv = W[(size_t)(ks * KC + k) * 256 + t];
#pragma unroll
    for (int r = 0; r < RB; ++r) accv[r] += fs[r * KC + k] * wv;
  }
  for (int r = 0; r < RB; ++r)
    atomicAdd(&h1[(size_t)(rb * RB + r) * 256 + t], accv[r]);
}

__global__ __launch_bounds__(256) void head_kernel(
    const float* __restrict__ h1, const float* __restrict__ w2,
    const float* __restrict__ b2, const float* __restrict__ sw,
    const float* __restrict__ sb, float* __restrict__ out) {
  int b = blockIdx.x * 256 + threadIdx.x;
  float h2[16];
#pragma unroll
  for (int j = 0; j < 16; ++j) h2[j] = b2[j];
#pragma unroll 1
  for (int k = 0; k < 256; ++k) {
    float v = fmaxf(h1[(size_t)b * 256 + k], 0.f);  // relu folded here
#pragma unroll
    for (int j = 0; j < 16; ++j) h2[j] += v * w2[k * 16 + j];
  }
  float s = sb[0];
#pragma unroll
  for (int j = 0; j < 16; ++j) s += fmaxf(h2[j], 0.f) * sw[j];
  out[b] = s;
}

// ---------------- launcher ----------------
extern "C" void kernel_launch(void* const* d_in, const int* in_sizes, int n_in,
                              void* d_out, int out_size, void* d_ws, size_t ws_size,
                              hipStream_t stream) {
  const float* x_q = (const float*)d_in[0];
  const float* x_c = (const float*)d_in[1];
  const int* edge_q = (const int*)d_in[2];
  const int* edge_c = (const int*)d_in[3];
  const float* gw1 = (const float*)d_in[4];
  const float* gb1 = (const float*)d_in[5];
  const float* gw2 = (const float*)d_in[6];
  const float* gb2 = (const float*)d_in[7];
  const float* gw3 = (const float*)d_in[8];
  const float* gb3 = (const float*)d_in[9];
  const float* cw1 = (const float*)d_in[10];
  const float* cb1 = (const float*)d_in[11];
  const float* cw2 = (const float*)d_in[12];
  const float* cb2 = (const float*)d_in[13];
  const float* cw3 = (const float*)d_in[14];
  const float* cb3 = (const float*)d_in[15];
  const float* lw1 = (const float*)d_in[16];
  const float* lb1 = (const float*)d_in[17];
  const float* lw2 = (const float*)d_in[18];
  const float* lb2 = (const float*)d_in[19];
  const float* swt = (const float*)d_in[20];
  const float* sbs = (const float*)d_in[21];
  float* ws = (float*)d_ws;

  // workspace layout (floats), with reuse
  const size_t o_dinvq = 0;
  const size_t o_dinvc = 32768;
  const size_t o_f1q = 65536;                 // 2097152
  const size_t o_f2q = o_f1q + 2097152;       // 1048576
  const size_t o_f3q = o_f2q + 1048576;       // 524288
  const size_t o_f1c = o_f3q + 524288;
  const size_t o_f2c = o_f1c + 2097152;
  const size_t o_f3c = o_f2c + 1048576;
  const size_t o_sims = o_f3c + 524288;       // 3*512*4096 = 6291456
  const size_t o_pm1 = o_sims + 6291456;      // 3*512*8*1024 = 12582912
  const size_t o_pm2 = o_sims;                // reuse (sims dead after conv1)
  const size_t o_feat = o_pm1;                // reuse (pm1 dead after conv2)
  const size_t o_h1 = o_f1q;                  // reuse (f1q dead after sims)

  float* dinvq = ws + o_dinvq;
  float* dinvc = ws + o_dinvc;
  float* f1q = ws + o_f1q; float* f2q = ws + o_f2q; float* f3q = ws + o_f3q;
  float* f1c = ws + o_f1c; float* f2c = ws + o_f2c; float* f3c = ws + o_f3c;
  float* sims = ws + o_sims;
  float* pm1 = ws + o_pm1;
  float* pm2 = ws + o_pm2;
  float* feat = ws + o_feat;
  float* h1 = ws + o_h1;

  deg_kernel<<<B, 256, 0, stream>>>(edge_q, dinvq);
  deg_kernel<<<B, 256, 0, stream>>>(edge_c, dinvc);

  gcn_kernel<16, 64, false><<<B, 256, 0, stream>>>(x_q, gw1, gb1, edge_q, dinvq, f1q);
  gcn_kernel<64, 32, true><<<B, 256, 0, stream>>>(f1q, gw2, gb2, edge_q, dinvq, f2q);
  gcn_kernel<32, 16, true><<<B, 256, 0, stream>>>(f2q, gw3, gb3, edge_q, dinvq, f3q);
  gcn_kernel<16, 64, false><<<B, 256, 0, stream>>>(x_c, gw1, gb1, edge_c, dinvc, f1c);
  gcn_kernel<64, 32, true><<<B, 256, 0, stream>>>(f1c, gw2, gb2, edge_c, dinvc, f2c);
  gcn_kernel<32, 16, true><<<B, 256, 0, stream>>>(f2c, gw3, gb3, edge_c, dinvc, f3c);

  sim_kernel<64><<<B, 256, 0, stream>>>(f1q, f1c, sims + 0 * (size_t)B * 4096);
  sim_kernel<32><<<B, 256, 0, stream>>>(f2q, f2c, sims + 1 * (size_t)B * 4096);
  sim_kernel<16><<<B, 256, 0, stream>>>(f3q, f3c, sims + 2 * (size_t)B * 4096);

  // conv1: [B,1,64,64] -> pooled [B,8,32,32]
  conv_kernel<1, 8, 8, 8, 64><<<dim3(B, 3, 1), 256, 0, stream>>>(
      sims, cw1, cb1, pm1, 4096, 2097152, 8192, 4194304);
  // conv2: [B,8,32,32] -> pooled [B,16,16,16]
  conv_kernel<8, 16, 16, 16, 32><<<dim3(B, 3, 1), 256, 0, stream>>>(
      pm1, cw2, cb2, pm2, 8192, 4194304, 4096, 2097152);
  // conv3: [B,16,16,16] -> pooled [B,32,8,8] written into feat[B,6144]
  conv_kernel<16, 32, 16, 4, 16><<<dim3(B, 3, 2), 256, 0, stream>>>(
      pm2, cw3, cb3, feat, 4096, 2097152, 6144, 2048);

  init_h1<<<512, 256, 0, stream>>>(lb1, h1);
  lin1_kernel<<<dim3(16, 16), 256, 0, stream>>>(feat, lw1, h1);
  head_kernel<<<2, 256, 0, stream>>>(h1, lw2, lb2, swt, sbs, (float*)d_out);
}

// Round 2
// 472.826 us; speedup vs baseline: 2.1842x; 2.1842x over previous
//
#include <hip/hip_runtime.h>
#include <hip/hip_bf16.h>

constexpr int B = 512, N = 64, E = 512, NE = B * E;

// =================== fused GCN layer: dense-A in LDS + 2 tiled matmuls ===================
// grid (B, 2): y=0 -> query graphs, y=1 -> corpus graphs
template <int DIN, int DOUT, bool RELU_IN, bool FIRST>
__global__ __launch_bounds__(256) void gcn_kernel(
    const float* __restrict__ xq, const float* __restrict__ xc,
    const float* __restrict__ Wg, const float* __restrict__ bias,
    const int* __restrict__ eq, const int* __restrict__ ec,
    float* __restrict__ dinvq, float* __restrict__ dinvc,
    float* __restrict__ outq, float* __restrict__ outc) {
  constexpr int XS = 68;  // padded row stride (16B-aligned, bank-spread)
  __shared__ __align__(16) float Xt[DIN * XS];   // X transposed [k][n]
  __shared__ __align__(16) float Wls[DIN * DOUT];
  __shared__ __align__(16) float Hs[N * XS];     // H = X@W, [n][c]
  __shared__ __align__(16) float At[N * XS];     // A^T [s][d]
  __shared__ float dl[N];
  __shared__ int cnt[N];
  const int g = blockIdx.x, t = threadIdx.x;
  const float* x = blockIdx.y ? xc : xq;
  const int* edges = blockIdx.y ? ec : eq;
  float* dinv = blockIdx.y ? dinvc : dinvq;
  float* out = blockIdx.y ? outc : outq;

  for (int i = t; i < N * DIN; i += 256) {
    int n = i / DIN, k = i % DIN;
    float v = x[(size_t)g * N * DIN + i];
    if (RELU_IN) v = fmaxf(v, 0.f);
    Xt[k * XS + n] = v;
  }
  for (int i = t; i < DIN * DOUT; i += 256) Wls[i] = Wg[i];
  for (int i = t; i < N * XS; i += 256) At[i] = 0.f;
  if (FIRST && t < N) cnt[t] = 1;  // self loop
  __syncthreads();
  const int* srcp = edges + (size_t)g * E;
  const int* dstp = edges + NE + (size_t)g * E;
  if (FIRST) {
    for (int j = t; j < E; j += 256) atomicAdd(&cnt[dstp[j] & (N - 1)], 1);
    __syncthreads();
    if (t < N) {
      float dv = rsqrtf((float)cnt[t]);
      dl[t] = dv;
      dinv[g * N + t] = dv;
    }
  } else {
    if (t < N) dl[t] = dinv[g * N + t];
  }
  __syncthreads();

  constexpr int CT = DOUT / 4;
  const int ct = t % CT, nt = t / CT;
  // matmul1: Hs[n][c] = sum_k Xt[k][n] * Wls[k][c]
  if (nt < 16) {
    float acc[4][4];
#pragma unroll
    for (int i = 0; i < 4; ++i)
#pragma unroll
      for (int j = 0; j < 4; ++j) acc[i][j] = 0.f;
#pragma unroll 4
    for (int k = 0; k < DIN; ++k) {
      float4 xv = *(const float4*)&Xt[k * XS + 4 * nt];
      float4 wv = *(const float4*)&Wls[k * DOUT + 4 * ct];
      float xa[4] = {xv.x, xv.y, xv.z, xv.w};
      float wa[4] = {wv.x, wv.y, wv.z, wv.w};
#pragma unroll
      for (int i = 0; i < 4; ++i)
#pragma unroll
        for (int j = 0; j < 4; ++j) acc[i][j] += xa[i] * wa[j];
    }
#pragma unroll
    for (int i = 0; i < 4; ++i) {
      float4 st = {acc[i][0], acc[i][1], acc[i][2], acc[i][3]};
      *(float4*)&Hs[(4 * nt + i) * XS + 4 * ct] = st;
    }
  }
  // build A^T: At[s][d] += dinv_s*dinv_d per edge; diagonal dinv_n^2
  for (int j = t; j < E; j += 256) {
    int s = srcp[j] & (N - 1), d = dstp[j] & (N - 1);
    atomicAdd(&At[s * XS + d], dl[s] * dl[d]);
  }
  if (t < N) atomicAdd(&At[t * XS + t], dl[t] * dl[t]);
  __syncthreads();
  // matmul2: out[n][c] = sum_s At[s][n] * Hs[s][c] + bias[c]
  if (nt < 16) {
    float acc[4][4];
#pragma unroll
    for (int i = 0; i < 4; ++i)
#pragma unroll
      for (int j = 0; j < 4; ++j) acc[i][j] = 0.f;
#pragma unroll 4
    for (int s = 0; s < N; ++s) {
      float4 av = *(const float4*)&At[s * XS + 4 * nt];
      float4 hv = *(const float4*)&Hs[s * XS + 4 * ct];
      float aa[4] = {av.x, av.y, av.z, av.w};
      float ha[4] = {hv.x, hv.y, hv.z, hv.w};
#pragma unroll
      for (int i = 0; i < 4; ++i)
#pragma unroll
        for (int j = 0; j < 4; ++j) acc[i][j] += aa[i] * ha[j];
    }
#pragma unroll
    for (int i = 0; i < 4; ++i) {
      float4 st = {acc[i][0] + bias[4 * ct + 0], acc[i][1] + bias[4 * ct + 1],
                   acc[i][2] + bias[4 * ct + 2], acc[i][3] + bias[4 * ct + 3]};
      *(float4*)&out[(size_t)g * N * DOUT + (size_t)(4 * nt + i) * DOUT + 4 * ct] = st;
    }
  }
}

// =================== similarity: sim[b,n,m] = q_n . c_m, 4x4 register tile ===================
template <int D>
__global__ __launch_bounds__(256) void sim_kernel(const float* __restrict__ fq,
                                                  const float* __restrict__ fc,
                                                  float* __restrict__ so) {
  constexpr int XS = 68;
  __shared__ __align__(16) float Qt[D * XS];
  __shared__ __align__(16) float Ct[D * XS];
  const int b = blockIdx.x, t = threadIdx.x;
  for (int i = t; i < N * D; i += 256) {
    int n = i / D, k = i % D;
    Qt[k * XS + n] = fq[(size_t)b * N * D + i];
    Ct[k * XS + n] = fc[(size_t)b * N * D + i];
  }
  __syncthreads();
  const int ct = t % 16, nt = t / 16;
  float acc[4][4];
#pragma unroll
  for (int i = 0; i < 4; ++i)
#pragma unroll
    for (int j = 0; j < 4; ++j) acc[i][j] = 0.f;
#pragma unroll 4
  for (int k = 0; k < D; ++k) {
    float4 qv = *(const float4*)&Qt[k * XS + 4 * nt];
    float4 cv = *(const float4*)&Ct[k * XS + 4 * ct];
    float qa[4] = {qv.x, qv.y, qv.z, qv.w};
    float ca[4] = {cv.x, cv.y, cv.z, cv.w};
#pragma unroll
    for (int i = 0; i < 4; ++i)
#pragma unroll
      for (int j = 0; j < 4; ++j) acc[i][j] += qa[i] * ca[j];
  }
#pragma unroll
  for (int i = 0; i < 4; ++i) {
    float4 st = {acc[i][0], acc[i][1], acc[i][2], acc[i][3]};
    *(float4*)&so[(size_t)b * 4096 + (size_t)(4 * nt + i) * 64 + 4 * ct] = st;
  }
}

// =================== conv1: CIN=1, 64x64, 8 oc sequential, immediate pooling ===================
__global__ __launch_bounds__(256) void conv1_kernel(const float* __restrict__ in,
                                                    const float* __restrict__ w,
                                                    const float* __restrict__ bias,
                                                    float* __restrict__ out) {
  constexpr int S = 64, PS = 68, PSPS = PS * PS, P = 32;
  __shared__ __align__(16) float ins[PSPS];
  __shared__ float wls[8 * 25];
  __shared__ float bls[8];
  const int b = blockIdx.x, m = blockIdx.y, t = threadIdx.x;
  for (int i = t; i < PSPS; i += 256) ins[i] = 0.f;
  if (t < 200) wls[t] = w[m * 200 + t];
  if (t < 8) bls[t] = bias[m * 8 + t];
  __syncthreads();
  const float* ip = in + (size_t)b * 4096 + (size_t)m * 2097152;
  for (int i = t; i < S * S; i += 256) {
    int y = i >> 6, xx = i & 63;
    ins[(y + 2) * PS + xx + 2] = ip[i];
  }
  __syncthreads();
  const int gy = t >> 4, gx = t & 15;
  float pr[8][8];
#pragma unroll
  for (int yy = 0; yy < 8; ++yy) {
    float4 a = *(const float4*)&ins[(4 * gy + yy) * PS + 4 * gx];
    float4 bb = *(const float4*)&ins[(4 * gy + yy) * PS + 4 * gx + 4];
    pr[yy][0] = a.x; pr[yy][1] = a.y; pr[yy][2] = a.z; pr[yy][3] = a.w;
    pr[yy][4] = bb.x; pr[yy][5] = bb.y; pr[yy][6] = bb.z; pr[yy][7] = bb.w;
  }
  float* op = out + (size_t)b * 8192 + (size_t)m * 4194304;
#pragma unroll 1
  for (int oc = 0; oc < 8; ++oc) {
    float acc[16];
#pragma unroll
    for (int p = 0; p < 16; ++p) acc[p] = 0.f;
#pragma unroll
    for (int ky = 0; ky < 5; ++ky)
#pragma unroll
      for (int kx = 0; kx < 5; ++kx) {
        float wv = wls[oc * 25 + ky * 5 + kx];
#pragma unroll
        for (int dy = 0; dy < 4; ++dy)
#pragma unroll
          for (int dx = 0; dx < 4; ++dx) acc[dy * 4 + dx] += pr[ky + dy][kx + dx] * wv;
      }
    float bv = bls[oc];
#pragma unroll
    for (int ay = 0; ay < 2; ++ay)
#pragma unroll
      for (int ax = 0; ax < 2; ++ax) {
        float v = fmaxf(fmaxf(acc[(2 * ay) * 4 + 2 * ax], acc[(2 * ay) * 4 + 2 * ax + 1]),
                        fmaxf(acc[(2 * ay + 1) * 4 + 2 * ax], acc[(2 * ay + 1) * 4 + 2 * ax + 1]));
        v = fmaxf(v + bv, 0.f);
        op[(size_t)oc * 1024 + (size_t)(2 * gy + ay) * 32 + (2 * gx + ax)] = v;
      }
  }
}

// =================== generic conv (conv2/conv3): 2x2 pooled x OCG ocs per thread ===================
template <int CIN, int CICH, int COCB, int OCG, int S, int COUT>
__global__ __launch_bounds__(256) void conv_kernel(
    const float* __restrict__ in, const float* __restrict__ w,
    const float* __restrict__ bias, float* __restrict__ out,
    int ib, size_t im, int ob, size_t om) {
  constexpr int PS = S + 4, PSPS = PS * PS, P = S / 2, PGW = P / 2;
  constexpr int PG = PGW * PGW, GROUPS = COCB / OCG, NC = CIN / CICH;
  static_assert(PG * GROUPS == 256, "thread mapping");
  __shared__ __align__(16) float ins[CICH * PSPS];
  __shared__ __align__(16) float wls[CIN * 25 * COCB];  // [ci][k][oc]
  __shared__ float bls[COCB];
  const int b = blockIdx.x, m = blockIdx.y, ocb = blockIdx.z * COCB;
  const int t = threadIdx.x;
  for (int i = t; i < CICH * PSPS; i += 256) ins[i] = 0.f;
  for (int i = t; i < CIN * 25 * COCB; i += 256) {
    int oc = i % COCB, rest = i / COCB, k = rest % 25, ci = rest / 25;
    wls[i] = w[((size_t)(m * COUT + ocb + oc) * CIN + ci) * 25 + k];
  }
  if (t < COCB) bls[t] = bias[m * COUT + ocb + t];
  const int pg = t % PG, grp = t / PG;
  const int gy = pg / PGW, gx = pg % PGW;
  const float* ip = in + (size_t)b * ib + (size_t)m * im;
  float acc[OCG][16];
#pragma unroll
  for (int o = 0; o < OCG; ++o)
#pragma unroll
    for (int p = 0; p < 16; ++p) acc[o][p] = 0.f;

#pragma unroll 1
  for (int cc = 0; cc < NC; ++cc) {
    __syncthreads();  // covers initial zero/weights too
    for (int i = t; i < CICH * S * S; i += 256) {
      int ci = i / (S * S), r = i % (S * S), y = r / S, xx = r % S;
      ins[ci * PSPS + (y + 2) * PS + xx + 2] = ip[(size_t)(cc * CICH + ci) * S * S + r];
    }
    __syncthreads();
#pragma unroll 1
    for (int ci = 0; ci < CICH; ++ci) {
      float pr[8][8];
#pragma unroll
      for (int yy = 0; yy < 8; ++yy) {
        float4 a = *(const float4*)&ins[ci * PSPS + (4 * gy + yy) * PS + 4 * gx];
        float4 bb = *(const float4*)&ins[ci * PSPS + (4 * gy + yy) * PS + 4 * gx + 4];
        pr[yy][0] = a.x; pr[yy][1] = a.y; pr[yy][2] = a.z; pr[yy][3] = a.w;
        pr[yy][4] = bb.x; pr[yy][5] = bb.y; pr[yy][6] = bb.z; pr[yy][7] = bb.w;
      }
      const int cig = cc * CICH + ci;
#pragma unroll
      for (int ky = 0; ky < 5; ++ky)
#pragma unroll
        for (int kx = 0; kx < 5; ++kx) {
          if constexpr (OCG == 4) {
            float4 wv = *(const float4*)&wls[(cig * 25 + ky * 5 + kx) * COCB + grp * 4];
            float wa[4] = {wv.x, wv.y, wv.z, wv.w};
#pragma unroll
            for (int o = 0; o < 4; ++o)
#pragma unroll
              for (int dy = 0; dy < 4; ++dy)
#pragma unroll
                for (int dx = 0; dx < 4; ++dx)
                  acc[o][dy * 4 + dx] += pr[ky + dy][kx + dx] * wa[o];
          } else {
            float wv = wls[(cig * 25 + ky * 5 + kx) * COCB + grp];
#pragma unroll
            for (int dy = 0; dy < 4; ++dy)
#pragma unroll
              for (int dx = 0; dx < 4; ++dx)
                acc[0][dy * 4 + dx] += pr[ky + dy][kx + dx] * wv;
          }
        }
    }
  }
  float* op = out + (size_t)b * ob + (size_t)m * om;
#pragma unroll
  for (int o = 0; o < OCG; ++o) {
    float bv = bls[grp * OCG + o];
#pragma unroll
    for (int ay = 0; ay < 2; ++ay)
#pragma unroll
      for (int ax = 0; ax < 2; ++ax) {
        float v = fmaxf(fmaxf(acc[o][(2 * ay) * 4 + 2 * ax], acc[o][(2 * ay) * 4 + 2 * ax + 1]),
                        fmaxf(acc[o][(2 * ay + 1) * 4 + 2 * ax], acc[o][(2 * ay + 1) * 4 + 2 * ax + 1]));
        v = fmaxf(v + bv, 0.f);
        op[(size_t)(ocb + grp * OCG + o) * (P * P) + (size_t)(2 * gy + ay) * P + (2 * gx + ax)] = v;
      }
  }
}

// =================== MLP ===================
__global__ void init_h1(const float* __restrict__ bias, float* __restrict__ h1) {
  int i = blockIdx.x * 256 + threadIdx.x;
  h1[i] = bias[i & 255];
}

// grid (8 rowblocks, 4 colquads, 8 ksplits); block: 64 rows x 64 cols, k-range 768
__global__ __launch_bounds__(256) void lin1_kernel(const float* __restrict__ feat,
                                                   const float* __restrict__ W,
                                                   float* __restrict__ h1) {
  constexpr int FS = 68;
  __shared__ __align__(16) float fsT[64 * FS];
  __shared__ __align__(16) float wsl[64 * 64];
  const int r0 = blockIdx.x * 64, c0 = blockIdx.y * 64, ks = blockIdx.z;
  const int t = threadIdx.x;
  const int ct = t % 16, rt = t / 16;
  float acc[4][4];
#pragma unroll
  for (int i = 0; i < 4; ++i)
#pragma unroll
    for (int j = 0; j < 4; ++j) acc[i][j] = 0.f;
#pragma unroll 1
  for (int ch = 0; ch < 12; ++ch) {
    const int k0 = ks * 768 + ch * 64;
    __syncthreads();
    for (int i = t; i < 4096; i += 256) {
      int r = i >> 6, k = i & 63;
      fsT[k * FS + r] = feat[(size_t)(r0 + r) * 6144 + k0 + k];
    }
    for (int i = t; i < 4096; i += 256) {
      int k = i >> 6, c = i & 63;
      wsl[k * 64 + c] = W[(size_t)(k0 + k) * 256 + c0 + c];
    }
    __syncthreads();
#pragma unroll 4
    for (int k = 0; k < 64; ++k) {
      float4 fv = *(const float4*)&fsT[k * FS + 4 * rt];
      float4 wv = *(const float4*)&wsl[k * 64 + 4 * ct];
      float fa[4] = {fv.x, fv.y, fv.z, fv.w};
      float wa[4] = {wv.x, wv.y, wv.z, wv.w};
#pragma unroll
      for (int i = 0; i < 4; ++i)
#pragma unroll
        for (int j = 0; j < 4; ++j) acc[i][j] += fa[i] * wa[j];
    }
  }
#pragma unroll
  for (int i = 0; i < 4; ++i)
#pragma unroll
    for (int j = 0; j < 4; ++j)
      atomicAdd(&h1[(size_t)(r0 + 4 * rt + i) * 256 + c0 + 4 * ct + j], acc[i][j]);
}

// grid 32 blocks; block = 16 rows; thread (r=t/16, j=t%16)
__global__ __launch_bounds__(256) void head_kernel(
    const float* __restrict__ h1, const float* __restrict__ w2,
    const float* __restrict__ b2, const float* __restrict__ sw,
    const float* __restrict__ sb, float* __restrict__ out) {
  constexpr int HS = 260;
  __shared__ __align__(16) float h1s[16 * HS];
  __shared__ __align__(16) float w2s[256 * 16];
  const int r0 = blockIdx.x * 16, t = threadIdx.x;
  for (int i = t; i < 4096; i += 256) {
    int r = i >> 8, k = i & 255;
    h1s[r * HS + k] = h1[(size_t)(r0 + r) * 256 + k];
    w2s[i] = w2[i];
  }
  __syncthreads();
  const int j = t & 15, r = t >> 4;
  float acc = b2[j];
#pragma unroll 4
  for (int k4 = 0; k4 < 64; ++k4) {
    float4 hv = *(const float4*)&h1s[r * HS + 4 * k4];
    float h0 = fmaxf(hv.x, 0.f), h1v = fmaxf(hv.y, 0.f);
    float h2v = fmaxf(hv.z, 0.f), h3 = fmaxf(hv.w, 0.f);
    acc += h0 * w2s[(4 * k4 + 0) * 16 + j];
    acc += h1v * w2s[(4 * k4 + 1) * 16 + j];
    acc += h2v * w2s[(4 * k4 + 2) * 16 + j];
    acc += h3 * w2s[(4 * k4 + 3) * 16 + j];
  }
  float v = fmaxf(acc, 0.f) * sw[j];
#pragma unroll
  for (int off = 8; off; off >>= 1) v += __shfl_xor(v, off, 16);
  if (j == 0) out[r0 + r] = v + sb[0];
}

// =================== launcher ===================
extern "C" void kernel_launch(void* const* d_in, const int* in_sizes, int n_in,
                              void* d_out, int out_size, void* d_ws, size_t ws_size,
                              hipStream_t stream) {
  const float* x_q = (const float*)d_in[0];
  const float* x_c = (const float*)d_in[1];
  const int* edge_q = (const int*)d_in[2];
  const int* edge_c = (const int*)d_in[3];
  const float* gw1 = (const float*)d_in[4];
  const float* gb1 = (const float*)d_in[5];
  const float* gw2 = (const float*)d_in[6];
  const float* gb2 = (const float*)d_in[7];
  const float* gw3 = (const float*)d_in[8];
  const float* gb3 = (const float*)d_in[9];
  const float* cw1 = (const float*)d_in[10];
  const float* cb1 = (const float*)d_in[11];
  const float* cw2 = (const float*)d_in[12];
  const float* cb2 = (const float*)d_in[13];
  const float* cw3 = (const float*)d_in[14];
  const float* cb3 = (const float*)d_in[15];
  const float* lw1 = (const float*)d_in[16];
  const float* lb1 = (const float*)d_in[17];
  const float* lw2 = (const float*)d_in[18];
  const float* lb2 = (const float*)d_in[19];
  const float* swt = (const float*)d_in[20];
  const float* sbs = (const float*)d_in[21];
  float* ws = (float*)d_ws;

  const size_t o_dinvq = 0;
  const size_t o_dinvc = 32768;
  const size_t o_f1q = 65536;
  const size_t o_f2q = o_f1q + 2097152;
  const size_t o_f3q = o_f2q + 1048576;
  const size_t o_f1c = o_f3q + 524288;
  const size_t o_f2c = o_f1c + 2097152;
  const size_t o_f3c = o_f2c + 1048576;
  const size_t o_sims = o_f3c + 524288;
  const size_t o_pm1 = o_sims + 6291456;
  const size_t o_pm2 = o_sims;  // reuse
  const size_t o_feat = o_pm1;  // reuse
  const size_t o_h1 = o_f1q;    // reuse

  float* dinvq = ws + o_dinvq;
  float* dinvc = ws + o_dinvc;
  float* f1q = ws + o_f1q; float* f2q = ws + o_f2q; float* f3q = ws + o_f3q;
  float* f1c = ws + o_f1c; float* f2c = ws + o_f2c; float* f3c = ws + o_f3c;
  float* sims = ws + o_sims;
  float* pm1 = ws + o_pm1;
  float* pm2 = ws + o_pm2;
  float* feat = ws + o_feat;
  float* h1 = ws + o_h1;

  gcn_kernel<16, 64, false, true><<<dim3(B, 2), 256, 0, stream>>>(
      x_q, x_c, gw1, gb1, edge_q, edge_c, dinvq, dinvc, f1q, f1c);
  gcn_kernel<64, 32, true, false><<<dim3(B, 2), 256, 0, stream>>>(
      f1q, f1c, gw2, gb2, edge_q, edge_c, dinvq, dinvc, f2q, f2c);
  gcn_kernel<32, 16, true, false><<<dim3(B, 2), 256, 0, stream>>>(
      f2q, f2c, gw3, gb3, edge_q, edge_c, dinvq, dinvc, f3q, f3c);

  sim_kernel<64><<<B, 256, 0, stream>>>(f1q, f1c, sims + 0 * (size_t)B * 4096);
  sim_kernel<32><<<B, 256, 0, stream>>>(f2q, f2c, sims + 1 * (size_t)B * 4096);
  sim_kernel<16><<<B, 256, 0, stream>>>(f3q, f3c, sims + 2 * (size_t)B * 4096);

  conv1_kernel<<<dim3(B, 3), 256, 0, stream>>>(sims, cw1, cb1, pm1);
  conv_kernel<8, 4, 16, 4, 32, 16><<<dim3(B, 3, 1), 256, 0, stream>>>(
      pm1, cw2, cb2, pm2, 8192, 4194304, 4096, 2097152);
  conv_kernel<16, 4, 16, 1, 16, 32><<<dim3(B, 3, 2), 256, 0, stream>>>(
      pm2, cw3, cb3, feat, 4096, 2097152, 6144, 2048);

  init_h1<<<512, 256, 0, stream>>>(lb1, h1);
  lin1_kernel<<<dim3(8, 4, 8), 256, 0, stream>>>(feat, lw1, h1);
  head_kernel<<<32, 256, 0, stream>>>(h1, lw2, lb2, swt, sbs, (float*)d_out);
}

// Round 3
// 440.315 us; speedup vs baseline: 2.3455x; 1.0738x over previous
//
#include <hip/hip_runtime.h>
#include <hip/hip_bf16.h>

constexpr int B = 512, N = 64, E = 512, NE = B * E;

// =================== fused 3-layer GCN: dense-A built once, layers chained in LDS ===================
template <int DIN, int DOUT, bool STORE_NEXT>
__device__ __forceinline__ void gcn_layer(
    float* __restrict__ At, float* __restrict__ Xt, float* __restrict__ Hs,
    float* __restrict__ Wls, const float* __restrict__ W,
    const float* __restrict__ bias, float* __restrict__ fout, int g, int t) {
  constexpr int XS = 68;
  for (int i = t; i < DIN * DOUT; i += 256) Wls[i] = W[i];
  __syncthreads();
  constexpr int CT = DOUT / 4;
  const int ct = t % CT, nt = t / CT;
  // matmul1: Hs[n][c] = sum_k Xt[k][n] * Wls[k][c]
  if (nt < 16) {
    float acc[4][4] = {};
#pragma unroll 4
    for (int k = 0; k < DIN; ++k) {
      float4 xv = *(const float4*)&Xt[k * XS + 4 * nt];
      float4 wv = *(const float4*)&Wls[k * DOUT + 4 * ct];
      float xa[4] = {xv.x, xv.y, xv.z, xv.w};
      float wa[4] = {wv.x, wv.y, wv.z, wv.w};
#pragma unroll
      for (int i = 0; i < 4; ++i)
#pragma unroll
        for (int j = 0; j < 4; ++j) acc[i][j] += xa[i] * wa[j];
    }
#pragma unroll
    for (int i = 0; i < 4; ++i) {
      float4 st = {acc[i][0], acc[i][1], acc[i][2], acc[i][3]};
      *(float4*)&Hs[(4 * nt + i) * XS + 4 * ct] = st;
    }
  }
  __syncthreads();
  // matmul2: out[d][c] = sum_s At[s][d] * Hs[s][c] + bias[c]
  if (nt < 16) {
    float acc[4][4] = {};
#pragma unroll 4
    for (int s = 0; s < N; ++s) {
      float4 av = *(const float4*)&At[s * XS + 4 * nt];
      float4 hv = *(const float4*)&Hs[s * XS + 4 * ct];
      float aa[4] = {av.x, av.y, av.z, av.w};
      float ha[4] = {hv.x, hv.y, hv.z, hv.w};
#pragma unroll
      for (int i = 0; i < 4; ++i)
#pragma unroll
        for (int j = 0; j < 4; ++j) acc[i][j] += aa[i] * ha[j];
    }
    const float4 bv = *(const float4*)&bias[4 * ct];
#pragma unroll
    for (int i = 0; i < 4; ++i) {
      float4 st = {acc[i][0] + bv.x, acc[i][1] + bv.y, acc[i][2] + bv.z,
                   acc[i][3] + bv.w};
      *(float4*)&fout[(size_t)g * N * DOUT + (size_t)(4 * nt + i) * DOUT + 4 * ct] = st;
      if (STORE_NEXT) {
        // next layer's input, transposed [k][n], with ReLU
        Xt[(4 * ct + 0) * XS + 4 * nt + i] = fmaxf(st.x, 0.f);
        Xt[(4 * ct + 1) * XS + 4 * nt + i] = fmaxf(st.y, 0.f);
        Xt[(4 * ct + 2) * XS + 4 * nt + i] = fmaxf(st.z, 0.f);
        Xt[(4 * ct + 3) * XS + 4 * nt + i] = fmaxf(st.w, 0.f);
      }
    }
  }
  __syncthreads();
}

__global__ __launch_bounds__(256) void gcn_fused(
    const float* __restrict__ xq, const float* __restrict__ xc,
    const float* __restrict__ W1, const float* __restrict__ b1,
    const float* __restrict__ W2, const float* __restrict__ b2,
    const float* __restrict__ W3, const float* __restrict__ b3,
    const int* __restrict__ eq, const int* __restrict__ ec,
    float* __restrict__ f1q, float* __restrict__ f1c,
    float* __restrict__ f2q, float* __restrict__ f2c,
    float* __restrict__ f3q, float* __restrict__ f3c) {
  constexpr int XS = 68;
  __shared__ __align__(16) float At[N * XS];
  __shared__ __align__(16) float Xt[N * XS];
  __shared__ __align__(16) float Hs[N * XS];
  __shared__ __align__(16) float Wls[64 * 32];
  __shared__ float dl[N];
  __shared__ int cnt[N];
  const int g = blockIdx.x, t = threadIdx.x;
  const float* x = blockIdx.y ? xc : xq;
  const int* edges = blockIdx.y ? ec : eq;
  float* o1 = blockIdx.y ? f1c : f1q;
  float* o2 = blockIdx.y ? f2c : f2q;
  float* o3 = blockIdx.y ? f3c : f3q;
  for (int i = t; i < N * 16; i += 256) {
    int n = i / 16, k = i % 16;
    Xt[k * XS + n] = x[(size_t)g * N * 16 + i];
  }
  for (int i = t; i < N * XS; i += 256) At[i] = 0.f;
  if (t < N) cnt[t] = 1;  // self loop
  __syncthreads();
  const int* srcp = edges + (size_t)g * E;
  const int* dstp = edges + NE + (size_t)g * E;
  for (int j = t; j < E; j += 256) atomicAdd(&cnt[dstp[j] & 63], 1);
  __syncthreads();
  if (t < N) dl[t] = rsqrtf((float)cnt[t]);
  __syncthreads();
  for (int j = t; j < E; j += 256) {
    int s = srcp[j] & 63, d = dstp[j] & 63;
    atomicAdd(&At[s * XS + d], dl[s] * dl[d]);
  }
  if (t < N) atomicAdd(&At[t * XS + t], dl[t] * dl[t]);
  __syncthreads();
  gcn_layer<16, 64, true>(At, Xt, Hs, Wls, W1, b1, o1, g, t);
  gcn_layer<64, 32, true>(At, Xt, Hs, Wls, W2, b2, o2, g, t);
  gcn_layer<32, 16, false>(At, Xt, Hs, Wls, W3, b3, o3, g, t);
}

// =================== similarity: sim[b,n,m] = q_n . c_m, 4x4 register tile ===================
template <int D>
__global__ __launch_bounds__(256) void sim_kernel(const float* __restrict__ fq,
                                                  const float* __restrict__ fc,
                                                  float* __restrict__ so) {
  constexpr int XS = 68;
  __shared__ __align__(16) float Qt[D * XS];
  __shared__ __align__(16) float Ct[D * XS];
  const int b = blockIdx.x, t = threadIdx.x;
  for (int i = t; i < N * D; i += 256) {
    int n = i / D, k = i % D;
    Qt[k * XS + n] = fq[(size_t)b * N * D + i];
    Ct[k * XS + n] = fc[(size_t)b * N * D + i];
  }
  __syncthreads();
  const int ct = t % 16, nt = t / 16;
  float acc[4][4] = {};
#pragma unroll 4
  for (int k = 0; k < D; ++k) {
    float4 qv = *(const float4*)&Qt[k * XS + 4 * nt];
    float4 cv = *(const float4*)&Ct[k * XS + 4 * ct];
    float qa[4] = {qv.x, qv.y, qv.z, qv.w};
    float ca[4] = {cv.x, cv.y, cv.z, cv.w};
#pragma unroll
    for (int i = 0; i < 4; ++i)
#pragma unroll
      for (int j = 0; j < 4; ++j) acc[i][j] += qa[i] * ca[j];
  }
#pragma unroll
  for (int i = 0; i < 4; ++i) {
    float4 st = {acc[i][0], acc[i][1], acc[i][2], acc[i][3]};
    *(float4*)&so[(size_t)b * 4096 + (size_t)(4 * nt + i) * 64 + 4 * ct] = st;
  }
}

// =================== conv1: CIN=1, 64x64 ===================
__global__ __launch_bounds__(256) void conv1_kernel(const float* __restrict__ in,
                                                    const float* __restrict__ w,
                                                    const float* __restrict__ bias,
                                                    float* __restrict__ out) {
  constexpr int S = 64, PS = 68, PSPS = PS * PS;
  __shared__ __align__(16) float ins[PSPS];
  __shared__ float wls[8 * 25];
  __shared__ float bls[8];
  const int b = blockIdx.x, m = blockIdx.y, t = threadIdx.x;
  for (int i = t; i < PSPS; i += 256) ins[i] = 0.f;
  if (t < 200) wls[t] = w[m * 200 + t];
  if (t < 8) bls[t] = bias[m * 8 + t];
  __syncthreads();
  const float* ip = in + (size_t)b * 4096 + (size_t)m * 2097152;
  for (int i = t; i < S * S; i += 256) {
    int y = i >> 6, xx = i & 63;
    ins[(y + 2) * PS + xx + 2] = ip[i];
  }
  __syncthreads();
  const int gy = t >> 4, gx = t & 15;
  float pr[8][8];
#pragma unroll
  for (int yy = 0; yy < 8; ++yy) {
    float4 a = *(const float4*)&ins[(4 * gy + yy) * PS + 4 * gx];
    float4 bb = *(const float4*)&ins[(4 * gy + yy) * PS + 4 * gx + 4];
    pr[yy][0] = a.x; pr[yy][1] = a.y; pr[yy][2] = a.z; pr[yy][3] = a.w;
    pr[yy][4] = bb.x; pr[yy][5] = bb.y; pr[yy][6] = bb.z; pr[yy][7] = bb.w;
  }
  float* op = out + (size_t)b * 8192 + (size_t)m * 4194304;
#pragma unroll 1
  for (int oc = 0; oc < 8; ++oc) {
    float acc[16];
#pragma unroll
    for (int p = 0; p < 16; ++p) acc[p] = 0.f;
#pragma unroll
    for (int ky = 0; ky < 5; ++ky)
#pragma unroll
      for (int kx = 0; kx < 5; ++kx) {
        float wv = wls[oc * 25 + ky * 5 + kx];
#pragma unroll
        for (int dy = 0; dy < 4; ++dy)
#pragma unroll
          for (int dx = 0; dx < 4; ++dx) acc[dy * 4 + dx] += pr[ky + dy][kx + dx] * wv;
      }
    float bv = bls[oc];
#pragma unroll
    for (int ay = 0; ay < 2; ++ay)
#pragma unroll
      for (int ax = 0; ax < 2; ++ax) {
        float v = fmaxf(fmaxf(acc[(2 * ay) * 4 + 2 * ax], acc[(2 * ay) * 4 + 2 * ax + 1]),
                        fmaxf(acc[(2 * ay + 1) * 4 + 2 * ax], acc[(2 * ay + 1) * 4 + 2 * ax + 1]));
        v = fmaxf(v + bv, 0.f);
        op[(size_t)oc * 1024 + (size_t)(2 * gy + ay) * 32 + (2 * gx + ax)] = v;
      }
  }
}

// =================== conv2/conv3: row-streaming, 4 oc x 16 conv positions per thread ===================
template <int CIN, int CICH, int COCB, int S, int COUT, int BLK>
__global__ __launch_bounds__(BLK) void convp_kernel(
    const float* __restrict__ in, const float* __restrict__ w,
    const float* __restrict__ bias, float* __restrict__ out,
    int ib, size_t im, int ob, size_t om) {
  constexpr int PS = S + 4, PSPS = PS * PS, P = S / 2, PGW = S / 4;
  constexpr int PG = PGW * PGW, GROUPS = BLK / PG, NC = CIN / CICH;
  static_assert(GROUPS * 4 == COCB, "mapping");
  __shared__ __align__(16) float ins[CICH * PSPS];
  __shared__ __align__(16) float wls[CICH * 25 * COCB];  // [ci][k][oc]
  __shared__ float bls[COCB];
  const int b = blockIdx.x, m = blockIdx.y, t = threadIdx.x;
  const int pg = t % PG, grp = t / PG;
  const int gy = pg / PGW, gx = pg % PGW;
  for (int i = t; i < CICH * PSPS; i += BLK) ins[i] = 0.f;
  if (t < COCB) bls[t] = bias[m * COUT + t];
  const float* ip = in + (size_t)b * ib + (size_t)m * im;
  float acc[4][16];
#pragma unroll
  for (int o = 0; o < 4; ++o)
#pragma unroll
    for (int p = 0; p < 16; ++p) acc[o][p] = 0.f;

#pragma unroll 1
  for (int cc = 0; cc < NC; ++cc) {
    __syncthreads();  // also covers initial zero-fill
    for (int i = t; i < CICH * S * S; i += BLK) {
      int ci = i / (S * S), r = i % (S * S), y = r / S, xx = r % S;
      ins[ci * PSPS + (y + 2) * PS + xx + 2] = ip[(size_t)(cc * CICH + ci) * S * S + r];
    }
    for (int i = t; i < CICH * 25 * COCB; i += BLK) {
      int oc = i % COCB, rest = i / COCB, k = rest % 25, cil = rest / 25;
      wls[i] = w[((size_t)(m * COUT + oc) * CIN + cc * CICH + cil) * 25 + k];
    }
    __syncthreads();
#pragma unroll 1
    for (int ci = 0; ci < CICH; ++ci) {
#pragma unroll
      for (int yy = 0; yy < 8; ++yy) {
        const float4 a = *(const float4*)&ins[ci * PSPS + (4 * gy + yy) * PS + 4 * gx];
        const float4 bq = *(const float4*)&ins[ci * PSPS + (4 * gy + yy) * PS + 4 * gx + 4];
        const float row[8] = {a.x, a.y, a.z, a.w, bq.x, bq.y, bq.z, bq.w};
#pragma unroll
        for (int dy = 0; dy < 4; ++dy) {
          const int ky = yy - dy;
          if (ky < 0 || ky > 4) continue;  // compile-time
#pragma unroll
          for (int kx = 0; kx < 5; ++kx) {
            const float4 wv =
                *(const float4*)&wls[(ci * 25 + ky * 5 + kx) * COCB + grp * 4];
#pragma unroll
            for (int dx = 0; dx < 4; ++dx) {
              const float rv = row[kx + dx];
              acc[0][dy * 4 + dx] += rv * wv.x;
              acc[1][dy * 4 + dx] += rv * wv.y;
              acc[2][dy * 4 + dx] += rv * wv.z;
              acc[3][dy * 4 + dx] += rv * wv.w;
            }
          }
        }
      }
    }
  }
  float* op = out + (size_t)b * ob + (size_t)m * om;
#pragma unroll
  for (int o = 0; o < 4; ++o) {
    float bv = bls[grp * 4 + o];
#pragma unroll
    for (int ay = 0; ay < 2; ++ay)
#pragma unroll
      for (int ax = 0; ax < 2; ++ax) {
        float v = fmaxf(fmaxf(acc[o][(2 * ay) * 4 + 2 * ax], acc[o][(2 * ay) * 4 + 2 * ax + 1]),
                        fmaxf(acc[o][(2 * ay + 1) * 4 + 2 * ax], acc[o][(2 * ay + 1) * 4 + 2 * ax + 1]));
        v = fmaxf(v + bv, 0.f);
        op[(size_t)(grp * 4 + o) * (P * P) + (size_t)(2 * gy + ay) * P + (2 * gx + ax)] = v;
      }
  }
}

// =================== MLP ===================
__global__ void init_h1(const float* __restrict__ bias, float* __restrict__ h1) {
  int i = blockIdx.x * 256 + threadIdx.x;
  h1[i] = bias[i & 255];
}

// grid (8 rowblocks, 4 colquads, 16 ksplits); block: 64 rows x 64 cols, k-range 384
__global__ __launch_bounds__(256) void lin1_kernel(const float* __restrict__ feat,
                                                   const float* __restrict__ W,
                                                   float* __restrict__ h1) {
  constexpr int FS = 68;
  __shared__ __align__(16) float fsT[64 * FS];
  __shared__ __align__(16) float wsl[64 * 64];
  const int r0 = blockIdx.x * 64, c0 = blockIdx.y * 64, ks = blockIdx.z;
  const int t = threadIdx.x;
  const int ct = t % 16, rt = t / 16;
  float acc[4][4] = {};
#pragma unroll 1
  for (int ch = 0; ch < 6; ++ch) {
    const int k0 = ks * 384 + ch * 64;
    __syncthreads();
    for (int i = t; i < 4096; i += 256) {
      int r = i >> 6, k = i & 63;
      fsT[k * FS + r] = feat[(size_t)(r0 + r) * 6144 + k0 + k];
    }
    for (int i = t; i < 4096; i += 256) {
      int k = i >> 6, c = i & 63;
      wsl[k * 64 + c] = W[(size_t)(k0 + k) * 256 + c0 + c];
    }
    __syncthreads();
#pragma unroll 4
    for (int k = 0; k < 64; ++k) {
      float4 fv = *(const float4*)&fsT[k * FS + 4 * rt];
      float4 wv = *(const float4*)&wsl[k * 64 + 4 * ct];
      float fa[4] = {fv.x, fv.y, fv.z, fv.w};
      float wa[4] = {wv.x, wv.y, wv.z, wv.w};
#pragma unroll
      for (int i = 0; i < 4; ++i)
#pragma unroll
        for (int j = 0; j < 4; ++j) acc[i][j] += fa[i] * wa[j];
    }
  }
#pragma unroll
  for (int i = 0; i < 4; ++i)
#pragma unroll
    for (int j = 0; j < 4; ++j)
      atomicAdd(&h1[(size_t)(r0 + 4 * rt + i) * 256 + c0 + 4 * ct + j], acc[i][j]);
}

// grid 32 blocks; block = 16 rows; thread (r=t/16, j=t%16)
__global__ __launch_bounds__(256) void head_kernel(
    const float* __restrict__ h1, const float* __restrict__ w2,
    const float* __restrict__ b2, const float* __restrict__ sw,
    const float* __restrict__ sb, float* __restrict__ out) {
  constexpr int HS = 260;
  __shared__ __align__(16) float h1s[16 * HS];
  __shared__ __align__(16) float w2s[256 * 16];
  const int r0 = blockIdx.x * 16, t = threadIdx.x;
  for (int i = t; i < 4096; i += 256) {
    int r = i >> 8, k = i & 255;
    h1s[r * HS + k] = h1[(size_t)(r0 + r) * 256 + k];
    w2s[i] = w2[i];
  }
  __syncthreads();
  const int j = t & 15, r = t >> 4;
  float acc = b2[j];
#pragma unroll 4
  for (int k4 = 0; k4 < 64; ++k4) {
    float4 hv = *(const float4*)&h1s[r * HS + 4 * k4];
    float h0 = fmaxf(hv.x, 0.f), h1v = fmaxf(hv.y, 0.f);
    float h2v = fmaxf(hv.z, 0.f), h3 = fmaxf(hv.w, 0.f);
    acc += h0 * w2s[(4 * k4 + 0) * 16 + j];
    acc += h1v * w2s[(4 * k4 + 1) * 16 + j];
    acc += h2v * w2s[(4 * k4 + 2) * 16 + j];
    acc += h3 * w2s[(4 * k4 + 3) * 16 + j];
  }
  float v = fmaxf(acc, 0.f) * sw[j];
#pragma unroll
  for (int off = 8; off; off >>= 1) v += __shfl_xor(v, off, 16);
  if (j == 0) out[r0 + r] = v + sb[0];
}

// =================== launcher ===================
extern "C" void kernel_launch(void* const* d_in, const int* in_sizes, int n_in,
                              void* d_out, int out_size, void* d_ws, size_t ws_size,
                              hipStream_t stream) {
  const float* x_q = (const float*)d_in[0];
  const float* x_c = (const float*)d_in[1];
  const int* edge_q = (const int*)d_in[2];
  const int* edge_c = (const int*)d_in[3];
  const float* gw1 = (const float*)d_in[4];
  const float* gb1 = (const float*)d_in[5];
  const float* gw2 = (const float*)d_in[6];
  const float* gb2 = (const float*)d_in[7];
  const float* gw3 = (const float*)d_in[8];
  const float* gb3 = (const float*)d_in[9];
  const float* cw1 = (const float*)d_in[10];
  const float* cb1 = (const float*)d_in[11];
  const float* cw2 = (const float*)d_in[12];
  const float* cb2 = (const float*)d_in[13];
  const float* cw3 = (const float*)d_in[14];
  const float* cb3 = (const float*)d_in[15];
  const float* lw1 = (const float*)d_in[16];
  const float* lb1 = (const float*)d_in[17];
  const float* lw2 = (const float*)d_in[18];
  const float* lb2 = (const float*)d_in[19];
  const float* swt = (const float*)d_in[20];
  const float* sbs = (const float*)d_in[21];
  float* ws = (float*)d_ws;

  const size_t o_f1q = 65536;
  const size_t o_f2q = o_f1q + 2097152;
  const size_t o_f3q = o_f2q + 1048576;
  const size_t o_f1c = o_f3q + 524288;
  const size_t o_f2c = o_f1c + 2097152;
  const size_t o_f3c = o_f2c + 1048576;
  const size_t o_sims = o_f3c + 524288;
  const size_t o_pm1 = o_sims + 6291456;
  const size_t o_pm2 = o_sims;  // reuse (sims dead after conv1)
  const size_t o_feat = o_pm1;  // reuse (pm1 dead after conv2)
  const size_t o_h1 = o_f1q;    // reuse (f1q dead after sims)

  float* f1q = ws + o_f1q; float* f2q = ws + o_f2q; float* f3q = ws + o_f3q;
  float* f1c = ws + o_f1c; float* f2c = ws + o_f2c; float* f3c = ws + o_f3c;
  float* sims = ws + o_sims;
  float* pm1 = ws + o_pm1;
  float* pm2 = ws + o_pm2;
  float* feat = ws + o_feat;
  float* h1 = ws + o_h1;

  gcn_fused<<<dim3(B, 2), 256, 0, stream>>>(x_q, x_c, gw1, gb1, gw2, gb2, gw3, gb3,
                                            edge_q, edge_c, f1q, f1c, f2q, f2c, f3q, f3c);

  sim_kernel<64><<<B, 256, 0, stream>>>(f1q, f1c, sims + 0 * (size_t)B * 4096);
  sim_kernel<32><<<B, 256, 0, stream>>>(f2q, f2c, sims + 1 * (size_t)B * 4096);
  sim_kernel<16><<<B, 256, 0, stream>>>(f3q, f3c, sims + 2 * (size_t)B * 4096);

  conv1_kernel<<<dim3(B, 3), 256, 0, stream>>>(sims, cw1, cb1, pm1);
  // conv2: [B,8,32,32] -> pooled [B,16,16,16]
  convp_kernel<8, 4, 16, 32, 16, 256><<<dim3(B, 3), 256, 0, stream>>>(
      pm1, cw2, cb2, pm2, 8192, 4194304, 4096, 2097152);
  // conv3: [B,16,16,16] -> pooled [B,32,8,8] into feat[B,6144]
  convp_kernel<16, 4, 32, 16, 32, 128><<<dim3(B, 3), 128, 0, stream>>>(
      pm2, cw3, cb3, feat, 4096, 2097152, 6144, 2048);

  init_h1<<<512, 256, 0, stream>>>(lb1, h1);
  lin1_kernel<<<dim3(8, 4, 16), 256, 0, stream>>>(feat, lw1, h1);
  head_kernel<<<32, 256, 0, stream>>>(h1, lw2, lb2, swt, sbs, (float*)d_out);
}

// Round 4
// 233.712 us; speedup vs baseline: 4.4190x; 1.8840x over previous
//
#include <hip/hip_runtime.h>
#include <hip/hip_bf16.h>

constexpr int B = 512, N = 64, E = 512, NE = B * E;

typedef __attribute__((ext_vector_type(8))) short bf8v;
typedef __attribute__((ext_vector_type(4))) float f32x4;
typedef unsigned short u16;

__device__ __forceinline__ u16 f2bf(float f) {
  unsigned u = __builtin_bit_cast(unsigned, f);
  u += 0x7FFFu + ((u >> 16) & 1u);
  return (u16)(u >> 16);
}

// =================== fused 3-layer GCN (unchanged) ===================
template <int DIN, int DOUT, bool STORE_NEXT>
__device__ __forceinline__ void gcn_layer(
    float* __restrict__ At, float* __restrict__ Xt, float* __restrict__ Hs,
    float* __restrict__ Wls, const float* __restrict__ W,
    const float* __restrict__ bias, float* __restrict__ fout, int g, int t) {
  constexpr int XS = 68;
  for (int i = t; i < DIN * DOUT; i += 256) Wls[i] = W[i];
  __syncthreads();
  constexpr int CT = DOUT / 4;
  const int ct = t % CT, nt = t / CT;
  if (nt < 16) {
    float acc[4][4] = {};
#pragma unroll 4
    for (int k = 0; k < DIN; ++k) {
      float4 xv = *(const float4*)&Xt[k * XS + 4 * nt];
      float4 wv = *(const float4*)&Wls[k * DOUT + 4 * ct];
      float xa[4] = {xv.x, xv.y, xv.z, xv.w};
      float wa[4] = {wv.x, wv.y, wv.z, wv.w};
#pragma unroll
      for (int i = 0; i < 4; ++i)
#pragma unroll
        for (int j = 0; j < 4; ++j) acc[i][j] += xa[i] * wa[j];
    }
#pragma unroll
    for (int i = 0; i < 4; ++i) {
      float4 st = {acc[i][0], acc[i][1], acc[i][2], acc[i][3]};
      *(float4*)&Hs[(4 * nt + i) * XS + 4 * ct] = st;
    }
  }
  __syncthreads();
  if (nt < 16) {
    float acc[4][4] = {};
#pragma unroll 4
    for (int s = 0; s < N; ++s) {
      float4 av = *(const float4*)&At[s * XS + 4 * nt];
      float4 hv = *(const float4*)&Hs[s * XS + 4 * ct];
      float aa[4] = {av.x, av.y, av.z, av.w};
      float ha[4] = {hv.x, hv.y, hv.z, hv.w};
#pragma unroll
      for (int i = 0; i < 4; ++i)
#pragma unroll
        for (int j = 0; j < 4; ++j) acc[i][j] += aa[i] * ha[j];
    }
    const float4 bv = *(const float4*)&bias[4 * ct];
#pragma unroll
    for (int i = 0; i < 4; ++i) {
      float4 st = {acc[i][0] + bv.x, acc[i][1] + bv.y, acc[i][2] + bv.z,
                   acc[i][3] + bv.w};
      *(float4*)&fout[(size_t)g * N * DOUT + (size_t)(4 * nt + i) * DOUT + 4 * ct] = st;
      if (STORE_NEXT) {
        Xt[(4 * ct + 0) * XS + 4 * nt + i] = fmaxf(st.x, 0.f);
        Xt[(4 * ct + 1) * XS + 4 * nt + i] = fmaxf(st.y, 0.f);
        Xt[(4 * ct + 2) * XS + 4 * nt + i] = fmaxf(st.z, 0.f);
        Xt[(4 * ct + 3) * XS + 4 * nt + i] = fmaxf(st.w, 0.f);
      }
    }
  }
  __syncthreads();
}

__global__ __launch_bounds__(256) void gcn_fused(
    const float* __restrict__ xq, const float* __restrict__ xc,
    const float* __restrict__ W1, const float* __restrict__ b1,
    const float* __restrict__ W2, const float* __restrict__ b2,
    const float* __restrict__ W3, const float* __restrict__ b3,
    const int* __restrict__ eq, const int* __restrict__ ec,
    float* __restrict__ f1q, float* __restrict__ f1c,
    float* __restrict__ f2q, float* __restrict__ f2c,
    float* __restrict__ f3q, float* __restrict__ f3c) {
  constexpr int XS = 68;
  __shared__ __align__(16) float At[N * XS];
  __shared__ __align__(16) float Xt[N * XS];
  __shared__ __align__(16) float Hs[N * XS];
  __shared__ __align__(16) float Wls[64 * 32];
  __shared__ float dl[N];
  __shared__ int cnt[N];
  const int g = blockIdx.x, t = threadIdx.x;
  const float* x = blockIdx.y ? xc : xq;
  const int* edges = blockIdx.y ? ec : eq;
  float* o1 = blockIdx.y ? f1c : f1q;
  float* o2 = blockIdx.y ? f2c : f2q;
  float* o3 = blockIdx.y ? f3c : f3q;
  for (int i = t; i < N * 16; i += 256) {
    int n = i / 16, k = i % 16;
    Xt[k * XS + n] = x[(size_t)g * N * 16 + i];
  }
  for (int i = t; i < N * XS; i += 256) At[i] = 0.f;
  if (t < N) cnt[t] = 1;
  __syncthreads();
  const int* srcp = edges + (size_t)g * E;
  const int* dstp = edges + NE + (size_t)g * E;
  for (int j = t; j < E; j += 256) atomicAdd(&cnt[dstp[j] & 63], 1);
  __syncthreads();
  if (t < N) dl[t] = rsqrtf((float)cnt[t]);
  __syncthreads();
  for (int j = t; j < E; j += 256) {
    int s = srcp[j] & 63, d = dstp[j] & 63;
    atomicAdd(&At[s * XS + d], dl[s] * dl[d]);
  }
  if (t < N) atomicAdd(&At[t * XS + t], dl[t] * dl[t]);
  __syncthreads();
  gcn_layer<16, 64, true>(At, Xt, Hs, Wls, W1, b1, o1, g, t);
  gcn_layer<64, 32, true>(At, Xt, Hs, Wls, W2, b2, o2, g, t);
  gcn_layer<32, 16, false>(At, Xt, Hs, Wls, W3, b3, o3, g, t);
}

// =================== similarity (unchanged) ===================
template <int D>
__global__ __launch_bounds__(256) void sim_kernel(const float* __restrict__ fq,
                                                  const float* __restrict__ fc,
                                                  float* __restrict__ so) {
  constexpr int XS = 68;
  __shared__ __align__(16) float Qt[D * XS];
  __shared__ __align__(16) float Ct[D * XS];
  const int b = blockIdx.x, t = threadIdx.x;
  for (int i = t; i < N * D; i += 256) {
    int n = i / D, k = i % D;
    Qt[k * XS + n] = fq[(size_t)b * N * D + i];
    Ct[k * XS + n] = fc[(size_t)b * N * D + i];
  }
  __syncthreads();
  const int ct = t % 16, nt = t / 16;
  float acc[4][4] = {};
#pragma unroll 4
  for (int k = 0; k < D; ++k) {
    float4 qv = *(const float4*)&Qt[k * XS + 4 * nt];
    float4 cv = *(const float4*)&Ct[k * XS + 4 * ct];
    float qa[4] = {qv.x, qv.y, qv.z, qv.w};
    float ca[4] = {cv.x, cv.y, cv.z, cv.w};
#pragma unroll
    for (int i = 0; i < 4; ++i)
#pragma unroll
      for (int j = 0; j < 4; ++j) acc[i][j] += qa[i] * ca[j];
  }
#pragma unroll
  for (int i = 0; i < 4; ++i) {
    float4 st = {acc[i][0], acc[i][1], acc[i][2], acc[i][3]};
    *(float4*)&so[(size_t)b * 4096 + (size_t)(4 * nt + i) * 64 + 4 * ct] = st;
  }
}

// =================== conv1: fp32 VALU, emits bf16 channels-last [32][32][8] ===================
__global__ __launch_bounds__(256) void conv1_kernel(const float* __restrict__ in,
                                                    const float* __restrict__ w,
                                                    const float* __restrict__ bias,
                                                    u16* __restrict__ out) {
  constexpr int S = 64, PS = 68, PSPS = PS * PS;
  __shared__ __align__(16) float ins[PSPS];
  __shared__ float wls[8 * 25];
  __shared__ float bls[8];
  const int b = blockIdx.x, m = blockIdx.y, t = threadIdx.x;
  for (int i = t; i < PSPS; i += 256) ins[i] = 0.f;
  if (t < 200) wls[t] = w[m * 200 + t];
  if (t < 8) bls[t] = bias[m * 8 + t];
  __syncthreads();
  const float* ip = in + (size_t)m * 2097152 + (size_t)b * 4096;
  for (int i = t; i < S * S; i += 256) {
    int y = i >> 6, xx = i & 63;
    ins[(y + 2) * PS + xx + 2] = ip[i];
  }
  __syncthreads();
  const int gy = t >> 4, gx = t & 15;
  float pr[8][8];
#pragma unroll
  for (int yy = 0; yy < 8; ++yy) {
    float4 a = *(const float4*)&ins[(4 * gy + yy) * PS + 4 * gx];
    float4 bb = *(const float4*)&ins[(4 * gy + yy) * PS + 4 * gx + 4];
    pr[yy][0] = a.x; pr[yy][1] = a.y; pr[yy][2] = a.z; pr[yy][3] = a.w;
    pr[yy][4] = bb.x; pr[yy][5] = bb.y; pr[yy][6] = bb.z; pr[yy][7] = bb.w;
  }
  u16* op = out + (size_t)(b * 3 + m) * 8192;
#pragma unroll 1
  for (int oc = 0; oc < 8; ++oc) {
    float acc[16];
#pragma unroll
    for (int p = 0; p < 16; ++p) acc[p] = 0.f;
#pragma unroll
    for (int ky = 0; ky < 5; ++ky)
#pragma unroll
      for (int kx = 0; kx < 5; ++kx) {
        float wv = wls[oc * 25 + ky * 5 + kx];
#pragma unroll
        for (int dy = 0; dy < 4; ++dy)
#pragma unroll
          for (int dx = 0; dx < 4; ++dx) acc[dy * 4 + dx] += pr[ky + dy][kx + dx] * wv;
      }
    float bv = bls[oc];
#pragma unroll
    for (int ay = 0; ay < 2; ++ay)
#pragma unroll
      for (int ax = 0; ax < 2; ++ax) {
        float v = fmaxf(fmaxf(acc[(2 * ay) * 4 + 2 * ax], acc[(2 * ay) * 4 + 2 * ax + 1]),
                        fmaxf(acc[(2 * ay + 1) * 4 + 2 * ax], acc[(2 * ay + 1) * 4 + 2 * ax + 1]));
        v = fmaxf(v + bv, 0.f);
        op[(((2 * gy + ay) * 32) + (2 * gx + ax)) * 8 + oc] = f2bf(v);
      }
  }
}

// =================== conv2: bf16 MFMA, K=32 = 4 shifts x 8 ci ===================
// in pm1 [b][m][32][32][8] bf16 -> out pm2 [b][m][16][16][16] bf16
__global__ __launch_bounds__(256) void conv2_mfma(
    const u16* __restrict__ in, const float* __restrict__ w,
    const float* __restrict__ bias, u16* __restrict__ out) {
  constexpr int PW = 36, BS = 40;
  __shared__ __align__(16) u16 ins[PW * PW * 8];   // [y][x][ci]
  __shared__ __align__(16) u16 wls[7 * 16 * BS];   // [step][oc][k]
  __shared__ float bls[16];
  const int b = blockIdx.x, m = blockIdx.y, t = threadIdx.x;
  const size_t ibase = (size_t)(b * 3 + m) * 8192;
  for (int i = t; i < PW * PW; i += 256) {
    int y = i / PW, x = i % PW;
    uint4 v = {0u, 0u, 0u, 0u};
    if (y >= 2 && y < 34 && x >= 2 && x < 34)
      v = *(const uint4*)&in[ibase + (size_t)((y - 2) * 32 + (x - 2)) * 8];
    *(uint4*)&ins[i * 8] = v;
  }
  for (int i = t; i < 7 * 16 * 32; i += 256) {
    int k = i & 31, oc = (i >> 5) & 15, st = i >> 9;
    int sl = k >> 3, ci = k & 7, tap = st * 4 + sl;
    float v = (tap < 25) ? w[((size_t)(m * 16 + oc) * 8 + ci) * 25 + tap] : 0.f;
    wls[(st * 16 + oc) * BS + k] = f2bf(v);
  }
  if (t < 16) bls[t] = bias[m * 16 + t];
  __syncthreads();
  const int wv = t >> 6, lane = t & 63;
  const int oc = lane & 15, g = lane >> 4;   // oc doubles as A-row (lane&15)
  const size_t obase = (size_t)(b * 3 + m) * 4096;
#pragma unroll 1
  for (int task = wv; task < 32; task += 4) {
    const int yp = task >> 1, xt = task & 1;
    const int y0 = 2 * yp, x = xt * 16 + oc;
    f32x4 acc0 = {0.f, 0.f, 0.f, 0.f}, acc1 = {0.f, 0.f, 0.f, 0.f};
#pragma unroll
    for (int st = 0; st < 7; ++st) {
      bf8v bvv = *(const bf8v*)&wls[(st * 16 + oc) * BS + g * 8];
      int tp = st * 4 + g; tp = tp > 24 ? 24 : tp;
      int ky = tp / 5, kx = tp % 5;
      bf8v a0 = *(const bf8v*)&ins[(size_t)((y0 + ky) * PW + x + kx) * 8];
      acc0 = __builtin_amdgcn_mfma_f32_16x16x32_bf16(a0, bvv, acc0, 0, 0, 0);
      bf8v a1 = *(const bf8v*)&ins[(size_t)((y0 + 1 + ky) * PW + x + kx) * 8];
      acc1 = __builtin_amdgcn_mfma_f32_16x16x32_bf16(a1, bvv, acc1, 0, 0, 0);
    }
    const float bb = bls[oc];
    const float v0 = fmaxf(fmaxf(fmaxf(acc0[0], acc0[1]), fmaxf(acc1[0], acc1[1])) + bb, 0.f);
    const float v1 = fmaxf(fmaxf(fmaxf(acc0[2], acc0[3]), fmaxf(acc1[2], acc1[3])) + bb, 0.f);
    const int px = xt * 8 + 2 * g;
    out[obase + (size_t)((yp * 16 + px) * 16 + oc)] = f2bf(v0);
    out[obase + (size_t)((yp * 16 + px + 1) * 16 + oc)] = f2bf(v1);
  }
}

// =================== conv3: bf16 MFMA, K=32 = 2 shifts x 16 ci ===================
// in pm2 [b][m][16][16][16] bf16 -> feat fp32 [b][m*2048 + oc*64 + py*8 + px]
__global__ __launch_bounds__(256) void conv3_mfma(
    const u16* __restrict__ in, const float* __restrict__ w,
    const float* __restrict__ bias, float* __restrict__ feat) {
  constexpr int PW = 20, BS = 40;
  __shared__ __align__(16) u16 ins[PW * PW * 16];        // [y][x][ci]
  __shared__ __align__(16) u16 wls[13 * 2 * 16 * BS];    // [step][half][oc][k]
  __shared__ float bls[32];
  const int b = blockIdx.x, m = blockIdx.y, t = threadIdx.x;
  const size_t ibase = (size_t)(b * 3 + m) * 4096;
  for (int i = t; i < PW * PW; i += 256) {
    int y = i / PW, x = i % PW;
    uint4 v0 = {0u, 0u, 0u, 0u}, v1 = {0u, 0u, 0u, 0u};
    if (y >= 2 && y < 18 && x >= 2 && x < 18) {
      const u16* p = &in[ibase + (size_t)((y - 2) * 16 + (x - 2)) * 16];
      v0 = *(const uint4*)p;
      v1 = *(const uint4*)(p + 8);
    }
    *(uint4*)&ins[i * 16] = v0;
    *(uint4*)&ins[i * 16 + 8] = v1;
  }
  for (int i = t; i < 13 * 2 * 16 * 32; i += 256) {
    int k = i & 31, oc16 = (i >> 5) & 15, half = (i >> 9) & 1, st = i >> 10;
    int sl = k >> 4, ci = k & 15, tap = st * 2 + sl;
    int oc = half * 16 + oc16;
    float v = (tap < 25) ? w[((size_t)(m * 32 + oc) * 16 + ci) * 25 + tap] : 0.f;
    wls[((st * 2 + half) * 16 + oc16) * BS + k] = f2bf(v);
  }
  if (t < 32) bls[t] = bias[m * 32 + t];
  __syncthreads();
  const int wv = t >> 6, lane = t & 63;
  const int oc = lane & 15, g = lane >> 4;
  const int sl = g >> 1, ch = (g & 1) * 8;
  float* fb = feat + (size_t)b * 6144 + m * 2048;
#pragma unroll 1
  for (int task = wv; task < 16; task += 4) {
    const int yp = task >> 1, half = task & 1;
    const int y0 = 2 * yp, x = oc;
    f32x4 acc0 = {0.f, 0.f, 0.f, 0.f}, acc1 = {0.f, 0.f, 0.f, 0.f};
#pragma unroll
    for (int st = 0; st < 13; ++st) {
      bf8v bvv = *(const bf8v*)&wls[(size_t)((st * 2 + half) * 16 + oc) * BS + g * 8];
      int tp = st * 2 + sl; tp = tp > 24 ? 24 : tp;
      int ky = tp / 5, kx = tp % 5;
      bf8v a0 = *(const bf8v*)&ins[(size_t)((y0 + ky) * PW + x + kx) * 16 + ch];
      acc0 = __builtin_amdgcn_mfma_f32_16x16x32_bf16(a0, bvv, acc0, 0, 0, 0);
      bf8v a1 = *(const bf8v*)&ins[(size_t)((y0 + 1 + ky) * PW + x + kx) * 16 + ch];
      acc1 = __builtin_amdgcn_mfma_f32_16x16x32_bf16(a1, bvv, acc1, 0, 0, 0);
    }
    const int ocg = half * 16 + oc;
    const float bb = bls[ocg];
    const float v0 = fmaxf(fmaxf(fmaxf(acc0[0], acc0[1]), fmaxf(acc1[0], acc1[1])) + bb, 0.f);
    const float v1 = fmaxf(fmaxf(fmaxf(acc0[2], acc0[3]), fmaxf(acc1[2], acc1[3])) + bb, 0.f);
    *(float2*)&fb[ocg * 64 + yp * 8 + 2 * g] = make_float2(v0, v1);
  }
}

// =================== MLP (unchanged) ===================
__global__ void init_h1(const float* __restrict__ bias, float* __restrict__ h1) {
  int i = blockIdx.x * 256 + threadIdx.x;
  h1[i] = bias[i & 255];
}

__global__ __launch_bounds__(256) void lin1_kernel(const float* __restrict__ feat,
                                                   const float* __restrict__ W,
                                                   float* __restrict__ h1) {
  constexpr int FS = 68;
  __shared__ __align__(16) float fsT[64 * FS];
  __shared__ __align__(16) float wsl[64 * 64];
  const int r0 = blockIdx.x * 64, c0 = blockIdx.y * 64, ks = blockIdx.z;
  const int t = threadIdx.x;
  const int ct = t % 16, rt = t / 16;
  float acc[4][4] = {};
#pragma unroll 1
  for (int ch = 0; ch < 6; ++ch) {
    const int k0 = ks * 384 + ch * 64;
    __syncthreads();
    for (int i = t; i < 4096; i += 256) {
      int r = i >> 6, k = i & 63;
      fsT[k * FS + r] = feat[(size_t)(r0 + r) * 6144 + k0 + k];
    }
    for (int i = t; i < 4096; i += 256) {
      int k = i >> 6, c = i & 63;
      wsl[k * 64 + c] = W[(size_t)(k0 + k) * 256 + c0 + c];
    }
    __syncthreads();
#pragma unroll 4
    for (int k = 0; k < 64; ++k) {
      float4 fv = *(const float4*)&fsT[k * FS + 4 * rt];
      float4 wvv = *(const float4*)&wsl[k * 64 + 4 * ct];
      float fa[4] = {fv.x, fv.y, fv.z, fv.w};
      float wa[4] = {wvv.x, wvv.y, wvv.z, wvv.w};
#pragma unroll
      for (int i = 0; i < 4; ++i)
#pragma unroll
        for (int j = 0; j < 4; ++j) acc[i][j] += fa[i] * wa[j];
    }
  }
#pragma unroll
  for (int i = 0; i < 4; ++i)
#pragma unroll
    for (int j = 0; j < 4; ++j)
      atomicAdd(&h1[(size_t)(r0 + 4 * rt + i) * 256 + c0 + 4 * ct + j], acc[i][j]);
}

__global__ __launch_bounds__(256) void head_kernel(
    const float* __restrict__ h1, const float* __restrict__ w2,
    const float* __restrict__ b2, const float* __restrict__ sw,
    const float* __restrict__ sb, float* __restrict__ out) {
  constexpr int HS = 260;
  __shared__ __align__(16) float h1s[16 * HS];
  __shared__ __align__(16) float w2s[256 * 16];
  const int r0 = blockIdx.x * 16, t = threadIdx.x;
  for (int i = t; i < 4096; i += 256) {
    int r = i >> 8, k = i & 255;
    h1s[r * HS + k] = h1[(size_t)(r0 + r) * 256 + k];
    w2s[i] = w2[i];
  }
  __syncthreads();
  const int j = t & 15, r = t >> 4;
  float acc = b2[j];
#pragma unroll 4
  for (int k4 = 0; k4 < 64; ++k4) {
    float4 hv = *(const float4*)&h1s[r * HS + 4 * k4];
    float h0 = fmaxf(hv.x, 0.f), h1v = fmaxf(hv.y, 0.f);
    float h2v = fmaxf(hv.z, 0.f), h3 = fmaxf(hv.w, 0.f);
    acc += h0 * w2s[(4 * k4 + 0) * 16 + j];
    acc += h1v * w2s[(4 * k4 + 1) * 16 + j];
    acc += h2v * w2s[(4 * k4 + 2) * 16 + j];
    acc += h3 * w2s[(4 * k4 + 3) * 16 + j];
  }
  float v = fmaxf(acc, 0.f) * sw[j];
#pragma unroll
  for (int off = 8; off; off >>= 1) v += __shfl_xor(v, off, 16);
  if (j == 0) out[r0 + r] = v + sb[0];
}

// =================== launcher ===================
extern "C" void kernel_launch(void* const* d_in, const int* in_sizes, int n_in,
                              void* d_out, int out_size, void* d_ws, size_t ws_size,
                              hipStream_t stream) {
  const float* x_q = (const float*)d_in[0];
  const float* x_c = (const float*)d_in[1];
  const int* edge_q = (const int*)d_in[2];
  const int* edge_c = (const int*)d_in[3];
  const float* gw1 = (const float*)d_in[4];
  const float* gb1 = (const float*)d_in[5];
  const float* gw2 = (const float*)d_in[6];
  const float* gb2 = (const float*)d_in[7];
  const float* gw3 = (const float*)d_in[8];
  const float* gb3 = (const float*)d_in[9];
  const float* cw1 = (const float*)d_in[10];
  const float* cb1 = (const float*)d_in[11];
  const float* cw2 = (const float*)d_in[12];
  const float* cb2 = (const float*)d_in[13];
  const float* cw3 = (const float*)d_in[14];
  const float* cb3 = (const float*)d_in[15];
  const float* lw1 = (const float*)d_in[16];
  const float* lb1 = (const float*)d_in[17];
  const float* lw2 = (const float*)d_in[18];
  const float* lb2 = (const float*)d_in[19];
  const float* swt = (const float*)d_in[20];
  const float* sbs = (const float*)d_in[21];
  float* ws = (float*)d_ws;

  const size_t o_f1q = 65536;
  const size_t o_f2q = o_f1q + 2097152;
  const size_t o_f3q = o_f2q + 1048576;
  const size_t o_f1c = o_f3q + 524288;
  const size_t o_f2c = o_f1c + 2097152;
  const size_t o_f3c = o_f2c + 1048576;
  const size_t o_sims = o_f3c + 524288;       // 6291456 floats
  const size_t o_pm1 = o_sims + 6291456;      // u16 region: 12582912 u16 = 6291456 floats
  const size_t o_pm2 = o_pm1 + 6291456;       // u16 region: 6291456 u16 = 3145728 floats
  const size_t o_feat = o_sims;               // reuse (sims dead after conv1)
  const size_t o_h1 = o_f1q;                  // reuse (f1q dead after sims)

  float* f1q = ws + o_f1q; float* f2q = ws + o_f2q; float* f3q = ws + o_f3q;
  float* f1c = ws + o_f1c; float* f2c = ws + o_f2c; float* f3c = ws + o_f3c;
  float* sims = ws + o_sims;
  u16* pm1 = (u16*)(ws + o_pm1);
  u16* pm2 = (u16*)(ws + o_pm2);
  float* feat = ws + o_feat;
  float* h1 = ws + o_h1;

  gcn_fused<<<dim3(B, 2), 256, 0, stream>>>(x_q, x_c, gw1, gb1, gw2, gb2, gw3, gb3,
                                            edge_q, edge_c, f1q, f1c, f2q, f2c, f3q, f3c);

  sim_kernel<64><<<B, 256, 0, stream>>>(f1q, f1c, sims + 0 * (size_t)B * 4096);
  sim_kernel<32><<<B, 256, 0, stream>>>(f2q, f2c, sims + 1 * (size_t)B * 4096);
  sim_kernel<16><<<B, 256, 0, stream>>>(f3q, f3c, sims + 2 * (size_t)B * 4096);

  conv1_kernel<<<dim3(B, 3), 256, 0, stream>>>(sims, cw1, cb1, pm1);
  conv2_mfma<<<dim3(B, 3), 256, 0, stream>>>(pm1, cw2, cb2, pm2);
  conv3_mfma<<<dim3(B, 3), 256, 0, stream>>>(pm2, cw3, cb3, feat);

  init_h1<<<512, 256, 0, stream>>>(lb1, h1);
  lin1_kernel<<<dim3(8, 4, 16), 256, 0, stream>>>(feat, lw1, h1);
  head_kernel<<<32, 256, 0, stream>>>(h1, lw2, lb2, swt, sbs, (float*)d_out);
}

// Round 5
// 194.300 us; speedup vs baseline: 5.3153x; 1.2028x over previous
//
#include <hip/hip_runtime.h>
#include <hip/hip_bf16.h>

constexpr int B = 512, N = 64, E = 512, NE = B * E;

typedef __attribute__((ext_vector_type(8))) short bf8v;
typedef __attribute__((ext_vector_type(4))) float f32x4;
typedef unsigned short u16;

__device__ __forceinline__ u16 f2bf(float f) {
  unsigned u = __builtin_bit_cast(unsigned, f);
  u += 0x7FFFu + ((u >> 16) & 1u);
  return (u16)(u >> 16);
}

// =================== fused 3-layer GCN (unchanged) ===================
template <int DIN, int DOUT, bool STORE_NEXT>
__device__ __forceinline__ void gcn_layer(
    float* __restrict__ At, float* __restrict__ Xt, float* __restrict__ Hs,
    float* __restrict__ Wls, const float* __restrict__ W,
    const float* __restrict__ bias, float* __restrict__ fout, int g, int t) {
  constexpr int XS = 68;
  for (int i = t; i < DIN * DOUT; i += 256) Wls[i] = W[i];
  __syncthreads();
  constexpr int CT = DOUT / 4;
  const int ct = t % CT, nt = t / CT;
  if (nt < 16) {
    float acc[4][4] = {};
#pragma unroll 4
    for (int k = 0; k < DIN; ++k) {
      float4 xv = *(const float4*)&Xt[k * XS + 4 * nt];
      float4 wv = *(const float4*)&Wls[k * DOUT + 4 * ct];
      float xa[4] = {xv.x, xv.y, xv.z, xv.w};
      float wa[4] = {wv.x, wv.y, wv.z, wv.w};
#pragma unroll
      for (int i = 0; i < 4; ++i)
#pragma unroll
        for (int j = 0; j < 4; ++j) acc[i][j] += xa[i] * wa[j];
    }
#pragma unroll
    for (int i = 0; i < 4; ++i) {
      float4 st = {acc[i][0], acc[i][1], acc[i][2], acc[i][3]};
      *(float4*)&Hs[(4 * nt + i) * XS + 4 * ct] = st;
    }
  }
  __syncthreads();
  if (nt < 16) {
    float acc[4][4] = {};
#pragma unroll 4
    for (int s = 0; s < N; ++s) {
      float4 av = *(const float4*)&At[s * XS + 4 * nt];
      float4 hv = *(const float4*)&Hs[s * XS + 4 * ct];
      float aa[4] = {av.x, av.y, av.z, av.w};
      float ha[4] = {hv.x, hv.y, hv.z, hv.w};
#pragma unroll
      for (int i = 0; i < 4; ++i)
#pragma unroll
        for (int j = 0; j < 4; ++j) acc[i][j] += aa[i] * ha[j];
    }
    const float4 bv = *(const float4*)&bias[4 * ct];
#pragma unroll
    for (int i = 0; i < 4; ++i) {
      float4 st = {acc[i][0] + bv.x, acc[i][1] + bv.y, acc[i][2] + bv.z,
                   acc[i][3] + bv.w};
      *(float4*)&fout[(size_t)g * N * DOUT + (size_t)(4 * nt + i) * DOUT + 4 * ct] = st;
      if (STORE_NEXT) {
        Xt[(4 * ct + 0) * XS + 4 * nt + i] = fmaxf(st.x, 0.f);
        Xt[(4 * ct + 1) * XS + 4 * nt + i] = fmaxf(st.y, 0.f);
        Xt[(4 * ct + 2) * XS + 4 * nt + i] = fmaxf(st.z, 0.f);
        Xt[(4 * ct + 3) * XS + 4 * nt + i] = fmaxf(st.w, 0.f);
      }
    }
  }
  __syncthreads();
}

__global__ __launch_bounds__(256) void gcn_fused(
    const float* __restrict__ xq, const float* __restrict__ xc,
    const float* __restrict__ W1, const float* __restrict__ b1,
    const float* __restrict__ W2, const float* __restrict__ b2,
    const float* __restrict__ W3, const float* __restrict__ b3,
    const int* __restrict__ eq, const int* __restrict__ ec,
    float* __restrict__ f1q, float* __restrict__ f1c,
    float* __restrict__ f2q, float* __restrict__ f2c,
    float* __restrict__ f3q, float* __restrict__ f3c) {
  constexpr int XS = 68;
  __shared__ __align__(16) float At[N * XS];
  __shared__ __align__(16) float Xt[N * XS];
  __shared__ __align__(16) float Hs[N * XS];
  __shared__ __align__(16) float Wls[64 * 32];
  __shared__ float dl[N];
  __shared__ int cnt[N];
  const int g = blockIdx.x, t = threadIdx.x;
  const float* x = blockIdx.y ? xc : xq;
  const int* edges = blockIdx.y ? ec : eq;
  float* o1 = blockIdx.y ? f1c : f1q;
  float* o2 = blockIdx.y ? f2c : f2q;
  float* o3 = blockIdx.y ? f3c : f3q;
  for (int i = t; i < N * 16; i += 256) {
    int n = i / 16, k = i % 16;
    Xt[k * XS + n] = x[(size_t)g * N * 16 + i];
  }
  for (int i = t; i < N * XS; i += 256) At[i] = 0.f;
  if (t < N) cnt[t] = 1;
  __syncthreads();
  const int* srcp = edges + (size_t)g * E;
  const int* dstp = edges + NE + (size_t)g * E;
  for (int j = t; j < E; j += 256) atomicAdd(&cnt[dstp[j] & 63], 1);
  __syncthreads();
  if (t < N) dl[t] = rsqrtf((float)cnt[t]);
  __syncthreads();
  for (int j = t; j < E; j += 256) {
    int s = srcp[j] & 63, d = dstp[j] & 63;
    atomicAdd(&At[s * XS + d], dl[s] * dl[d]);
  }
  if (t < N) atomicAdd(&At[t * XS + t], dl[t] * dl[t]);
  __syncthreads();
  gcn_layer<16, 64, true>(At, Xt, Hs, Wls, W1, b1, o1, g, t);
  gcn_layer<64, 32, true>(At, Xt, Hs, Wls, W2, b2, o2, g, t);
  gcn_layer<32, 16, false>(At, Xt, Hs, Wls, W3, b3, o3, g, t);
}

// =================== similarity (unchanged) ===================
template <int D>
__global__ __launch_bounds__(256) void sim_kernel(const float* __restrict__ fq,
                                                  const float* __restrict__ fc,
                                                  float* __restrict__ so) {
  constexpr int XS = 68;
  __shared__ __align__(16) float Qt[D * XS];
  __shared__ __align__(16) float Ct[D * XS];
  const int b = blockIdx.x, t = threadIdx.x;
  for (int i = t; i < N * D; i += 256) {
    int n = i / D, k = i % D;
    Qt[k * XS + n] = fq[(size_t)b * N * D + i];
    Ct[k * XS + n] = fc[(size_t)b * N * D + i];
  }
  __syncthreads();
  const int ct = t % 16, nt = t / 16;
  float acc[4][4] = {};
#pragma unroll 4
  for (int k = 0; k < D; ++k) {
    float4 qv = *(const float4*)&Qt[k * XS + 4 * nt];
    float4 cv = *(const float4*)&Ct[k * XS + 4 * ct];
    float qa[4] = {qv.x, qv.y, qv.z, qv.w};
    float ca[4] = {cv.x, cv.y, cv.z, cv.w};
#pragma unroll
    for (int i = 0; i < 4; ++i)
#pragma unroll
      for (int j = 0; j < 4; ++j) acc[i][j] += qa[i] * ca[j];
  }
#pragma unroll
  for (int i = 0; i < 4; ++i) {
    float4 st = {acc[i][0], acc[i][1], acc[i][2], acc[i][3]};
    *(float4*)&so[(size_t)b * 4096 + (size_t)(4 * nt + i) * 64 + 4 * ct] = st;
  }
}

// =================== conv1: fp32 VALU, emits bf16 channels-last [32][32][8] ===================
__global__ __launch_bounds__(256) void conv1_kernel(const float* __restrict__ in,
                                                    const float* __restrict__ w,
                                                    const float* __restrict__ bias,
                                                    u16* __restrict__ out) {
  constexpr int S = 64, PS = 68, PSPS = PS * PS;
  __shared__ __align__(16) float ins[PSPS];
  __shared__ float wls[8 * 25];
  __shared__ float bls[8];
  const int b = blockIdx.x, m = blockIdx.y, t = threadIdx.x;
  for (int i = t; i < PSPS; i += 256) ins[i] = 0.f;
  if (t < 200) wls[t] = w[m * 200 + t];
  if (t < 8) bls[t] = bias[m * 8 + t];
  __syncthreads();
  const float* ip = in + (size_t)m * 2097152 + (size_t)b * 4096;
  for (int i = t; i < S * S; i += 256) {
    int y = i >> 6, xx = i & 63;
    ins[(y + 2) * PS + xx + 2] = ip[i];
  }
  __syncthreads();
  const int gy = t >> 4, gx = t & 15;
  float pr[8][8];
#pragma unroll
  for (int yy = 0; yy < 8; ++yy) {
    float4 a = *(const float4*)&ins[(4 * gy + yy) * PS + 4 * gx];
    float4 bb = *(const float4*)&ins[(4 * gy + yy) * PS + 4 * gx + 4];
    pr[yy][0] = a.x; pr[yy][1] = a.y; pr[yy][2] = a.z; pr[yy][3] = a.w;
    pr[yy][4] = bb.x; pr[yy][5] = bb.y; pr[yy][6] = bb.z; pr[yy][7] = bb.w;
  }
  u16* op = out + (size_t)(b * 3 + m) * 8192;
#pragma unroll 1
  for (int oc = 0; oc < 8; ++oc) {
    float acc[16];
#pragma unroll
    for (int p = 0; p < 16; ++p) acc[p] = 0.f;
#pragma unroll
    for (int ky = 0; ky < 5; ++ky)
#pragma unroll
      for (int kx = 0; kx < 5; ++kx) {
        float wv = wls[oc * 25 + ky * 5 + kx];
#pragma unroll
        for (int dy = 0; dy < 4; ++dy)
#pragma unroll
          for (int dx = 0; dx < 4; ++dx) acc[dy * 4 + dx] += pr[ky + dy][kx + dx] * wv;
      }
    float bv = bls[oc];
#pragma unroll
    for (int ay = 0; ay < 2; ++ay)
#pragma unroll
      for (int ax = 0; ax < 2; ++ax) {
        float v = fmaxf(fmaxf(acc[(2 * ay) * 4 + 2 * ax], acc[(2 * ay) * 4 + 2 * ax + 1]),
                        fmaxf(acc[(2 * ay + 1) * 4 + 2 * ax], acc[(2 * ay + 1) * 4 + 2 * ax + 1]));
        v = fmaxf(v + bv, 0.f);
        op[(((2 * gy + ay) * 32) + (2 * gx + ax)) * 8 + oc] = f2bf(v);
      }
  }
}

// =================== conv2: bf16 MFMA (unchanged) ===================
__global__ __launch_bounds__(256) void conv2_mfma(
    const u16* __restrict__ in, const float* __restrict__ w,
    const float* __restrict__ bias, u16* __restrict__ out) {
  constexpr int PW = 36, BS = 40;
  __shared__ __align__(16) u16 ins[PW * PW * 8];
  __shared__ __align__(16) u16 wls[7 * 16 * BS];
  __shared__ float bls[16];
  const int b = blockIdx.x, m = blockIdx.y, t = threadIdx.x;
  const size_t ibase = (size_t)(b * 3 + m) * 8192;
  for (int i = t; i < PW * PW; i += 256) {
    int y = i / PW, x = i % PW;
    uint4 v = {0u, 0u, 0u, 0u};
    if (y >= 2 && y < 34 && x >= 2 && x < 34)
      v = *(const uint4*)&in[ibase + (size_t)((y - 2) * 32 + (x - 2)) * 8];
    *(uint4*)&ins[i * 8] = v;
  }
  for (int i = t; i < 7 * 16 * 32; i += 256) {
    int k = i & 31, oc = (i >> 5) & 15, st = i >> 9;
    int sl = k >> 3, ci = k & 7, tap = st * 4 + sl;
    float v = (tap < 25) ? w[((size_t)(m * 16 + oc) * 8 + ci) * 25 + tap] : 0.f;
    wls[(st * 16 + oc) * BS + k] = f2bf(v);
  }
  if (t < 16) bls[t] = bias[m * 16 + t];
  __syncthreads();
  const int wv = t >> 6, lane = t & 63;
  const int oc = lane & 15, g = lane >> 4;
  const size_t obase = (size_t)(b * 3 + m) * 4096;
#pragma unroll 1
  for (int task = wv; task < 32; task += 4) {
    const int yp = task >> 1, xt = task & 1;
    const int y0 = 2 * yp, x = xt * 16 + oc;
    f32x4 acc0 = {0.f, 0.f, 0.f, 0.f}, acc1 = {0.f, 0.f, 0.f, 0.f};
#pragma unroll
    for (int st = 0; st < 7; ++st) {
      bf8v bvv = *(const bf8v*)&wls[(st * 16 + oc) * BS + g * 8];
      int tp = st * 4 + g; tp = tp > 24 ? 24 : tp;
      int ky = tp / 5, kx = tp % 5;
      bf8v a0 = *(const bf8v*)&ins[(size_t)((y0 + ky) * PW + x + kx) * 8];
      acc0 = __builtin_amdgcn_mfma_f32_16x16x32_bf16(a0, bvv, acc0, 0, 0, 0);
      bf8v a1 = *(const bf8v*)&ins[(size_t)((y0 + 1 + ky) * PW + x + kx) * 8];
      acc1 = __builtin_amdgcn_mfma_f32_16x16x32_bf16(a1, bvv, acc1, 0, 0, 0);
    }
    const float bb = bls[oc];
    const float v0 = fmaxf(fmaxf(fmaxf(acc0[0], acc0[1]), fmaxf(acc1[0], acc1[1])) + bb, 0.f);
    const float v1 = fmaxf(fmaxf(fmaxf(acc0[2], acc0[3]), fmaxf(acc1[2], acc1[3])) + bb, 0.f);
    const int px = xt * 8 + 2 * g;
    out[obase + (size_t)((yp * 16 + px) * 16 + oc)] = f2bf(v0);
    out[obase + (size_t)((yp * 16 + px + 1) * 16 + oc)] = f2bf(v1);
  }
}

// =================== conv3: bf16 MFMA, now writes feat as bf16 ===================
__global__ __launch_bounds__(256) void conv3_mfma(
    const u16* __restrict__ in, const float* __restrict__ w,
    const float* __restrict__ bias, u16* __restrict__ feat) {
  constexpr int PW = 20, BS = 40;
  __shared__ __align__(16) u16 ins[PW * PW * 16];
  __shared__ __align__(16) u16 wls[13 * 2 * 16 * BS];
  __shared__ float bls[32];
  const int b = blockIdx.x, m = blockIdx.y, t = threadIdx.x;
  const size_t ibase = (size_t)(b * 3 + m) * 4096;
  for (int i = t; i < PW * PW; i += 256) {
    int y = i / PW, x = i % PW;
    uint4 v0 = {0u, 0u, 0u, 0u}, v1 = {0u, 0u, 0u, 0u};
    if (y >= 2 && y < 18 && x >= 2 && x < 18) {
      const u16* p = &in[ibase + (size_t)((y - 2) * 16 + (x - 2)) * 16];
      v0 = *(const uint4*)p;
      v1 = *(const uint4*)(p + 8);
    }
    *(uint4*)&ins[i * 16] = v0;
    *(uint4*)&ins[i * 16 + 8] = v1;
  }
  for (int i = t; i < 13 * 2 * 16 * 32; i += 256) {
    int k = i & 31, oc16 = (i >> 5) & 15, half = (i >> 9) & 1, st = i >> 10;
    int sl = k >> 4, ci = k & 15, tap = st * 2 + sl;
    int oc = half * 16 + oc16;
    float v = (tap < 25) ? w[((size_t)(m * 32 + oc) * 16 + ci) * 25 + tap] : 0.f;
    wls[((st * 2 + half) * 16 + oc16) * BS + k] = f2bf(v);
  }
  if (t < 32) bls[t] = bias[m * 32 + t];
  __syncthreads();
  const int wv = t >> 6, lane = t & 63;
  const int oc = lane & 15, g = lane >> 4;
  const int sl = g >> 1, ch = (g & 1) * 8;
  u16* fb = feat + (size_t)b * 6144 + m * 2048;
#pragma unroll 1
  for (int task = wv; task < 16; task += 4) {
    const int yp = task >> 1, half = task & 1;
    const int y0 = 2 * yp, x = oc;
    f32x4 acc0 = {0.f, 0.f, 0.f, 0.f}, acc1 = {0.f, 0.f, 0.f, 0.f};
#pragma unroll
    for (int st = 0; st < 13; ++st) {
      bf8v bvv = *(const bf8v*)&wls[(size_t)((st * 2 + half) * 16 + oc) * BS + g * 8];
      int tp = st * 2 + sl; tp = tp > 24 ? 24 : tp;
      int ky = tp / 5, kx = tp % 5;
      bf8v a0 = *(const bf8v*)&ins[(size_t)((y0 + ky) * PW + x + kx) * 16 + ch];
      acc0 = __builtin_amdgcn_mfma_f32_16x16x32_bf16(a0, bvv, acc0, 0, 0, 0);
      bf8v a1 = *(const bf8v*)&ins[(size_t)((y0 + 1 + ky) * PW + x + kx) * 16 + ch];
      acc1 = __builtin_amdgcn_mfma_f32_16x16x32_bf16(a1, bvv, acc1, 0, 0, 0);
    }
    const int ocg = half * 16 + oc;
    const float bb = bls[ocg];
    const float v0 = fmaxf(fmaxf(fmaxf(acc0[0], acc0[1]), fmaxf(acc1[0], acc1[1])) + bb, 0.f);
    const float v1 = fmaxf(fmaxf(fmaxf(acc0[2], acc0[3]), fmaxf(acc1[2], acc1[3])) + bb, 0.f);
    unsigned pack = (unsigned)f2bf(v0) | ((unsigned)f2bf(v1) << 16);
    *(unsigned*)&fb[ocg * 64 + yp * 8 + 2 * g] = pack;
  }
}

// =================== wcvt: lin_w1 [k][c] fp32 -> wT [c][k] bf16 ===================
__global__ __launch_bounds__(256) void wcvt_kernel(const float* __restrict__ W,
                                                   u16* __restrict__ wT) {
  __shared__ float tile[64][65];
  const int k0 = blockIdx.x * 64, c0 = blockIdx.y * 64, t = threadIdx.x;
  for (int i = t; i < 4096; i += 256) {
    int r = i >> 6, c = i & 63;
    tile[r][c] = W[(size_t)(k0 + r) * 256 + c0 + c];
  }
  __syncthreads();
  for (int i = t; i < 4096; i += 256) {
    int c = i >> 6, k = i & 63;
    wT[(size_t)(c0 + c) * 6144 + k0 + k] = f2bf(tile[k][c]);
  }
}

// =================== lin1: bf16 MFMA GEMM, k-split partials ===================
// grid (8,4,16): 64x64 tile, K-range 384. h1p[ks][512][256] fp32.
__global__ __launch_bounds__(256) void lin1_mfma(const u16* __restrict__ feat,
                                                 const u16* __restrict__ wT,
                                                 float* __restrict__ h1p) {
  constexpr int AS = 72;  // padded u16 row stride
  __shared__ __align__(16) u16 As[64 * AS];
  __shared__ __align__(16) u16 Bs[64 * AS];
  const int r0 = blockIdx.x * 64, c0 = blockIdx.y * 64, kb = blockIdx.z * 384;
  const int t = threadIdx.x;
  const int w = t >> 6, lane = t & 63;
  const int row16 = lane & 15, kg = lane >> 4;
  f32x4 acc[4] = {{0.f, 0.f, 0.f, 0.f}, {0.f, 0.f, 0.f, 0.f},
                  {0.f, 0.f, 0.f, 0.f}, {0.f, 0.f, 0.f, 0.f}};
  const int lr = t >> 2, lk = (t & 3) * 16;
#pragma unroll 1
  for (int st = 0; st < 6; ++st) {
    __syncthreads();
    const int ks = kb + st * 64;
    {
      const u16* srcA = feat + (size_t)(r0 + lr) * 6144 + ks + lk;
      uint4 a0 = *(const uint4*)srcA;
      uint4 a1 = *(const uint4*)(srcA + 8);
      *(uint4*)&As[lr * AS + lk] = a0;
      *(uint4*)&As[lr * AS + lk + 8] = a1;
      const u16* srcB = wT + (size_t)(c0 + lr) * 6144 + ks + lk;
      uint4 b0 = *(const uint4*)srcB;
      uint4 b1 = *(const uint4*)(srcB + 8);
      *(uint4*)&Bs[lr * AS + lk] = b0;
      *(uint4*)&Bs[lr * AS + lk + 8] = b1;
    }
    __syncthreads();
#pragma unroll
    for (int kk = 0; kk < 2; ++kk) {
      bf8v a = *(const bf8v*)&As[(w * 16 + row16) * AS + kk * 32 + kg * 8];
#pragma unroll
      for (int ct = 0; ct < 4; ++ct) {
        bf8v bb = *(const bf8v*)&Bs[(ct * 16 + row16) * AS + kk * 32 + kg * 8];
        acc[ct] = __builtin_amdgcn_mfma_f32_16x16x32_bf16(a, bb, acc[ct], 0, 0, 0);
      }
    }
  }
  float* out = h1p + (size_t)blockIdx.z * 131072;
#pragma unroll
  for (int ct = 0; ct < 4; ++ct)
#pragma unroll
    for (int j = 0; j < 4; ++j)
      out[(size_t)(r0 + w * 16 + kg * 4 + j) * 256 + c0 + ct * 16 + row16] = acc[ct][j];
}

// =================== head: sum k-split partials + bias, then MLP tail ===================
__global__ __launch_bounds__(256) void head_kernel(
    const float* __restrict__ h1p, const float* __restrict__ b1,
    const float* __restrict__ w2, const float* __restrict__ b2,
    const float* __restrict__ sw, const float* __restrict__ sb,
    float* __restrict__ out) {
  constexpr int HS = 260;
  __shared__ __align__(16) float h1s[16 * HS];
  __shared__ __align__(16) float w2s[256 * 16];
  const int r0 = blockIdx.x * 16, t = threadIdx.x;
  for (int i = t; i < 4096; i += 256) {
    int r = i >> 8, k = i & 255;
    float s = b1[k];
#pragma unroll
    for (int p = 0; p < 16; ++p) s += h1p[(size_t)p * 131072 + (size_t)(r0 + r) * 256 + k];
    h1s[r * HS + k] = s;
    w2s[i] = w2[i];
  }
  __syncthreads();
  const int j = t & 15, r = t >> 4;
  float acc = b2[j];
#pragma unroll 4
  for (int k4 = 0; k4 < 64; ++k4) {
    float4 hv = *(const float4*)&h1s[r * HS + 4 * k4];
    float h0 = fmaxf(hv.x, 0.f), h1v = fmaxf(hv.y, 0.f);
    float h2v = fmaxf(hv.z, 0.f), h3 = fmaxf(hv.w, 0.f);
    acc += h0 * w2s[(4 * k4 + 0) * 16 + j];
    acc += h1v * w2s[(4 * k4 + 1) * 16 + j];
    acc += h2v * w2s[(4 * k4 + 2) * 16 + j];
    acc += h3 * w2s[(4 * k4 + 3) * 16 + j];
  }
  float v = fmaxf(acc, 0.f) * sw[j];
#pragma unroll
  for (int off = 8; off; off >>= 1) v += __shfl_xor(v, off, 16);
  if (j == 0) out[r0 + r] = v + sb[0];
}

// =================== launcher ===================
extern "C" void kernel_launch(void* const* d_in, const int* in_sizes, int n_in,
                              void* d_out, int out_size, void* d_ws, size_t ws_size,
                              hipStream_t stream) {
  const float* x_q = (const float*)d_in[0];
  const float* x_c = (const float*)d_in[1];
  const int* edge_q = (const int*)d_in[2];
  const int* edge_c = (const int*)d_in[3];
  const float* gw1 = (const float*)d_in[4];
  const float* gb1 = (const float*)d_in[5];
  const float* gw2 = (const float*)d_in[6];
  const float* gb2 = (const float*)d_in[7];
  const float* gw3 = (const float*)d_in[8];
  const float* gb3 = (const float*)d_in[9];
  const float* cw1 = (const float*)d_in[10];
  const float* cb1 = (const float*)d_in[11];
  const float* cw2 = (const float*)d_in[12];
  const float* cb2 = (const float*)d_in[13];
  const float* cw3 = (const float*)d_in[14];
  const float* cb3 = (const float*)d_in[15];
  const float* lw1 = (const float*)d_in[16];
  const float* lb1 = (const float*)d_in[17];
  const float* lw2 = (const float*)d_in[18];
  const float* lb2 = (const float*)d_in[19];
  const float* swt = (const float*)d_in[20];
  const float* sbs = (const float*)d_in[21];
  float* ws = (float*)d_ws;

  const size_t o_f1q = 65536;                  // later reused as h1p (needs 2097152 exactly)
  const size_t o_f2q = o_f1q + 2097152;
  const size_t o_f3q = o_f2q + 1048576;
  const size_t o_f1c = o_f3q + 524288;
  const size_t o_f2c = o_f1c + 2097152;
  const size_t o_f3c = o_f2c + 1048576;
  const size_t o_sims = o_f3c + 524288;        // 6291456 floats
  const size_t o_pm1 = o_sims + 6291456;       // u16 region
  const size_t o_pm2 = o_pm1 + 6291456;        // u16 region (3145728 floats)
  const size_t o_wT = o_pm2 + 3145728;         // u16 region: 1572864 u16 = 786432 floats
  const size_t o_feat = o_sims;                // reuse (sims dead after conv1), bf16
  const size_t o_h1p = o_f1q;                  // reuse (f1q dead after sims): 16*131072 floats

  float* f1q = ws + o_f1q; float* f2q = ws + o_f2q; float* f3q = ws + o_f3q;
  float* f1c = ws + o_f1c; float* f2c = ws + o_f2c; float* f3c = ws + o_f3c;
  float* sims = ws + o_sims;
  u16* pm1 = (u16*)(ws + o_pm1);
  u16* pm2 = (u16*)(ws + o_pm2);
  u16* wT = (u16*)(ws + o_wT);
  u16* feat = (u16*)(ws + o_feat);
  float* h1p = ws + o_h1p;

  wcvt_kernel<<<dim3(96, 4), 256, 0, stream>>>(lw1, wT);

  gcn_fused<<<dim3(B, 2), 256, 0, stream>>>(x_q, x_c, gw1, gb1, gw2, gb2, gw3, gb3,
                                            edge_q, edge_c, f1q, f1c, f2q, f2c, f3q, f3c);

  sim_kernel<64><<<B, 256, 0, stream>>>(f1q, f1c, sims + 0 * (size_t)B * 4096);
  sim_kernel<32><<<B, 256, 0, stream>>>(f2q, f2c, sims + 1 * (size_t)B * 4096);
  sim_kernel<16><<<B, 256, 0, stream>>>(f3q, f3c, sims + 2 * (size_t)B * 4096);

  conv1_kernel<<<dim3(B, 3), 256, 0, stream>>>(sims, cw1, cb1, pm1);
  conv2_mfma<<<dim3(B, 3), 256, 0, stream>>>(pm1, cw2, cb2, pm2);
  conv3_mfma<<<dim3(B, 3), 256, 0, stream>>>(pm2, cw3, cb3, feat);

  lin1_mfma<<<dim3(8, 4, 16), 256, 0, stream>>>(feat, wT, h1p);
  head_kernel<<<32, 256, 0, stream>>>(h1p, lb1, lw2, lb2, swt, sbs, (float*)d_out);
}

// Round 6
// 192.351 us; speedup vs baseline: 5.3692x; 1.0101x over previous
//
#include <hip/hip_runtime.h>
#include <hip/hip_bf16.h>

constexpr int B = 512, N = 64, E = 512, NE = B * E;

typedef __attribute__((ext_vector_type(8))) short bf8v;
typedef __attribute__((ext_vector_type(4))) float f32x4;
typedef unsigned short u16;

__device__ __forceinline__ u16 f2bf(float f) {
  unsigned u = __builtin_bit_cast(unsigned, f);
  u += 0x7FFFu + ((u >> 16) & 1u);
  return (u16)(u >> 16);
}

// =================== fused 3-layer GCN: 512 threads, 4x2 tiles ===================
template <int DIN, int DOUT, bool STORE_NEXT>
__device__ __forceinline__ void gcn_layer(
    float* __restrict__ At, float* __restrict__ Xt, float* __restrict__ Hs,
    float* __restrict__ Wls, const float* __restrict__ W,
    const float* __restrict__ bias, float* __restrict__ fout, int g, int t) {
  constexpr int XS = 68;
  for (int i = t; i < DIN * DOUT; i += 512) Wls[i] = W[i];
  __syncthreads();
  constexpr int CT = DOUT / 2;  // col-pairs
  const int ct = t % CT, nt = t / CT;
  // matmul1: Hs[n][c] = sum_k Xt[k][n] * Wls[k][c]
  if (nt < 16) {
    float acc[4][2] = {};
#pragma unroll 4
    for (int k = 0; k < DIN; ++k) {
      float4 xv = *(const float4*)&Xt[k * XS + 4 * nt];
      float2 wv = *(const float2*)&Wls[k * DOUT + 2 * ct];
      float xa[4] = {xv.x, xv.y, xv.z, xv.w};
#pragma unroll
      for (int i = 0; i < 4; ++i) {
        acc[i][0] += xa[i] * wv.x;
        acc[i][1] += xa[i] * wv.y;
      }
    }
#pragma unroll
    for (int i = 0; i < 4; ++i)
      *(float2*)&Hs[(4 * nt + i) * XS + 2 * ct] = make_float2(acc[i][0], acc[i][1]);
  }
  __syncthreads();
  // matmul2: out[d][c] = sum_s At[s][d] * Hs[s][c] + bias[c]
  if (nt < 16) {
    float acc[4][2] = {};
#pragma unroll 4
    for (int s = 0; s < N; ++s) {
      float4 av = *(const float4*)&At[s * XS + 4 * nt];
      float2 hv = *(const float2*)&Hs[s * XS + 2 * ct];
      float aa[4] = {av.x, av.y, av.z, av.w};
#pragma unroll
      for (int i = 0; i < 4; ++i) {
        acc[i][0] += aa[i] * hv.x;
        acc[i][1] += aa[i] * hv.y;
      }
    }
    const float2 bv = *(const float2*)&bias[2 * ct];
#pragma unroll
    for (int i = 0; i < 4; ++i) {
      float2 st = make_float2(acc[i][0] + bv.x, acc[i][1] + bv.y);
      *(float2*)&fout[(size_t)g * N * DOUT + (size_t)(4 * nt + i) * DOUT + 2 * ct] = st;
      if (STORE_NEXT) {
        Xt[(2 * ct + 0) * XS + 4 * nt + i] = fmaxf(st.x, 0.f);
        Xt[(2 * ct + 1) * XS + 4 * nt + i] = fmaxf(st.y, 0.f);
      }
    }
  }
  __syncthreads();
}

__global__ __launch_bounds__(512) void gcn_fused(
    const float* __restrict__ xq, const float* __restrict__ xc,
    const float* __restrict__ W1, const float* __restrict__ b1,
    const float* __restrict__ W2, const float* __restrict__ b2,
    const float* __restrict__ W3, const float* __restrict__ b3,
    const int* __restrict__ eq, const int* __restrict__ ec,
    float* __restrict__ f1q, float* __restrict__ f1c,
    float* __restrict__ f2q, float* __restrict__ f2c,
    float* __restrict__ f3q, float* __restrict__ f3c) {
  constexpr int XS = 68;
  __shared__ __align__(16) float At[N * XS];
  __shared__ __align__(16) float Xt[N * XS];
  __shared__ __align__(16) float Hs[N * XS];
  __shared__ __align__(16) float Wls[64 * 32];
  __shared__ float dl[N];
  __shared__ int cnt[N];
  const int g = blockIdx.x, t = threadIdx.x;
  const float* x = blockIdx.y ? xc : xq;
  const int* edges = blockIdx.y ? ec : eq;
  float* o1 = blockIdx.y ? f1c : f1q;
  float* o2 = blockIdx.y ? f2c : f2q;
  float* o3 = blockIdx.y ? f3c : f3q;
  for (int i = t; i < N * 16; i += 512) {
    int n = i / 16, k = i % 16;
    Xt[k * XS + n] = x[(size_t)g * N * 16 + i];
  }
  for (int i = t; i < N * XS; i += 512) At[i] = 0.f;
  if (t < N) cnt[t] = 1;
  __syncthreads();
  const int* srcp = edges + (size_t)g * E;
  const int* dstp = edges + NE + (size_t)g * E;
  for (int j = t; j < E; j += 512) atomicAdd(&cnt[dstp[j] & 63], 1);
  __syncthreads();
  if (t < N) dl[t] = rsqrtf((float)cnt[t]);
  __syncthreads();
  for (int j = t; j < E; j += 512) {
    int s = srcp[j] & 63, d = dstp[j] & 63;
    atomicAdd(&At[s * XS + d], dl[s] * dl[d]);
  }
  if (t < N) atomicAdd(&At[t * XS + t], dl[t] * dl[t]);
  __syncthreads();
  gcn_layer<16, 64, true>(At, Xt, Hs, Wls, W1, b1, o1, g, t);
  gcn_layer<64, 32, true>(At, Xt, Hs, Wls, W2, b2, o2, g, t);
  gcn_layer<32, 16, false>(At, Xt, Hs, Wls, W3, b3, o3, g, t);
}

// =================== similarity: one kernel for all 3 scales ===================
template <int D>
__device__ __forceinline__ void sim_body(const float* __restrict__ fq,
                                         const float* __restrict__ fc,
                                         float* __restrict__ so,
                                         float* __restrict__ sh, int b, int t) {
  constexpr int XS = 68;
  float* Qt = sh;
  float* Ct = sh + D * XS;
  for (int i = t; i < N * D; i += 256) {
    int n = i / D, k = i % D;
    Qt[k * XS + n] = fq[(size_t)b * N * D + i];
    Ct[k * XS + n] = fc[(size_t)b * N * D + i];
  }
  __syncthreads();
  const int ct = t % 16, nt = t / 16;
  float acc[4][4] = {};
#pragma unroll 4
  for (int k = 0; k < D; ++k) {
    float4 qv = *(const float4*)&Qt[k * XS + 4 * nt];
    float4 cv = *(const float4*)&Ct[k * XS + 4 * ct];
    float qa[4] = {qv.x, qv.y, qv.z, qv.w};
    float ca[4] = {cv.x, cv.y, cv.z, cv.w};
#pragma unroll
    for (int i = 0; i < 4; ++i)
#pragma unroll
      for (int j = 0; j < 4; ++j) acc[i][j] += qa[i] * ca[j];
  }
#pragma unroll
  for (int i = 0; i < 4; ++i) {
    float4 st = {acc[i][0], acc[i][1], acc[i][2], acc[i][3]};
    *(float4*)&so[(size_t)b * 4096 + (size_t)(4 * nt + i) * 64 + 4 * ct] = st;
  }
}

__global__ __launch_bounds__(256) void sim_all(
    const float* __restrict__ f1q, const float* __restrict__ f1c,
    const float* __restrict__ f2q, const float* __restrict__ f2c,
    const float* __restrict__ f3q, const float* __restrict__ f3c,
    float* __restrict__ sims) {
  __shared__ __align__(16) float sh[2 * 64 * 68];
  const int b = blockIdx.x, t = threadIdx.x;
  if (blockIdx.y == 0)
    sim_body<64>(f1q, f1c, sims, sh, b, t);
  else if (blockIdx.y == 1)
    sim_body<32>(f2q, f2c, sims + (size_t)B * 4096, sh, b, t);
  else
    sim_body<16>(f3q, f3c, sims + 2 * (size_t)B * 4096, sh, b, t);
}

// =================== conv1: fp32 VALU, oc-quad per block, bf16 channels-last out ===================
// grid (B, 3, 2)
__global__ __launch_bounds__(256) void conv1_kernel(const float* __restrict__ in,
                                                    const float* __restrict__ w,
                                                    const float* __restrict__ bias,
                                                    u16* __restrict__ out) {
  constexpr int S = 64, PS = 68, PSPS = PS * PS;
  __shared__ __align__(16) float ins[PSPS];
  __shared__ __align__(16) float wls[25][4];
  __shared__ float bls[4];
  const int b = blockIdx.x, m = blockIdx.y, z = blockIdx.z, t = threadIdx.x;
  for (int i = t; i < PSPS; i += 256) ins[i] = 0.f;
  if (t < 100) {
    int tap = t >> 2, o = t & 3;
    wls[tap][o] = w[m * 200 + (z * 4 + o) * 25 + tap];
  }
  if (t < 4) bls[t] = bias[m * 8 + z * 4 + t];
  __syncthreads();
  const float* ip = in + (size_t)m * 2097152 + (size_t)b * 4096;
  for (int i = t; i < S * S; i += 256) {
    int y = i >> 6, xx = i & 63;
    ins[(y + 2) * PS + xx + 2] = ip[i];
  }
  __syncthreads();
  const int gy = t >> 4, gx = t & 15;
  float acc[4][16] = {};
#pragma unroll
  for (int ky = 0; ky < 5; ++ky) {
    float rows[4][8];
#pragma unroll
    for (int dy = 0; dy < 4; ++dy) {
      const float* rp = &ins[(4 * gy + ky + dy) * PS + 4 * gx];
      float4 a = *(const float4*)rp;
      float4 bq = *(const float4*)(rp + 4);
      rows[dy][0] = a.x; rows[dy][1] = a.y; rows[dy][2] = a.z; rows[dy][3] = a.w;
      rows[dy][4] = bq.x; rows[dy][5] = bq.y; rows[dy][6] = bq.z; rows[dy][7] = bq.w;
    }
#pragma unroll
    for (int kx = 0; kx < 5; ++kx) {
      float4 wv = *(const float4*)&wls[ky * 5 + kx][0];
#pragma unroll
      for (int dy = 0; dy < 4; ++dy)
#pragma unroll
        for (int dx = 0; dx < 4; ++dx) {
          float rv = rows[dy][kx + dx];
          acc[0][dy * 4 + dx] += rv * wv.x;
          acc[1][dy * 4 + dx] += rv * wv.y;
          acc[2][dy * 4 + dx] += rv * wv.z;
          acc[3][dy * 4 + dx] += rv * wv.w;
        }
    }
  }
  u16* op = out + (size_t)(b * 3 + m) * 8192;
#pragma unroll
  for (int ay = 0; ay < 2; ++ay)
#pragma unroll
    for (int ax = 0; ax < 2; ++ax) {
      u16 pk[4];
#pragma unroll
      for (int o = 0; o < 4; ++o) {
        float v = fmaxf(fmaxf(acc[o][(2 * ay) * 4 + 2 * ax], acc[o][(2 * ay) * 4 + 2 * ax + 1]),
                        fmaxf(acc[o][(2 * ay + 1) * 4 + 2 * ax], acc[o][(2 * ay + 1) * 4 + 2 * ax + 1]));
        v = fmaxf(v + bls[o], 0.f);
        pk[o] = f2bf(v);
      }
      uint2 u;
      u.x = (unsigned)pk[0] | ((unsigned)pk[1] << 16);
      u.y = (unsigned)pk[2] | ((unsigned)pk[3] << 16);
      *(uint2*)&op[(size_t)(((2 * gy + ay) * 32) + (2 * gx + ax)) * 8 + z * 4] = u;
    }
}

// =================== conv2: bf16 MFMA (unchanged) ===================
__global__ __launch_bounds__(256) void conv2_mfma(
    const u16* __restrict__ in, const float* __restrict__ w,
    const float* __restrict__ bias, u16* __restrict__ out) {
  constexpr int PW = 36, BS = 40;
  __shared__ __align__(16) u16 ins[PW * PW * 8];
  __shared__ __align__(16) u16 wls[7 * 16 * BS];
  __shared__ float bls[16];
  const int b = blockIdx.x, m = blockIdx.y, t = threadIdx.x;
  const size_t ibase = (size_t)(b * 3 + m) * 8192;
  for (int i = t; i < PW * PW; i += 256) {
    int y = i / PW, x = i % PW;
    uint4 v = {0u, 0u, 0u, 0u};
    if (y >= 2 && y < 34 && x >= 2 && x < 34)
      v = *(const uint4*)&in[ibase + (size_t)((y - 2) * 32 + (x - 2)) * 8];
    *(uint4*)&ins[i * 8] = v;
  }
  for (int i = t; i < 7 * 16 * 32; i += 256) {
    int k = i & 31, oc = (i >> 5) & 15, st = i >> 9;
    int sl = k >> 3, ci = k & 7, tap = st * 4 + sl;
    float v = (tap < 25) ? w[((size_t)(m * 16 + oc) * 8 + ci) * 25 + tap] : 0.f;
    wls[(st * 16 + oc) * BS + k] = f2bf(v);
  }
  if (t < 16) bls[t] = bias[m * 16 + t];
  __syncthreads();
  const int wv = t >> 6, lane = t & 63;
  const int oc = lane & 15, g = lane >> 4;
  const size_t obase = (size_t)(b * 3 + m) * 4096;
#pragma unroll 1
  for (int task = wv; task < 32; task += 4) {
    const int yp = task >> 1, xt = task & 1;
    const int y0 = 2 * yp, x = xt * 16 + oc;
    f32x4 acc0 = {0.f, 0.f, 0.f, 0.f}, acc1 = {0.f, 0.f, 0.f, 0.f};
#pragma unroll
    for (int st = 0; st < 7; ++st) {
      bf8v bvv = *(const bf8v*)&wls[(st * 16 + oc) * BS + g * 8];
      int tp = st * 4 + g; tp = tp > 24 ? 24 : tp;
      int ky = tp / 5, kx = tp % 5;
      bf8v a0 = *(const bf8v*)&ins[(size_t)((y0 + ky) * PW + x + kx) * 8];
      acc0 = __builtin_amdgcn_mfma_f32_16x16x32_bf16(a0, bvv, acc0, 0, 0, 0);
      bf8v a1 = *(const bf8v*)&ins[(size_t)((y0 + 1 + ky) * PW + x + kx) * 8];
      acc1 = __builtin_amdgcn_mfma_f32_16x16x32_bf16(a1, bvv, acc1, 0, 0, 0);
    }
    const float bb = bls[oc];
    const float v0 = fmaxf(fmaxf(fmaxf(acc0[0], acc0[1]), fmaxf(acc1[0], acc1[1])) + bb, 0.f);
    const float v1 = fmaxf(fmaxf(fmaxf(acc0[2], acc0[3]), fmaxf(acc1[2], acc1[3])) + bb, 0.f);
    const int px = xt * 8 + 2 * g;
    out[obase + (size_t)((yp * 16 + px) * 16 + oc)] = f2bf(v0);
    out[obase + (size_t)((yp * 16 + px + 1) * 16 + oc)] = f2bf(v1);
  }
}

// =================== conv3: bf16 MFMA, writes feat bf16 (unchanged) ===================
__global__ __launch_bounds__(256) void conv3_mfma(
    const u16* __restrict__ in, const float* __restrict__ w,
    const float* __restrict__ bias, u16* __restrict__ feat) {
  constexpr int PW = 20, BS = 40;
  __shared__ __align__(16) u16 ins[PW * PW * 16];
  __shared__ __align__(16) u16 wls[13 * 2 * 16 * BS];
  __shared__ float bls[32];
  const int b = blockIdx.x, m = blockIdx.y, t = threadIdx.x;
  const size_t ibase = (size_t)(b * 3 + m) * 4096;
  for (int i = t; i < PW * PW; i += 256) {
    int y = i / PW, x = i % PW;
    uint4 v0 = {0u, 0u, 0u, 0u}, v1 = {0u, 0u, 0u, 0u};
    if (y >= 2 && y < 18 && x >= 2 && x < 18) {
      const u16* p = &in[ibase + (size_t)((y - 2) * 16 + (x - 2)) * 16];
      v0 = *(const uint4*)p;
      v1 = *(const uint4*)(p + 8);
    }
    *(uint4*)&ins[i * 16] = v0;
    *(uint4*)&ins[i * 16 + 8] = v1;
  }
  for (int i = t; i < 13 * 2 * 16 * 32; i += 256) {
    int k = i & 31, oc16 = (i >> 5) & 15, half = (i >> 9) & 1, st = i >> 10;
    int sl = k >> 4, ci = k & 15, tap = st * 2 + sl;
    int oc = half * 16 + oc16;
    float v = (tap < 25) ? w[((size_t)(m * 32 + oc) * 16 + ci) * 25 + tap] : 0.f;
    wls[((st * 2 + half) * 16 + oc16) * BS + k] = f2bf(v);
  }
  if (t < 32) bls[t] = bias[m * 32 + t];
  __syncthreads();
  const int wv = t >> 6, lane = t & 63;
  const int oc = lane & 15, g = lane >> 4;
  const int sl = g >> 1, ch = (g & 1) * 8;
  u16* fb = feat + (size_t)b * 6144 + m * 2048;
#pragma unroll 1
  for (int task = wv; task < 16; task += 4) {
    const int yp = task >> 1, half = task & 1;
    const int y0 = 2 * yp, x = oc;
    f32x4 acc0 = {0.f, 0.f, 0.f, 0.f}, acc1 = {0.f, 0.f, 0.f, 0.f};
#pragma unroll
    for (int st = 0; st < 13; ++st) {
      bf8v bvv = *(const bf8v*)&wls[(size_t)((st * 2 + half) * 16 + oc) * BS + g * 8];
      int tp = st * 2 + sl; tp = tp > 24 ? 24 : tp;
      int ky = tp / 5, kx = tp % 5;
      bf8v a0 = *(const bf8v*)&ins[(size_t)((y0 + ky) * PW + x + kx) * 16 + ch];
      acc0 = __builtin_amdgcn_mfma_f32_16x16x32_bf16(a0, bvv, acc0, 0, 0, 0);
      bf8v a1 = *(const bf8v*)&ins[(size_t)((y0 + 1 + ky) * PW + x + kx) * 16 + ch];
      acc1 = __builtin_amdgcn_mfma_f32_16x16x32_bf16(a1, bvv, acc1, 0, 0, 0);
    }
    const int ocg = half * 16 + oc;
    const float bb = bls[ocg];
    const float v0 = fmaxf(fmaxf(fmaxf(acc0[0], acc0[1]), fmaxf(acc1[0], acc1[1])) + bb, 0.f);
    const float v1 = fmaxf(fmaxf(fmaxf(acc0[2], acc0[3]), fmaxf(acc1[2], acc1[3])) + bb, 0.f);
    unsigned pack = (unsigned)f2bf(v0) | ((unsigned)f2bf(v1) << 16);
    *(unsigned*)&fb[ocg * 64 + yp * 8 + 2 * g] = pack;
  }
}

// =================== wcvt (unchanged) ===================
__global__ __launch_bounds__(256) void wcvt_kernel(const float* __restrict__ W,
                                                   u16* __restrict__ wT) {
  __shared__ float tile[64][65];
  const int k0 = blockIdx.x * 64, c0 = blockIdx.y * 64, t = threadIdx.x;
  for (int i = t; i < 4096; i += 256) {
    int r = i >> 6, c = i & 63;
    tile[r][c] = W[(size_t)(k0 + r) * 256 + c0 + c];
  }
  __syncthreads();
  for (int i = t; i < 4096; i += 256) {
    int c = i >> 6, k = i & 63;
    wT[(size_t)(c0 + c) * 6144 + k0 + k] = f2bf(tile[k][c]);
  }
}

// =================== lin1: bf16 MFMA GEMM (unchanged) ===================
__global__ __launch_bounds__(256) void lin1_mfma(const u16* __restrict__ feat,
                                                 const u16* __restrict__ wT,
                                                 float* __restrict__ h1p) {
  constexpr int AS = 72;
  __shared__ __align__(16) u16 As[64 * AS];
  __shared__ __align__(16) u16 Bs[64 * AS];
  const int r0 = blockIdx.x * 64, c0 = blockIdx.y * 64, kb = blockIdx.z * 384;
  const int t = threadIdx.x;
  const int w = t >> 6, lane = t & 63;
  const int row16 = lane & 15, kg = lane >> 4;
  f32x4 acc[4] = {{0.f, 0.f, 0.f, 0.f}, {0.f, 0.f, 0.f, 0.f},
                  {0.f, 0.f, 0.f, 0.f}, {0.f, 0.f, 0.f, 0.f}};
  const int lr = t >> 2, lk = (t & 3) * 16;
#pragma unroll 1
  for (int st = 0; st < 6; ++st) {
    __syncthreads();
    const int ks = kb + st * 64;
    {
      const u16* srcA = feat + (size_t)(r0 + lr) * 6144 + ks + lk;
      uint4 a0 = *(const uint4*)srcA;
      uint4 a1 = *(const uint4*)(srcA + 8);
      *(uint4*)&As[lr * AS + lk] = a0;
      *(uint4*)&As[lr * AS + lk + 8] = a1;
      const u16* srcB = wT + (size_t)(c0 + lr) * 6144 + ks + lk;
      uint4 b0 = *(const uint4*)srcB;
      uint4 b1 = *(const uint4*)(srcB + 8);
      *(uint4*)&Bs[lr * AS + lk] = b0;
      *(uint4*)&Bs[lr * AS + lk + 8] = b1;
    }
    __syncthreads();
#pragma unroll
    for (int kk = 0; kk < 2; ++kk) {
      bf8v a = *(const bf8v*)&As[(w * 16 + row16) * AS + kk * 32 + kg * 8];
#pragma unroll
      for (int ct = 0; ct < 4; ++ct) {
        bf8v bb = *(const bf8v*)&Bs[(ct * 16 + row16) * AS + kk * 32 + kg * 8];
        acc[ct] = __builtin_amdgcn_mfma_f32_16x16x32_bf16(a, bb, acc[ct], 0, 0, 0);
      }
    }
  }
  float* out = h1p + (size_t)blockIdx.z * 131072;
#pragma unroll
  for (int ct = 0; ct < 4; ++ct)
#pragma unroll
    for (int j = 0; j < 4; ++j)
      out[(size_t)(r0 + w * 16 + kg * 4 + j) * 256 + c0 + ct * 16 + row16] = acc[ct][j];
}

// =================== head (unchanged) ===================
__global__ __launch_bounds__(256) void head_kernel(
    const float* __restrict__ h1p, const float* __restrict__ b1,
    const float* __restrict__ w2, const float* __restrict__ b2,
    const float* __restrict__ sw, const float* __restrict__ sb,
    float* __restrict__ out) {
  constexpr int HS = 260;
  __shared__ __align__(16) float h1s[16 * HS];
  __shared__ __align__(16) float w2s[256 * 16];
  const int r0 = blockIdx.x * 16, t = threadIdx.x;
  for (int i = t; i < 4096; i += 256) {
    int r = i >> 8, k = i & 255;
    float s = b1[k];
#pragma unroll
    for (int p = 0; p < 16; ++p) s += h1p[(size_t)p * 131072 + (size_t)(r0 + r) * 256 + k];
    h1s[r * HS + k] = s;
    w2s[i] = w2[i];
  }
  __syncthreads();
  const int j = t & 15, r = t >> 4;
  float acc = b2[j];
#pragma unroll 4
  for (int k4 = 0; k4 < 64; ++k4) {
    float4 hv = *(const float4*)&h1s[r * HS + 4 * k4];
    float h0 = fmaxf(hv.x, 0.f), h1v = fmaxf(hv.y, 0.f);
    float h2v = fmaxf(hv.z, 0.f), h3 = fmaxf(hv.w, 0.f);
    acc += h0 * w2s[(4 * k4 + 0) * 16 + j];
    acc += h1v * w2s[(4 * k4 + 1) * 16 + j];
    acc += h2v * w2s[(4 * k4 + 2) * 16 + j];
    acc += h3 * w2s[(4 * k4 + 3) * 16 + j];
  }
  float v = fmaxf(acc, 0.f) * sw[j];
#pragma unroll
  for (int off = 8; off; off >>= 1) v += __shfl_xor(v, off, 16);
  if (j == 0) out[r0 + r] = v + sb[0];
}

// =================== launcher ===================
extern "C" void kernel_launch(void* const* d_in, const int* in_sizes, int n_in,
                              void* d_out, int out_size, void* d_ws, size_t ws_size,
                              hipStream_t stream) {
  const float* x_q = (const float*)d_in[0];
  const float* x_c = (const float*)d_in[1];
  const int* edge_q = (const int*)d_in[2];
  const int* edge_c = (const int*)d_in[3];
  const float* gw1 = (const float*)d_in[4];
  const float* gb1 = (const float*)d_in[5];
  const float* gw2 = (const float*)d_in[6];
  const float* gb2 = (const float*)d_in[7];
  const float* gw3 = (const float*)d_in[8];
  const float* gb3 = (const float*)d_in[9];
  const float* cw1 = (const float*)d_in[10];
  const float* cb1 = (const float*)d_in[11];
  const float* cw2 = (const float*)d_in[12];
  const float* cb2 = (const float*)d_in[13];
  const float* cw3 = (const float*)d_in[14];
  const float* cb3 = (const float*)d_in[15];
  const float* lw1 = (const float*)d_in[16];
  const float* lb1 = (const float*)d_in[17];
  const float* lw2 = (const float*)d_in[18];
  const float* lb2 = (const float*)d_in[19];
  const float* swt = (const float*)d_in[20];
  const float* sbs = (const float*)d_in[21];
  float* ws = (float*)d_ws;

  const size_t o_f1q = 65536;
  const size_t o_f2q = o_f1q + 2097152;
  const size_t o_f3q = o_f2q + 1048576;
  const size_t o_f1c = o_f3q + 524288;
  const size_t o_f2c = o_f1c + 2097152;
  const size_t o_f3c = o_f2c + 1048576;
  const size_t o_sims = o_f3c + 524288;
  const size_t o_pm1 = o_sims + 6291456;
  const size_t o_pm2 = o_pm1 + 6291456;
  const size_t o_wT = o_pm2 + 3145728;
  const size_t o_feat = o_sims;   // reuse (sims dead after conv1), bf16
  const size_t o_h1p = o_f1q;     // reuse (f1q dead after sims)

  float* f1q = ws + o_f1q; float* f2q = ws + o_f2q; float* f3q = ws + o_f3q;
  float* f1c = ws + o_f1c; float* f2c = ws + o_f2c; float* f3c = ws + o_f3c;
  float* sims = ws + o_sims;
  u16* pm1 = (u16*)(ws + o_pm1);
  u16* pm2 = (u16*)(ws + o_pm2);
  u16* wT = (u16*)(ws + o_wT);
  u16* feat = (u16*)(ws + o_feat);
  float* h1p = ws + o_h1p;

  wcvt_kernel<<<dim3(96, 4), 256, 0, stream>>>(lw1, wT);

  gcn_fused<<<dim3(B, 2), 512, 0, stream>>>(x_q, x_c, gw1, gb1, gw2, gb2, gw3, gb3,
                                            edge_q, edge_c, f1q, f1c, f2q, f2c, f3q, f3c);

  sim_all<<<dim3(B, 3), 256, 0, stream>>>(f1q, f1c, f2q, f2c, f3q, f3c, sims);

  conv1_kernel<<<dim3(B, 3, 2), 256, 0, stream>>>(sims, cw1, cb1, pm1);
  conv2_mfma<<<dim3(B, 3), 256, 0, stream>>>(pm1, cw2, cb2, pm2);
  conv3_mfma<<<dim3(B, 3), 256, 0, stream>>>(pm2, cw3, cb3, feat);

  lin1_mfma<<<dim3(8, 4, 16), 256, 0, stream>>>(feat, wT, h1p);
  head_kernel<<<32, 256, 0, stream>>>(h1p, lb1, lw2, lb2, swt, sbs, (float*)d_out);
}

// Round 7
// 179.134 us; speedup vs baseline: 5.7653x; 1.0738x over previous
//
#include <hip/hip_runtime.h>
#include <hip/hip_bf16.h>

constexpr int B = 512, N = 64, E = 512, NE = B * E;

typedef __attribute__((ext_vector_type(8))) short bf8v;
typedef __attribute__((ext_vector_type(4))) float f32x4;
typedef unsigned short u16;

__device__ __forceinline__ u16 f2bf(float f) {
  unsigned u = __builtin_bit_cast(unsigned, f);
  u += 0x7FFFu + ((u >> 16) & 1u);
  return (u16)(u >> 16);
}

// =================== fused 3-layer GCN: 512 threads (unchanged) ===================
template <int DIN, int DOUT, bool STORE_NEXT>
__device__ __forceinline__ void gcn_layer(
    float* __restrict__ At, float* __restrict__ Xt, float* __restrict__ Hs,
    float* __restrict__ Wls, const float* __restrict__ W,
    const float* __restrict__ bias, float* __restrict__ fout, int g, int t) {
  constexpr int XS = 68;
  for (int i = t; i < DIN * DOUT; i += 512) Wls[i] = W[i];
  __syncthreads();
  constexpr int CT = DOUT / 2;  // col-pairs
  const int ct = t % CT, nt = t / CT;
  if (nt < 16) {
    float acc[4][2] = {};
#pragma unroll 4
    for (int k = 0; k < DIN; ++k) {
      float4 xv = *(const float4*)&Xt[k * XS + 4 * nt];
      float2 wv = *(const float2*)&Wls[k * DOUT + 2 * ct];
      float xa[4] = {xv.x, xv.y, xv.z, xv.w};
#pragma unroll
      for (int i = 0; i < 4; ++i) {
        acc[i][0] += xa[i] * wv.x;
        acc[i][1] += xa[i] * wv.y;
      }
    }
#pragma unroll
    for (int i = 0; i < 4; ++i)
      *(float2*)&Hs[(4 * nt + i) * XS + 2 * ct] = make_float2(acc[i][0], acc[i][1]);
  }
  __syncthreads();
  if (nt < 16) {
    float acc[4][2] = {};
#pragma unroll 4
    for (int s = 0; s < N; ++s) {
      float4 av = *(const float4*)&At[s * XS + 4 * nt];
      float2 hv = *(const float2*)&Hs[s * XS + 2 * ct];
      float aa[4] = {av.x, av.y, av.z, av.w};
#pragma unroll
      for (int i = 0; i < 4; ++i) {
        acc[i][0] += aa[i] * hv.x;
        acc[i][1] += aa[i] * hv.y;
      }
    }
    const float2 bv = *(const float2*)&bias[2 * ct];
#pragma unroll
    for (int i = 0; i < 4; ++i) {
      float2 st = make_float2(acc[i][0] + bv.x, acc[i][1] + bv.y);
      *(float2*)&fout[(size_t)g * N * DOUT + (size_t)(4 * nt + i) * DOUT + 2 * ct] = st;
      if (STORE_NEXT) {
        Xt[(2 * ct + 0) * XS + 4 * nt + i] = fmaxf(st.x, 0.f);
        Xt[(2 * ct + 1) * XS + 4 * nt + i] = fmaxf(st.y, 0.f);
      }
    }
  }
  __syncthreads();
}

__global__ __launch_bounds__(512) void gcn_fused(
    const float* __restrict__ xq, const float* __restrict__ xc,
    const float* __restrict__ W1, const float* __restrict__ b1,
    const float* __restrict__ W2, const float* __restrict__ b2,
    const float* __restrict__ W3, const float* __restrict__ b3,
    const int* __restrict__ eq, const int* __restrict__ ec,
    float* __restrict__ f1q, float* __restrict__ f1c,
    float* __restrict__ f2q, float* __restrict__ f2c,
    float* __restrict__ f3q, float* __restrict__ f3c) {
  constexpr int XS = 68;
  __shared__ __align__(16) float At[N * XS];
  __shared__ __align__(16) float Xt[N * XS];
  __shared__ __align__(16) float Hs[N * XS];
  __shared__ __align__(16) float Wls[64 * 32];
  __shared__ float dl[N];
  __shared__ int cnt[N];
  const int g = blockIdx.x, t = threadIdx.x;
  const float* x = blockIdx.y ? xc : xq;
  const int* edges = blockIdx.y ? ec : eq;
  float* o1 = blockIdx.y ? f1c : f1q;
  float* o2 = blockIdx.y ? f2c : f2q;
  float* o3 = blockIdx.y ? f3c : f3q;
  for (int i = t; i < N * 16; i += 512) {
    int n = i / 16, k = i % 16;
    Xt[k * XS + n] = x[(size_t)g * N * 16 + i];
  }
  for (int i = t; i < N * XS; i += 512) At[i] = 0.f;
  if (t < N) cnt[t] = 1;
  __syncthreads();
  const int* srcp = edges + (size_t)g * E;
  const int* dstp = edges + NE + (size_t)g * E;
  for (int j = t; j < E; j += 512) atomicAdd(&cnt[dstp[j] & 63], 1);
  __syncthreads();
  if (t < N) dl[t] = rsqrtf((float)cnt[t]);
  __syncthreads();
  for (int j = t; j < E; j += 512) {
    int s = srcp[j] & 63, d = dstp[j] & 63;
    atomicAdd(&At[s * XS + d], dl[s] * dl[d]);
  }
  if (t < N) atomicAdd(&At[t * XS + t], dl[t] * dl[t]);
  __syncthreads();
  gcn_layer<16, 64, true>(At, Xt, Hs, Wls, W1, b1, o1, g, t);
  gcn_layer<64, 32, true>(At, Xt, Hs, Wls, W2, b2, o2, g, t);
  gcn_layer<32, 16, false>(At, Xt, Hs, Wls, W3, b3, o3, g, t);
}

// =================== fused sim + conv1: sim in LDS, conv reads LDS ===================
template <int D>
__device__ __forceinline__ void sim_phase(const float* __restrict__ fq,
                                          const float* __restrict__ fc,
                                          float* __restrict__ Qt,
                                          float* __restrict__ Ct,
                                          float* __restrict__ simp, int b, int t) {
  constexpr int XS = 68;
  for (int i = t; i < N * D; i += 256) {
    int n = i / D, k = i % D;
    Qt[k * XS + n] = fq[(size_t)b * N * D + i];
    Ct[k * XS + n] = fc[(size_t)b * N * D + i];
  }
  __syncthreads();  // also covers simp zero-fill done before call
  const int ct = t % 16, nt = t / 16;
  float acc[4][4] = {};
#pragma unroll 4
  for (int k = 0; k < D; ++k) {
    float4 qv = *(const float4*)&Qt[k * XS + 4 * nt];
    float4 cv = *(const float4*)&Ct[k * XS + 4 * ct];
    float qa[4] = {qv.x, qv.y, qv.z, qv.w};
    float ca[4] = {cv.x, cv.y, cv.z, cv.w};
#pragma unroll
    for (int i = 0; i < 4; ++i)
#pragma unroll
      for (int j = 0; j < 4; ++j) acc[i][j] += qa[i] * ca[j];
  }
  // write into padded LDS image: image (n,m) -> simp[(n+2)*68 + (m+2)]
#pragma unroll
  for (int i = 0; i < 4; ++i) {
    *(float2*)&simp[(4 * nt + i + 2) * 68 + 4 * ct + 2] = make_float2(acc[i][0], acc[i][1]);
    *(float2*)&simp[(4 * nt + i + 2) * 68 + 4 * ct + 4] = make_float2(acc[i][2], acc[i][3]);
  }
}

__global__ __launch_bounds__(256) void simconv1(
    const float* __restrict__ f1q, const float* __restrict__ f1c,
    const float* __restrict__ f2q, const float* __restrict__ f2c,
    const float* __restrict__ f3q, const float* __restrict__ f3c,
    const float* __restrict__ w, const float* __restrict__ bias,
    u16* __restrict__ out) {
  constexpr int PS = 68;
  __shared__ __align__(16) float QtCt[2 * 64 * 68];
  __shared__ __align__(16) float simp[68 * 68];
  __shared__ float wls[200];
  __shared__ float bls[8];
  const int b = blockIdx.x, m = blockIdx.y, t = threadIdx.x;
  for (int i = t; i < 68 * 68; i += 256) simp[i] = 0.f;
  if (t < 200) wls[t] = w[m * 200 + t];
  if (t < 8) bls[t] = bias[m * 8 + t];
  float* Qt = QtCt;
  if (m == 0)
    sim_phase<64>(f1q, f1c, Qt, QtCt + 64 * 68, simp, b, t);
  else if (m == 1)
    sim_phase<32>(f2q, f2c, Qt, QtCt + 32 * 68, simp, b, t);
  else
    sim_phase<16>(f3q, f3c, Qt, QtCt + 16 * 68, simp, b, t);
  __syncthreads();
  // conv phase: thread = pooled 2x2 block (gy,gx); 8 ocs sequential
  const int gy = t >> 4, gx = t & 15;
  float pr[8][8];
#pragma unroll
  for (int yy = 0; yy < 8; ++yy) {
    float4 a = *(const float4*)&simp[(4 * gy + yy) * PS + 4 * gx];
    float4 bb = *(const float4*)&simp[(4 * gy + yy) * PS + 4 * gx + 4];
    pr[yy][0] = a.x; pr[yy][1] = a.y; pr[yy][2] = a.z; pr[yy][3] = a.w;
    pr[yy][4] = bb.x; pr[yy][5] = bb.y; pr[yy][6] = bb.z; pr[yy][7] = bb.w;
  }
  u16* op = out + (size_t)(b * 3 + m) * 8192;
#pragma unroll 1
  for (int oc = 0; oc < 8; ++oc) {
    float acc[16];
#pragma unroll
    for (int p = 0; p < 16; ++p) acc[p] = 0.f;
#pragma unroll
    for (int ky = 0; ky < 5; ++ky)
#pragma unroll
      for (int kx = 0; kx < 5; ++kx) {
        float wv = wls[oc * 25 + ky * 5 + kx];
#pragma unroll
        for (int dy = 0; dy < 4; ++dy)
#pragma unroll
          for (int dx = 0; dx < 4; ++dx) acc[dy * 4 + dx] += pr[ky + dy][kx + dx] * wv;
      }
    float bv = bls[oc];
#pragma unroll
    for (int ay = 0; ay < 2; ++ay)
#pragma unroll
      for (int ax = 0; ax < 2; ++ax) {
        float v = fmaxf(fmaxf(acc[(2 * ay) * 4 + 2 * ax], acc[(2 * ay) * 4 + 2 * ax + 1]),
                        fmaxf(acc[(2 * ay + 1) * 4 + 2 * ax], acc[(2 * ay + 1) * 4 + 2 * ax + 1]));
        v = fmaxf(v + bv, 0.f);
        op[(size_t)(((2 * gy + ay) * 32) + (2 * gx + ax)) * 8 + oc] = f2bf(v);
      }
  }
}

// =================== conv2: bf16 MFMA (unchanged) ===================
__global__ __launch_bounds__(256) void conv2_mfma(
    const u16* __restrict__ in, const float* __restrict__ w,
    const float* __restrict__ bias, u16* __restrict__ out) {
  constexpr int PW = 36, BS = 40;
  __shared__ __align__(16) u16 ins[PW * PW * 8];
  __shared__ __align__(16) u16 wls[7 * 16 * BS];
  __shared__ float bls[16];
  const int b = blockIdx.x, m = blockIdx.y, t = threadIdx.x;
  const size_t ibase = (size_t)(b * 3 + m) * 8192;
  for (int i = t; i < PW * PW; i += 256) {
    int y = i / PW, x = i % PW;
    uint4 v = {0u, 0u, 0u, 0u};
    if (y >= 2 && y < 34 && x >= 2 && x < 34)
      v = *(const uint4*)&in[ibase + (size_t)((y - 2) * 32 + (x - 2)) * 8];
    *(uint4*)&ins[i * 8] = v;
  }
  for (int i = t; i < 7 * 16 * 32; i += 256) {
    int k = i & 31, oc = (i >> 5) & 15, st = i >> 9;
    int sl = k >> 3, ci = k & 7, tap = st * 4 + sl;
    float v = (tap < 25) ? w[((size_t)(m * 16 + oc) * 8 + ci) * 25 + tap] : 0.f;
    wls[(st * 16 + oc) * BS + k] = f2bf(v);
  }
  if (t < 16) bls[t] = bias[m * 16 + t];
  __syncthreads();
  const int wv = t >> 6, lane = t & 63;
  const int oc = lane & 15, g = lane >> 4;
  const size_t obase = (size_t)(b * 3 + m) * 4096;
#pragma unroll 1
  for (int task = wv; task < 32; task += 4) {
    const int yp = task >> 1, xt = task & 1;
    const int y0 = 2 * yp, x = xt * 16 + oc;
    f32x4 acc0 = {0.f, 0.f, 0.f, 0.f}, acc1 = {0.f, 0.f, 0.f, 0.f};
#pragma unroll
    for (int st = 0; st < 7; ++st) {
      bf8v bvv = *(const bf8v*)&wls[(st * 16 + oc) * BS + g * 8];
      int tp = st * 4 + g; tp = tp > 24 ? 24 : tp;
      int ky = tp / 5, kx = tp % 5;
      bf8v a0 = *(const bf8v*)&ins[(size_t)((y0 + ky) * PW + x + kx) * 8];
      acc0 = __builtin_amdgcn_mfma_f32_16x16x32_bf16(a0, bvv, acc0, 0, 0, 0);
      bf8v a1 = *(const bf8v*)&ins[(size_t)((y0 + 1 + ky) * PW + x + kx) * 8];
      acc1 = __builtin_amdgcn_mfma_f32_16x16x32_bf16(a1, bvv, acc1, 0, 0, 0);
    }
    const float bb = bls[oc];
    const float v0 = fmaxf(fmaxf(fmaxf(acc0[0], acc0[1]), fmaxf(acc1[0], acc1[1])) + bb, 0.f);
    const float v1 = fmaxf(fmaxf(fmaxf(acc0[2], acc0[3]), fmaxf(acc1[2], acc1[3])) + bb, 0.f);
    const int px = xt * 8 + 2 * g;
    out[obase + (size_t)((yp * 16 + px) * 16 + oc)] = f2bf(v0);
    out[obase + (size_t)((yp * 16 + px + 1) * 16 + oc)] = f2bf(v1);
  }
}

// =================== conv3: bf16 MFMA, writes feat bf16 (unchanged) ===================
__global__ __launch_bounds__(256) void conv3_mfma(
    const u16* __restrict__ in, const float* __restrict__ w,
    const float* __restrict__ bias, u16* __restrict__ feat) {
  constexpr int PW = 20, BS = 40;
  __shared__ __align__(16) u16 ins[PW * PW * 16];
  __shared__ __align__(16) u16 wls[13 * 2 * 16 * BS];
  __shared__ float bls[32];
  const int b = blockIdx.x, m = blockIdx.y, t = threadIdx.x;
  const size_t ibase = (size_t)(b * 3 + m) * 4096;
  for (int i = t; i < PW * PW; i += 256) {
    int y = i / PW, x = i % PW;
    uint4 v0 = {0u, 0u, 0u, 0u}, v1 = {0u, 0u, 0u, 0u};
    if (y >= 2 && y < 18 && x >= 2 && x < 18) {
      const u16* p = &in[ibase + (size_t)((y - 2) * 16 + (x - 2)) * 16];
      v0 = *(const uint4*)p;
      v1 = *(const uint4*)(p + 8);
    }
    *(uint4*)&ins[i * 16] = v0;
    *(uint4*)&ins[i * 16 + 8] = v1;
  }
  for (int i = t; i < 13 * 2 * 16 * 32; i += 256) {
    int k = i & 31, oc16 = (i >> 5) & 15, half = (i >> 9) & 1, st = i >> 10;
    int sl = k >> 4, ci = k & 15, tap = st * 2 + sl;
    int oc = half * 16 + oc16;
    float v = (tap < 25) ? w[((size_t)(m * 32 + oc) * 16 + ci) * 25 + tap] : 0.f;
    wls[((st * 2 + half) * 16 + oc16) * BS + k] = f2bf(v);
  }
  if (t < 32) bls[t] = bias[m * 32 + t];
  __syncthreads();
  const int wv = t >> 6, lane = t & 63;
  const int oc = lane & 15, g = lane >> 4;
  const int sl = g >> 1, ch = (g & 1) * 8;
  u16* fb = feat + (size_t)b * 6144 + m * 2048;
#pragma unroll 1
  for (int task = wv; task < 16; task += 4) {
    const int yp = task >> 1, half = task & 1;
    const int y0 = 2 * yp, x = oc;
    f32x4 acc0 = {0.f, 0.f, 0.f, 0.f}, acc1 = {0.f, 0.f, 0.f, 0.f};
#pragma unroll
    for (int st = 0; st < 13; ++st) {
      bf8v bvv = *(const bf8v*)&wls[(size_t)((st * 2 + half) * 16 + oc) * BS + g * 8];
      int tp = st * 2 + sl; tp = tp > 24 ? 24 : tp;
      int ky = tp / 5, kx = tp % 5;
      bf8v a0 = *(const bf8v*)&ins[(size_t)((y0 + ky) * PW + x + kx) * 16 + ch];
      acc0 = __builtin_amdgcn_mfma_f32_16x16x32_bf16(a0, bvv, acc0, 0, 0, 0);
      bf8v a1 = *(const bf8v*)&ins[(size_t)((y0 + 1 + ky) * PW + x + kx) * 16 + ch];
      acc1 = __builtin_amdgcn_mfma_f32_16x16x32_bf16(a1, bvv, acc1, 0, 0, 0);
    }
    const int ocg = half * 16 + oc;
    const float bb = bls[ocg];
    const float v0 = fmaxf(fmaxf(fmaxf(acc0[0], acc0[1]), fmaxf(acc1[0], acc1[1])) + bb, 0.f);
    const float v1 = fmaxf(fmaxf(fmaxf(acc0[2], acc0[3]), fmaxf(acc1[2], acc1[3])) + bb, 0.f);
    unsigned pack = (unsigned)f2bf(v0) | ((unsigned)f2bf(v1) << 16);
    *(unsigned*)&fb[ocg * 64 + yp * 8 + 2 * g] = pack;
  }
}

// =================== wcvt (unchanged) ===================
__global__ __launch_bounds__(256) void wcvt_kernel(const float* __restrict__ W,
                                                   u16* __restrict__ wT) {
  __shared__ float tile[64][65];
  const int k0 = blockIdx.x * 64, c0 = blockIdx.y * 64, t = threadIdx.x;
  for (int i = t; i < 4096; i += 256) {
    int r = i >> 6, c = i & 63;
    tile[r][c] = W[(size_t)(k0 + r) * 256 + c0 + c];
  }
  __syncthreads();
  for (int i = t; i < 4096; i += 256) {
    int c = i >> 6, k = i & 63;
    wT[(size_t)(c0 + c) * 6144 + k0 + k] = f2bf(tile[k][c]);
  }
}

// =================== lin1: bf16 MFMA GEMM (unchanged) ===================
__global__ __launch_bounds__(256) void lin1_mfma(const u16* __restrict__ feat,
                                                 const u16* __restrict__ wT,
                                                 float* __restrict__ h1p) {
  constexpr int AS = 72;
  __shared__ __align__(16) u16 As[64 * AS];
  __shared__ __align__(16) u16 Bs[64 * AS];
  const int r0 = blockIdx.x * 64, c0 = blockIdx.y * 64, kb = blockIdx.z * 384;
  const int t = threadIdx.x;
  const int w = t >> 6, lane = t & 63;
  const int row16 = lane & 15, kg = lane >> 4;
  f32x4 acc[4] = {{0.f, 0.f, 0.f, 0.f}, {0.f, 0.f, 0.f, 0.f},
                  {0.f, 0.f, 0.f, 0.f}, {0.f, 0.f, 0.f, 0.f}};
  const int lr = t >> 2, lk = (t & 3) * 16;
#pragma unroll 1
  for (int st = 0; st < 6; ++st) {
    __syncthreads();
    const int ks = kb + st * 64;
    {
      const u16* srcA = feat + (size_t)(r0 + lr) * 6144 + ks + lk;
      uint4 a0 = *(const uint4*)srcA;
      uint4 a1 = *(const uint4*)(srcA + 8);
      *(uint4*)&As[lr * AS + lk] = a0;
      *(uint4*)&As[lr * AS + lk + 8] = a1;
      const u16* srcB = wT + (size_t)(c0 + lr) * 6144 + ks + lk;
      uint4 b0 = *(const uint4*)srcB;
      uint4 b1 = *(const uint4*)(srcB + 8);
      *(uint4*)&Bs[lr * AS + lk] = b0;
      *(uint4*)&Bs[lr * AS + lk + 8] = b1;
    }
    __syncthreads();
#pragma unroll
    for (int kk = 0; kk < 2; ++kk) {
      bf8v a = *(const bf8v*)&As[(w * 16 + row16) * AS + kk * 32 + kg * 8];
#pragma unroll
      for (int ct = 0; ct < 4; ++ct) {
        bf8v bb = *(const bf8v*)&Bs[(ct * 16 + row16) * AS + kk * 32 + kg * 8];
        acc[ct] = __builtin_amdgcn_mfma_f32_16x16x32_bf16(a, bb, acc[ct], 0, 0, 0);
      }
    }
  }
  float* out = h1p + (size_t)blockIdx.z * 131072;
#pragma unroll
  for (int ct = 0; ct < 4; ++ct)
#pragma unroll
    for (int j = 0; j < 4; ++j)
      out[(size_t)(r0 + w * 16 + kg * 4 + j) * 256 + c0 + ct * 16 + row16] = acc[ct][j];
}

// =================== head (unchanged) ===================
__global__ __launch_bounds__(256) void head_kernel(
    const float* __restrict__ h1p, const float* __restrict__ b1,
    const float* __restrict__ w2, const float* __restrict__ b2,
    const float* __restrict__ sw, const float* __restrict__ sb,
    float* __restrict__ out) {
  constexpr int HS = 260;
  __shared__ __align__(16) float h1s[16 * HS];
  __shared__ __align__(16) float w2s[256 * 16];
  const int r0 = blockIdx.x * 16, t = threadIdx.x;
  for (int i = t; i < 4096; i += 256) {
    int r = i >> 8, k = i & 255;
    float s = b1[k];
#pragma unroll
    for (int p = 0; p < 16; ++p) s += h1p[(size_t)p * 131072 + (size_t)(r0 + r) * 256 + k];
    h1s[r * HS + k] = s;
    w2s[i] = w2[i];
  }
  __syncthreads();
  const int j = t & 15, r = t >> 4;
  float acc = b2[j];
#pragma unroll 4
  for (int k4 = 0; k4 < 64; ++k4) {
    float4 hv = *(const float4*)&h1s[r * HS + 4 * k4];
    float h0 = fmaxf(hv.x, 0.f), h1v = fmaxf(hv.y, 0.f);
    float h2v = fmaxf(hv.z, 0.f), h3 = fmaxf(hv.w, 0.f);
    acc += h0 * w2s[(4 * k4 + 0) * 16 + j];
    acc += h1v * w2s[(4 * k4 + 1) * 16 + j];
    acc += h2v * w2s[(4 * k4 + 2) * 16 + j];
    acc += h3 * w2s[(4 * k4 + 3) * 16 + j];
  }
  float v = fmaxf(acc, 0.f) * sw[j];
#pragma unroll
  for (int off = 8; off; off >>= 1) v += __shfl_xor(v, off, 16);
  if (j == 0) out[r0 + r] = v + sb[0];
}

// =================== launcher ===================
extern "C" void kernel_launch(void* const* d_in, const int* in_sizes, int n_in,
                              void* d_out, int out_size, void* d_ws, size_t ws_size,
                              hipStream_t stream) {
  const float* x_q = (const float*)d_in[0];
  const float* x_c = (const float*)d_in[1];
  const int* edge_q = (const int*)d_in[2];
  const int* edge_c = (const int*)d_in[3];
  const float* gw1 = (const float*)d_in[4];
  const float* gb1 = (const float*)d_in[5];
  const float* gw2 = (const float*)d_in[6];
  const float* gb2 = (const float*)d_in[7];
  const float* gw3 = (const float*)d_in[8];
  const float* gb3 = (const float*)d_in[9];
  const float* cw1 = (const float*)d_in[10];
  const float* cb1 = (const float*)d_in[11];
  const float* cw2 = (const float*)d_in[12];
  const float* cb2 = (const float*)d_in[13];
  const float* cw3 = (const float*)d_in[14];
  const float* cb3 = (const float*)d_in[15];
  const float* lw1 = (const float*)d_in[16];
  const float* lb1 = (const float*)d_in[17];
  const float* lw2 = (const float*)d_in[18];
  const float* lb2 = (const float*)d_in[19];
  const float* swt = (const float*)d_in[20];
  const float* sbs = (const float*)d_in[21];
  float* ws = (float*)d_ws;

  const size_t o_f1q = 65536;
  const size_t o_f2q = o_f1q + 2097152;
  const size_t o_f3q = o_f2q + 1048576;
  const size_t o_f1c = o_f3q + 524288;
  const size_t o_f2c = o_f1c + 2097152;
  const size_t o_f3c = o_f2c + 1048576;
  const size_t o_sims = o_f3c + 524288;   // now only feat scratch
  const size_t o_pm1 = o_sims + 6291456;
  const size_t o_pm2 = o_pm1 + 6291456;
  const size_t o_wT = o_pm2 + 3145728;
  const size_t o_feat = o_sims;           // bf16 feat
  const size_t o_h1p = o_f1q;             // reuse (f1q dead after simconv1)

  float* f1q = ws + o_f1q; float* f2q = ws + o_f2q; float* f3q = ws + o_f3q;
  float* f1c = ws + o_f1c; float* f2c = ws + o_f2c; float* f3c = ws + o_f3c;
  u16* pm1 = (u16*)(ws + o_pm1);
  u16* pm2 = (u16*)(ws + o_pm2);
  u16* wT = (u16*)(ws + o_wT);
  u16* feat = (u16*)(ws + o_feat);
  float* h1p = ws + o_h1p;

  wcvt_kernel<<<dim3(96, 4), 256, 0, stream>>>(lw1, wT);

  gcn_fused<<<dim3(B, 2), 512, 0, stream>>>(x_q, x_c, gw1, gb1, gw2, gb2, gw3, gb3,
                                            edge_q, edge_c, f1q, f1c, f2q, f2c, f3q, f3c);

  simconv1<<<dim3(B, 3), 256, 0, stream>>>(f1q, f1c, f2q, f2c, f3q, f3c, cw1, cb1, pm1);

  conv2_mfma<<<dim3(B, 3), 256, 0, stream>>>(pm1, cw2, cb2, pm2);
  conv3_mfma<<<dim3(B, 3), 256, 0, stream>>>(pm2, cw3, cb3, feat);

  lin1_mfma<<<dim3(8, 4, 16), 256, 0, stream>>>(feat, wT, h1p);
  head_kernel<<<32, 256, 0, stream>>>(h1p, lb1, lw2, lb2, swt, sbs, (float*)d_out);
}

// Round 8
// 175.969 us; speedup vs baseline: 5.8690x; 1.0180x over previous
//
#include <hip/hip_runtime.h>
#include <hip/hip_bf16.h>

constexpr int B = 512, N = 64, E = 512, NE = B * E;

typedef __attribute__((ext_vector_type(8))) short bf8v;
typedef __attribute__((ext_vector_type(4))) float f32x4;
typedef unsigned short u16;

__device__ __forceinline__ u16 f2bf(float f) {
  unsigned u = __builtin_bit_cast(unsigned, f);
  u += 0x7FFFu + ((u >> 16) & 1u);
  return (u16)(u >> 16);
}

// =================== fused 3-layer GCN: 512 threads (unchanged) ===================
template <int DIN, int DOUT, bool STORE_NEXT>
__device__ __forceinline__ void gcn_layer(
    float* __restrict__ At, float* __restrict__ Xt, float* __restrict__ Hs,
    float* __restrict__ Wls, const float* __restrict__ W,
    const float* __restrict__ bias, float* __restrict__ fout, int g, int t) {
  constexpr int XS = 68;
  for (int i = t; i < DIN * DOUT; i += 512) Wls[i] = W[i];
  __syncthreads();
  constexpr int CT = DOUT / 2;  // col-pairs
  const int ct = t % CT, nt = t / CT;
  if (nt < 16) {
    float acc[4][2] = {};
#pragma unroll 4
    for (int k = 0; k < DIN; ++k) {
      float4 xv = *(const float4*)&Xt[k * XS + 4 * nt];
      float2 wv = *(const float2*)&Wls[k * DOUT + 2 * ct];
      float xa[4] = {xv.x, xv.y, xv.z, xv.w};
#pragma unroll
      for (int i = 0; i < 4; ++i) {
        acc[i][0] += xa[i] * wv.x;
        acc[i][1] += xa[i] * wv.y;
      }
    }
#pragma unroll
    for (int i = 0; i < 4; ++i)
      *(float2*)&Hs[(4 * nt + i) * XS + 2 * ct] = make_float2(acc[i][0], acc[i][1]);
  }
  __syncthreads();
  if (nt < 16) {
    float acc[4][2] = {};
#pragma unroll 4
    for (int s = 0; s < N; ++s) {
      float4 av = *(const float4*)&At[s * XS + 4 * nt];
      float2 hv = *(const float2*)&Hs[s * XS + 2 * ct];
      float aa[4] = {av.x, av.y, av.z, av.w};
#pragma unroll
      for (int i = 0; i < 4; ++i) {
        acc[i][0] += aa[i] * hv.x;
        acc[i][1] += aa[i] * hv.y;
      }
    }
    const float2 bv = *(const float2*)&bias[2 * ct];
#pragma unroll
    for (int i = 0; i < 4; ++i) {
      float2 st = make_float2(acc[i][0] + bv.x, acc[i][1] + bv.y);
      *(float2*)&fout[(size_t)g * N * DOUT + (size_t)(4 * nt + i) * DOUT + 2 * ct] = st;
      if (STORE_NEXT) {
        Xt[(2 * ct + 0) * XS + 4 * nt + i] = fmaxf(st.x, 0.f);
        Xt[(2 * ct + 1) * XS + 4 * nt + i] = fmaxf(st.y, 0.f);
      }
    }
  }
  __syncthreads();
}

__global__ __launch_bounds__(512) void gcn_fused(
    const float* __restrict__ xq, const float* __restrict__ xc,
    const float* __restrict__ W1, const float* __restrict__ b1,
    const float* __restrict__ W2, const float* __restrict__ b2,
    const float* __restrict__ W3, const float* __restrict__ b3,
    const int* __restrict__ eq, const int* __restrict__ ec,
    float* __restrict__ f1q, float* __restrict__ f1c,
    float* __restrict__ f2q, float* __restrict__ f2c,
    float* __restrict__ f3q, float* __restrict__ f3c) {
  constexpr int XS = 68;
  __shared__ __align__(16) float At[N * XS];
  __shared__ __align__(16) float Xt[N * XS];
  __shared__ __align__(16) float Hs[N * XS];
  __shared__ __align__(16) float Wls[64 * 32];
  __shared__ float dl[N];
  __shared__ int cnt[N];
  const int g = blockIdx.x, t = threadIdx.x;
  const float* x = blockIdx.y ? xc : xq;
  const int* edges = blockIdx.y ? ec : eq;
  float* o1 = blockIdx.y ? f1c : f1q;
  float* o2 = blockIdx.y ? f2c : f2q;
  float* o3 = blockIdx.y ? f3c : f3q;
  for (int i = t; i < N * 16; i += 512) {
    int n = i / 16, k = i % 16;
    Xt[k * XS + n] = x[(size_t)g * N * 16 + i];
  }
  for (int i = t; i < N * XS; i += 512) At[i] = 0.f;
  if (t < N) cnt[t] = 1;
  __syncthreads();
  const int* srcp = edges + (size_t)g * E;
  const int* dstp = edges + NE + (size_t)g * E;
  for (int j = t; j < E; j += 512) atomicAdd(&cnt[dstp[j] & 63], 1);
  __syncthreads();
  if (t < N) dl[t] = rsqrtf((float)cnt[t]);
  __syncthreads();
  for (int j = t; j < E; j += 512) {
    int s = srcp[j] & 63, d = dstp[j] & 63;
    atomicAdd(&At[s * XS + d], dl[s] * dl[d]);
  }
  if (t < N) atomicAdd(&At[t * XS + t], dl[t] * dl[t]);
  __syncthreads();
  gcn_layer<16, 64, true>(At, Xt, Hs, Wls, W1, b1, o1, g, t);
  gcn_layer<64, 32, true>(At, Xt, Hs, Wls, W2, b2, o2, g, t);
  gcn_layer<32, 16, false>(At, Xt, Hs, Wls, W3, b3, o3, g, t);
}

// =================== fused sim (bf16 MFMA) + conv1 (fp32 VALU) ===================
__global__ __launch_bounds__(256) void simconv1(
    const float* __restrict__ f1q, const float* __restrict__ f1c,
    const float* __restrict__ f2q, const float* __restrict__ f2c,
    const float* __restrict__ f3q, const float* __restrict__ f3c,
    const float* __restrict__ w, const float* __restrict__ bias,
    u16* __restrict__ out) {
  constexpr int PS = 68, QS = 72;
  __shared__ __align__(16) u16 Qs[64 * QS];
  __shared__ __align__(16) u16 Cs[64 * QS];
  __shared__ __align__(16) float simp[68 * 68];
  __shared__ float wls[200];
  __shared__ float bls[8];
  const int b = blockIdx.x, m = blockIdx.y, t = threadIdx.x;
  for (int i = t; i < 68 * 68; i += 256) simp[i] = 0.f;
  if (t < 200) wls[t] = w[m * 200 + t];
  if (t < 8) bls[t] = bias[m * 8 + t];
  const float* fq = (m == 0) ? f1q : (m == 1) ? f2q : f3q;
  const float* fc = (m == 0) ? f1c : (m == 1) ? f2c : f3c;
  const int D = 64 >> m;                 // 64 / 32 / 16
  const int Kpad = (m == 0) ? 64 : 32;   // K rounded to MFMA depth
  // stage features as bf16 [n][k] rows (stride 72: 16B-aligned, 2-way bank alias = free)
  const int tot = 64 * Kpad;
  for (int i = t; i < tot; i += 256) {
    int n = i / Kpad, k = i - n * Kpad;
    u16 qv = 0, cv = 0;
    if (k < D) {
      qv = f2bf(fq[(size_t)b * 64 * D + n * D + k]);
      cv = f2bf(fc[(size_t)b * 64 * D + n * D + k]);
    }
    Qs[n * QS + k] = qv;
    Cs[n * QS + k] = cv;
  }
  __syncthreads();
  // sim via MFMA: wave w4 owns output rows [16*w4, 16*w4+16)
  const int w4 = t >> 6, lane = t & 63;
  const int r16 = lane & 15, kg = lane >> 4;
#pragma unroll 1
  for (int ct = 0; ct < 4; ++ct) {
    f32x4 acc = {0.f, 0.f, 0.f, 0.f};
    for (int ks = 0; ks < Kpad; ks += 32) {
      bf8v a = *(const bf8v*)&Qs[(w4 * 16 + r16) * QS + ks + kg * 8];
      bf8v bb = *(const bf8v*)&Cs[(ct * 16 + r16) * QS + ks + kg * 8];
      acc = __builtin_amdgcn_mfma_f32_16x16x32_bf16(a, bb, acc, 0, 0, 0);
    }
#pragma unroll
    for (int j = 0; j < 4; ++j)
      simp[(w4 * 16 + kg * 4 + j + 2) * PS + ct * 16 + r16 + 2] = acc[j];
  }
  __syncthreads();
  // conv phase (identical to round-6 verified structure)
  const int gy = t >> 4, gx = t & 15;
  float pr[8][8];
#pragma unroll
  for (int yy = 0; yy < 8; ++yy) {
    float4 a = *(const float4*)&simp[(4 * gy + yy) * PS + 4 * gx];
    float4 bb = *(const float4*)&simp[(4 * gy + yy) * PS + 4 * gx + 4];
    pr[yy][0] = a.x; pr[yy][1] = a.y; pr[yy][2] = a.z; pr[yy][3] = a.w;
    pr[yy][4] = bb.x; pr[yy][5] = bb.y; pr[yy][6] = bb.z; pr[yy][7] = bb.w;
  }
  u16* op = out + (size_t)(b * 3 + m) * 8192;
#pragma unroll 1
  for (int oc = 0; oc < 8; ++oc) {
    float acc[16];
#pragma unroll
    for (int p = 0; p < 16; ++p) acc[p] = 0.f;
#pragma unroll
    for (int ky = 0; ky < 5; ++ky)
#pragma unroll
      for (int kx = 0; kx < 5; ++kx) {
        float wv = wls[oc * 25 + ky * 5 + kx];
#pragma unroll
        for (int dy = 0; dy < 4; ++dy)
#pragma unroll
          for (int dx = 0; dx < 4; ++dx) acc[dy * 4 + dx] += pr[ky + dy][kx + dx] * wv;
      }
    float bv = bls[oc];
#pragma unroll
    for (int ay = 0; ay < 2; ++ay)
#pragma unroll
      for (int ax = 0; ax < 2; ++ax) {
        float v = fmaxf(fmaxf(acc[(2 * ay) * 4 + 2 * ax], acc[(2 * ay) * 4 + 2 * ax + 1]),
                        fmaxf(acc[(2 * ay + 1) * 4 + 2 * ax], acc[(2 * ay + 1) * 4 + 2 * ax + 1]));
        v = fmaxf(v + bv, 0.f);
        op[(size_t)(((2 * gy + ay) * 32) + (2 * gx + ax)) * 8 + oc] = f2bf(v);
      }
  }
}

// =================== conv2: bf16 MFMA (unchanged) ===================
__global__ __launch_bounds__(256) void conv2_mfma(
    const u16* __restrict__ in, const float* __restrict__ w,
    const float* __restrict__ bias, u16* __restrict__ out) {
  constexpr int PW = 36, BS = 40;
  __shared__ __align__(16) u16 ins[PW * PW * 8];
  __shared__ __align__(16) u16 wls[7 * 16 * BS];
  __shared__ float bls[16];
  const int b = blockIdx.x, m = blockIdx.y, t = threadIdx.x;
  const size_t ibase = (size_t)(b * 3 + m) * 8192;
  for (int i = t; i < PW * PW; i += 256) {
    int y = i / PW, x = i % PW;
    uint4 v = {0u, 0u, 0u, 0u};
    if (y >= 2 && y < 34 && x >= 2 && x < 34)
      v = *(const uint4*)&in[ibase + (size_t)((y - 2) * 32 + (x - 2)) * 8];
    *(uint4*)&ins[i * 8] = v;
  }
  for (int i = t; i < 7 * 16 * 32; i += 256) {
    int k = i & 31, oc = (i >> 5) & 15, st = i >> 9;
    int sl = k >> 3, ci = k & 7, tap = st * 4 + sl;
    float v = (tap < 25) ? w[((size_t)(m * 16 + oc) * 8 + ci) * 25 + tap] : 0.f;
    wls[(st * 16 + oc) * BS + k] = f2bf(v);
  }
  if (t < 16) bls[t] = bias[m * 16 + t];
  __syncthreads();
  const int wv = t >> 6, lane = t & 63;
  const int oc = lane & 15, g = lane >> 4;
  const size_t obase = (size_t)(b * 3 + m) * 4096;
#pragma unroll 1
  for (int task = wv; task < 32; task += 4) {
    const int yp = task >> 1, xt = task & 1;
    const int y0 = 2 * yp, x = xt * 16 + oc;
    f32x4 acc0 = {0.f, 0.f, 0.f, 0.f}, acc1 = {0.f, 0.f, 0.f, 0.f};
#pragma unroll
    for (int st = 0; st < 7; ++st) {
      bf8v bvv = *(const bf8v*)&wls[(st * 16 + oc) * BS + g * 8];
      int tp = st * 4 + g; tp = tp > 24 ? 24 : tp;
      int ky = tp / 5, kx = tp % 5;
      bf8v a0 = *(const bf8v*)&ins[(size_t)((y0 + ky) * PW + x + kx) * 8];
      acc0 = __builtin_amdgcn_mfma_f32_16x16x32_bf16(a0, bvv, acc0, 0, 0, 0);
      bf8v a1 = *(const bf8v*)&ins[(size_t)((y0 + 1 + ky) * PW + x + kx) * 8];
      acc1 = __builtin_amdgcn_mfma_f32_16x16x32_bf16(a1, bvv, acc1, 0, 0, 0);
    }
    const float bb = bls[oc];
    const float v0 = fmaxf(fmaxf(fmaxf(acc0[0], acc0[1]), fmaxf(acc1[0], acc1[1])) + bb, 0.f);
    const float v1 = fmaxf(fmaxf(fmaxf(acc0[2], acc0[3]), fmaxf(acc1[2], acc1[3])) + bb, 0.f);
    const int px = xt * 8 + 2 * g;
    out[obase + (size_t)((yp * 16 + px) * 16 + oc)] = f2bf(v0);
    out[obase + (size_t)((yp * 16 + px + 1) * 16 + oc)] = f2bf(v1);
  }
}

// =================== conv3: bf16 MFMA, writes feat bf16 (unchanged) ===================
__global__ __launch_bounds__(256) void conv3_mfma(
    const u16* __restrict__ in, const float* __restrict__ w,
    const float* __restrict__ bias, u16* __restrict__ feat) {
  constexpr int PW = 20, BS = 40;
  __shared__ __align__(16) u16 ins[PW * PW * 16];
  __shared__ __align__(16) u16 wls[13 * 2 * 16 * BS];
  __shared__ float bls[32];
  const int b = blockIdx.x, m = blockIdx.y, t = threadIdx.x;
  const size_t ibase = (size_t)(b * 3 + m) * 4096;
  for (int i = t; i < PW * PW; i += 256) {
    int y = i / PW, x = i % PW;
    uint4 v0 = {0u, 0u, 0u, 0u}, v1 = {0u, 0u, 0u, 0u};
    if (y >= 2 && y < 18 && x >= 2 && x < 18) {
      const u16* p = &in[ibase + (size_t)((y - 2) * 16 + (x - 2)) * 16];
      v0 = *(const uint4*)p;
      v1 = *(const uint4*)(p + 8);
    }
    *(uint4*)&ins[i * 16] = v0;
    *(uint4*)&ins[i * 16 + 8] = v1;
  }
  for (int i = t; i < 13 * 2 * 16 * 32; i += 256) {
    int k = i & 31, oc16 = (i >> 5) & 15, half = (i >> 9) & 1, st = i >> 10;
    int sl = k >> 4, ci = k & 15, tap = st * 2 + sl;
    int oc = half * 16 + oc16;
    float v = (tap < 25) ? w[((size_t)(m * 32 + oc) * 16 + ci) * 25 + tap] : 0.f;
    wls[((st * 2 + half) * 16 + oc16) * BS + k] = f2bf(v);
  }
  if (t < 32) bls[t] = bias[m * 32 + t];
  __syncthreads();
  const int wv = t >> 6, lane = t & 63;
  const int oc = lane & 15, g = lane >> 4;
  const int sl = g >> 1, ch = (g & 1) * 8;
  u16* fb = feat + (size_t)b * 6144 + m * 2048;
#pragma unroll 1
  for (int task = wv; task < 16; task += 4) {
    const int yp = task >> 1, half = task & 1;
    const int y0 = 2 * yp, x = oc;
    f32x4 acc0 = {0.f, 0.f, 0.f, 0.f}, acc1 = {0.f, 0.f, 0.f, 0.f};
#pragma unroll
    for (int st = 0; st < 13; ++st) {
      bf8v bvv = *(const bf8v*)&wls[(size_t)((st * 2 + half) * 16 + oc) * BS + g * 8];
      int tp = st * 2 + sl; tp = tp > 24 ? 24 : tp;
      int ky = tp / 5, kx = tp % 5;
      bf8v a0 = *(const bf8v*)&ins[(size_t)((y0 + ky) * PW + x + kx) * 16 + ch];
      acc0 = __builtin_amdgcn_mfma_f32_16x16x32_bf16(a0, bvv, acc0, 0, 0, 0);
      bf8v a1 = *(const bf8v*)&ins[(size_t)((y0 + 1 + ky) * PW + x + kx) * 16 + ch];
      acc1 = __builtin_amdgcn_mfma_f32_16x16x32_bf16(a1, bvv, acc1, 0, 0, 0);
    }
    const int ocg = half * 16 + oc;
    const float bb = bls[ocg];
    const float v0 = fmaxf(fmaxf(fmaxf(acc0[0], acc0[1]), fmaxf(acc1[0], acc1[1])) + bb, 0.f);
    const float v1 = fmaxf(fmaxf(fmaxf(acc0[2], acc0[3]), fmaxf(acc1[2], acc1[3])) + bb, 0.f);
    unsigned pack = (unsigned)f2bf(v0) | ((unsigned)f2bf(v1) << 16);
    *(unsigned*)&fb[ocg * 64 + yp * 8 + 2 * g] = pack;
  }
}

// =================== wcvt (unchanged) ===================
__global__ __launch_bounds__(256) void wcvt_kernel(const float* __restrict__ W,
                                                   u16* __restrict__ wT) {
  __shared__ float tile[64][65];
  const int k0 = blockIdx.x * 64, c0 = blockIdx.y * 64, t = threadIdx.x;
  for (int i = t; i < 4096; i += 256) {
    int r = i >> 6, c = i & 63;
    tile[r][c] = W[(size_t)(k0 + r) * 256 + c0 + c];
  }
  __syncthreads();
  for (int i = t; i < 4096; i += 256) {
    int c = i >> 6, k = i & 63;
    wT[(size_t)(c0 + c) * 6144 + k0 + k] = f2bf(tile[k][c]);
  }
}

// =================== lin1: bf16 MFMA GEMM (unchanged) ===================
__global__ __launch_bounds__(256) void lin1_mfma(const u16* __restrict__ feat,
                                                 const u16* __restrict__ wT,
                                                 float* __restrict__ h1p) {
  constexpr int AS = 72;
  __shared__ __align__(16) u16 As[64 * AS];
  __shared__ __align__(16) u16 Bs[64 * AS];
  const int r0 = blockIdx.x * 64, c0 = blockIdx.y * 64, kb = blockIdx.z * 384;
  const int t = threadIdx.x;
  const int w = t >> 6, lane = t & 63;
  const int row16 = lane & 15, kg = lane >> 4;
  f32x4 acc[4] = {{0.f, 0.f, 0.f, 0.f}, {0.f, 0.f, 0.f, 0.f},
                  {0.f, 0.f, 0.f, 0.f}, {0.f, 0.f, 0.f, 0.f}};
  const int lr = t >> 2, lk = (t & 3) * 16;
#pragma unroll 1
  for (int st = 0; st < 6; ++st) {
    __syncthreads();
    const int ks = kb + st * 64;
    {
      const u16* srcA = feat + (size_t)(r0 + lr) * 6144 + ks + lk;
      uint4 a0 = *(const uint4*)srcA;
      uint4 a1 = *(const uint4*)(srcA + 8);
      *(uint4*)&As[lr * AS + lk] = a0;
      *(uint4*)&As[lr * AS + lk + 8] = a1;
      const u16* srcB = wT + (size_t)(c0 + lr) * 6144 + ks + lk;
      uint4 b0 = *(const uint4*)srcB;
      uint4 b1 = *(const uint4*)(srcB + 8);
      *(uint4*)&Bs[lr * AS + lk] = b0;
      *(uint4*)&Bs[lr * AS + lk + 8] = b1;
    }
    __syncthreads();
#pragma unroll
    for (int kk = 0; kk < 2; ++kk) {
      bf8v a = *(const bf8v*)&As[(w * 16 + row16) * AS + kk * 32 + kg * 8];
#pragma unroll
      for (int ct = 0; ct < 4; ++ct) {
        bf8v bb = *(const bf8v*)&Bs[(ct * 16 + row16) * AS + kk * 32 + kg * 8];
        acc[ct] = __builtin_amdgcn_mfma_f32_16x16x32_bf16(a, bb, acc[ct], 0, 0, 0);
      }
    }
  }
  float* out = h1p + (size_t)blockIdx.z * 131072;
#pragma unroll
  for (int ct = 0; ct < 4; ++ct)
#pragma unroll
    for (int j = 0; j < 4; ++j)
      out[(size_t)(r0 + w * 16 + kg * 4 + j) * 256 + c0 + ct * 16 + row16] = acc[ct][j];
}

// =================== head (unchanged) ===================
__global__ __launch_bounds__(256) void head_kernel(
    const float* __restrict__ h1p, const float* __restrict__ b1,
    const float* __restrict__ w2, const float* __restrict__ b2,
    const float* __restrict__ sw, const float* __restrict__ sb,
    float* __restrict__ out) {
  constexpr int HS = 260;
  __shared__ __align__(16) float h1s[16 * HS];
  __shared__ __align__(16) float w2s[256 * 16];
  const int r0 = blockIdx.x * 16, t = threadIdx.x;
  for (int i = t; i < 4096; i += 256) {
    int r = i >> 8, k = i & 255;
    float s = b1[k];
#pragma unroll
    for (int p = 0; p < 16; ++p) s += h1p[(size_t)p * 131072 + (size_t)(r0 + r) * 256 + k];
    h1s[r * HS + k] = s;
    w2s[i] = w2[i];
  }
  __syncthreads();
  const int j = t & 15, r = t >> 4;
  float acc = b2[j];
#pragma unroll 4
  for (int k4 = 0; k4 < 64; ++k4) {
    float4 hv = *(const float4*)&h1s[r * HS + 4 * k4];
    float h0 = fmaxf(hv.x, 0.f), h1v = fmaxf(hv.y, 0.f);
    float h2v = fmaxf(hv.z, 0.f), h3 = fmaxf(hv.w, 0.f);
    acc += h0 * w2s[(4 * k4 + 0) * 16 + j];
    acc += h1v * w2s[(4 * k4 + 1) * 16 + j];
    acc += h2v * w2s[(4 * k4 + 2) * 16 + j];
    acc += h3 * w2s[(4 * k4 + 3) * 16 + j];
  }
  float v = fmaxf(acc, 0.f) * sw[j];
#pragma unroll
  for (int off = 8; off; off >>= 1) v += __shfl_xor(v, off, 16);
  if (j == 0) out[r0 + r] = v + sb[0];
}

// =================== launcher ===================
extern "C" void kernel_launch(void* const* d_in, const int* in_sizes, int n_in,
                              void* d_out, int out_size, void* d_ws, size_t ws_size,
                              hipStream_t stream) {
  const float* x_q = (const float*)d_in[0];
  const float* x_c = (const float*)d_in[1];
  const int* edge_q = (const int*)d_in[2];
  const int* edge_c = (const int*)d_in[3];
  const float* gw1 = (const float*)d_in[4];
  const float* gb1 = (const float*)d_in[5];
  const float* gw2 = (const float*)d_in[6];
  const float* gb2 = (const float*)d_in[7];
  const float* gw3 = (const float*)d_in[8];
  const float* gb3 = (const float*)d_in[9];
  const float* cw1 = (const float*)d_in[10];
  const float* cb1 = (const float*)d_in[11];
  const float* cw2 = (const float*)d_in[12];
  const float* cb2 = (const float*)d_in[13];
  const float* cw3 = (const float*)d_in[14];
  const float* cb3 = (const float*)d_in[15];
  const float* lw1 = (const float*)d_in[16];
  const float* lb1 = (const float*)d_in[17];
  const float* lw2 = (const float*)d_in[18];
  const float* lb2 = (const float*)d_in[19];
  const float* swt = (const float*)d_in[20];
  const float* sbs = (const float*)d_in[21];
  float* ws = (float*)d_ws;

  const size_t o_f1q = 65536;
  const size_t o_f2q = o_f1q + 2097152;
  const size_t o_f3q = o_f2q + 1048576;
  const size_t o_f1c = o_f3q + 524288;
  const size_t o_f2c = o_f1c + 2097152;
  const size_t o_f3c = o_f2c + 1048576;
  const size_t o_sims = o_f3c + 524288;
  const size_t o_pm1 = o_sims + 6291456;
  const size_t o_pm2 = o_pm1 + 6291456;
  const size_t o_wT = o_pm2 + 3145728;
  const size_t o_feat = o_sims;           // bf16 feat
  const size_t o_h1p = o_f1q;             // reuse (f1q dead after simconv1)

  float* f1q = ws + o_f1q; float* f2q = ws + o_f2q; float* f3q = ws + o_f3q;
  float* f1c = ws + o_f1c; float* f2c = ws + o_f2c; float* f3c = ws + o_f3c;
  u16* pm1 = (u16*)(ws + o_pm1);
  u16* pm2 = (u16*)(ws + o_pm2);
  u16* wT = (u16*)(ws + o_wT);
  u16* feat = (u16*)(ws + o_feat);
  float* h1p = ws + o_h1p;

  wcvt_kernel<<<dim3(96, 4), 256, 0, stream>>>(lw1, wT);

  gcn_fused<<<dim3(B, 2), 512, 0, stream>>>(x_q, x_c, gw1, gb1, gw2, gb2, gw3, gb3,
                                            edge_q, edge_c, f1q, f1c, f2q, f2c, f3q, f3c);

  simconv1<<<dim3(B, 3), 256, 0, stream>>>(f1q, f1c, f2q, f2c, f3q, f3c, cw1, cb1, pm1);

  conv2_mfma<<<dim3(B, 3), 256, 0, stream>>>(pm1, cw2, cb2, pm2);
  conv3_mfma<<<dim3(B, 3), 256, 0, stream>>>(pm2, cw3, cb3, feat);

  lin1_mfma<<<dim3(8, 4, 16), 256, 0, stream>>>(feat, wT, h1p);
  head_kernel<<<32, 256, 0, stream>>>(h1p, lb1, lw2, lb2, swt, sbs, (float*)d_out);
}

// Round 9
// 162.072 us; speedup vs baseline: 6.3723x; 1.0857x over previous
//
#include <hip/hip_runtime.h>
#include <hip/hip_bf16.h>

constexpr int B = 512, N = 64, E = 512, NE = B * E;

typedef __attribute__((ext_vector_type(8))) short bf8v;
typedef __attribute__((ext_vector_type(4))) float f32x4;
typedef unsigned short u16;

__device__ __forceinline__ u16 f2bf(float f) {
  unsigned u = __builtin_bit_cast(unsigned, f);
  u += 0x7FFFu + ((u >> 16) & 1u);
  return (u16)(u >> 16);
}

// =================== fused 3-layer GCN: 512 threads, bf16 feature output ===================
template <int DIN, int DOUT, bool STORE_NEXT>
__device__ __forceinline__ void gcn_layer(
    float* __restrict__ At, float* __restrict__ Xt, float* __restrict__ Hs,
    float* __restrict__ Wls, const float* __restrict__ W,
    const float* __restrict__ bias, u16* __restrict__ fout, int g, int t) {
  constexpr int XS = 68;
  for (int i = t; i < DIN * DOUT; i += 512) Wls[i] = W[i];
  __syncthreads();
  constexpr int CT = DOUT / 2;  // col-pairs
  const int ct = t % CT, nt = t / CT;
  if (nt < 16) {
    float acc[4][2] = {};
#pragma unroll 4
    for (int k = 0; k < DIN; ++k) {
      float4 xv = *(const float4*)&Xt[k * XS + 4 * nt];
      float2 wv = *(const float2*)&Wls[k * DOUT + 2 * ct];
      float xa[4] = {xv.x, xv.y, xv.z, xv.w};
#pragma unroll
      for (int i = 0; i < 4; ++i) {
        acc[i][0] += xa[i] * wv.x;
        acc[i][1] += xa[i] * wv.y;
      }
    }
#pragma unroll
    for (int i = 0; i < 4; ++i)
      *(float2*)&Hs[(4 * nt + i) * XS + 2 * ct] = make_float2(acc[i][0], acc[i][1]);
  }
  __syncthreads();
  if (nt < 16) {
    float acc[4][2] = {};
#pragma unroll 4
    for (int s = 0; s < N; ++s) {
      float4 av = *(const float4*)&At[s * XS + 4 * nt];
      float2 hv = *(const float2*)&Hs[s * XS + 2 * ct];
      float aa[4] = {av.x, av.y, av.z, av.w};
#pragma unroll
      for (int i = 0; i < 4; ++i) {
        acc[i][0] += aa[i] * hv.x;
        acc[i][1] += aa[i] * hv.y;
      }
    }
    const float2 bv = *(const float2*)&bias[2 * ct];
#pragma unroll
    for (int i = 0; i < 4; ++i) {
      float2 st = make_float2(acc[i][0] + bv.x, acc[i][1] + bv.y);
      unsigned pack = (unsigned)f2bf(st.x) | ((unsigned)f2bf(st.y) << 16);
      *(unsigned*)&fout[(size_t)g * N * DOUT + (size_t)(4 * nt + i) * DOUT + 2 * ct] = pack;
      if (STORE_NEXT) {
        Xt[(2 * ct + 0) * XS + 4 * nt + i] = fmaxf(st.x, 0.f);
        Xt[(2 * ct + 1) * XS + 4 * nt + i] = fmaxf(st.y, 0.f);
      }
    }
  }
  __syncthreads();
}

__global__ __launch_bounds__(512) void gcn_fused(
    const float* __restrict__ xq, const float* __restrict__ xc,
    const float* __restrict__ W1, const float* __restrict__ b1,
    const float* __restrict__ W2, const float* __restrict__ b2,
    const float* __restrict__ W3, const float* __restrict__ b3,
    const int* __restrict__ eq, const int* __restrict__ ec,
    u16* __restrict__ f1q, u16* __restrict__ f1c,
    u16* __restrict__ f2q, u16* __restrict__ f2c,
    u16* __restrict__ f3q, u16* __restrict__ f3c) {
  constexpr int XS = 68;
  __shared__ __align__(16) float At[N * XS];
  __shared__ __align__(16) float Xt[N * XS];
  __shared__ __align__(16) float Hs[N * XS];
  __shared__ __align__(16) float Wls[64 * 32];
  __shared__ float dl[N];
  __shared__ int cnt[N];
  const int g = blockIdx.x, t = threadIdx.x;
  const float* x = blockIdx.y ? xc : xq;
  const int* edges = blockIdx.y ? ec : eq;
  u16* o1 = blockIdx.y ? f1c : f1q;
  u16* o2 = blockIdx.y ? f2c : f2q;
  u16* o3 = blockIdx.y ? f3c : f3q;
  for (int i = t; i < N * 16; i += 512) {
    int n = i / 16, k = i % 16;
    Xt[k * XS + n] = x[(size_t)g * N * 16 + i];
  }
  for (int i = t; i < N * XS; i += 512) At[i] = 0.f;
  if (t < N) cnt[t] = 1;
  __syncthreads();
  const int* srcp = edges + (size_t)g * E;
  const int* dstp = edges + NE + (size_t)g * E;
  for (int j = t; j < E; j += 512) atomicAdd(&cnt[dstp[j] & 63], 1);
  __syncthreads();
  if (t < N) dl[t] = rsqrtf((float)cnt[t]);
  __syncthreads();
  for (int j = t; j < E; j += 512) {
    int s = srcp[j] & 63, d = dstp[j] & 63;
    atomicAdd(&At[s * XS + d], dl[s] * dl[d]);
  }
  if (t < N) atomicAdd(&At[t * XS + t], dl[t] * dl[t]);
  __syncthreads();
  gcn_layer<16, 64, true>(At, Xt, Hs, Wls, W1, b1, o1, g, t);
  gcn_layer<64, 32, true>(At, Xt, Hs, Wls, W2, b2, o2, g, t);
  gcn_layer<32, 16, false>(At, Xt, Hs, Wls, W3, b3, o3, g, t);
}

// =================== fused sim (bf16 MFMA) + conv1 (fp32 VALU, oc-pairs) ===================
__global__ __launch_bounds__(256, 4) void simconv1(
    const u16* __restrict__ f1q, const u16* __restrict__ f1c,
    const u16* __restrict__ f2q, const u16* __restrict__ f2c,
    const u16* __restrict__ f3q, const u16* __restrict__ f3c,
    const float* __restrict__ w, const float* __restrict__ bias,
    u16* __restrict__ out) {
  constexpr int PS = 68, QS = 72;
  __shared__ __align__(16) u16 Qs[64 * QS];
  __shared__ __align__(16) u16 Cs[64 * QS];
  __shared__ __align__(16) float simp[68 * 68];
  __shared__ float wls[25 * 8];  // [tap][oc]
  __shared__ float bls[8];
  const int b = blockIdx.x, m = blockIdx.y, t = threadIdx.x;
  for (int i = t; i < 68 * 68; i += 256) simp[i] = 0.f;
  if (t < 200) {
    int oc = t / 25, tap = t % 25;
    wls[tap * 8 + oc] = w[m * 200 + t];
  }
  if (t < 8) bls[t] = bias[m * 8 + t];
  const u16* fq = (m == 0) ? f1q : (m == 1) ? f2q : f3q;
  const u16* fc = (m == 0) ? f1c : (m == 1) ? f2c : f3c;
  const int D = 64 >> m;          // 64 / 32 / 16
  const int SEG = D >> 3;         // uint4 segments per row: 8/4/2
  // stage bf16 features [n][k] via uint4 copies
  for (int i = t; i < 64 * SEG; i += 256) {
    int n = i / SEG, s = i - n * SEG;
    *(uint4*)&Qs[n * QS + s * 8] = *(const uint4*)&fq[(size_t)b * 64 * D + n * D + s * 8];
    *(uint4*)&Cs[n * QS + s * 8] = *(const uint4*)&fc[(size_t)b * 64 * D + n * D + s * 8];
  }
  if (m == 2 && t < 128) {  // zero-pad k=16..31
    int n = t >> 1, s = t & 1;
    uint4 z = {0u, 0u, 0u, 0u};
    *(uint4*)&Qs[n * QS + 16 + s * 8] = z;
    *(uint4*)&Cs[n * QS + 16 + s * 8] = z;
  }
  __syncthreads();
  // sim via MFMA: wave w4 owns output rows [16*w4, 16*w4+16)
  const int w4 = t >> 6, lane = t & 63;
  const int r16 = lane & 15, kg = lane >> 4;
  const int Kpad = (m == 0) ? 64 : 32;
#pragma unroll 1
  for (int ct = 0; ct < 4; ++ct) {
    f32x4 acc = {0.f, 0.f, 0.f, 0.f};
    for (int ks = 0; ks < Kpad; ks += 32) {
      bf8v a = *(const bf8v*)&Qs[(w4 * 16 + r16) * QS + ks + kg * 8];
      bf8v bb = *(const bf8v*)&Cs[(ct * 16 + r16) * QS + ks + kg * 8];
      acc = __builtin_amdgcn_mfma_f32_16x16x32_bf16(a, bb, acc, 0, 0, 0);
    }
#pragma unroll
    for (int j = 0; j < 4; ++j)
      simp[(w4 * 16 + kg * 4 + j + 2) * PS + ct * 16 + r16 + 2] = acc[j];
  }
  __syncthreads();
  // conv phase: patch in regs, ocs in pairs
  const int gy = t >> 4, gx = t & 15;
  float pr[8][8];
#pragma unroll
  for (int yy = 0; yy < 8; ++yy) {
    float4 a = *(const float4*)&simp[(4 * gy + yy) * PS + 4 * gx];
    float4 bb = *(const float4*)&simp[(4 * gy + yy) * PS + 4 * gx + 4];
    pr[yy][0] = a.x; pr[yy][1] = a.y; pr[yy][2] = a.z; pr[yy][3] = a.w;
    pr[yy][4] = bb.x; pr[yy][5] = bb.y; pr[yy][6] = bb.z; pr[yy][7] = bb.w;
  }
  u16* op = out + (size_t)(b * 3 + m) * 8192;
#pragma unroll 1
  for (int p2 = 0; p2 < 4; ++p2) {
    float acc[2][16];
#pragma unroll
    for (int p = 0; p < 16; ++p) { acc[0][p] = 0.f; acc[1][p] = 0.f; }
#pragma unroll
    for (int ky = 0; ky < 5; ++ky)
#pragma unroll
      for (int kx = 0; kx < 5; ++kx) {
        float2 wv = *(const float2*)&wls[(ky * 5 + kx) * 8 + p2 * 2];
#pragma unroll
        for (int dy = 0; dy < 4; ++dy)
#pragma unroll
          for (int dx = 0; dx < 4; ++dx) {
            float rv = pr[ky + dy][kx + dx];
            acc[0][dy * 4 + dx] += rv * wv.x;
            acc[1][dy * 4 + dx] += rv * wv.y;
          }
      }
    float b0 = bls[p2 * 2], b1 = bls[p2 * 2 + 1];
#pragma unroll
    for (int ay = 0; ay < 2; ++ay)
#pragma unroll
      for (int ax = 0; ax < 2; ++ax) {
        float v0 = fmaxf(fmaxf(acc[0][(2 * ay) * 4 + 2 * ax], acc[0][(2 * ay) * 4 + 2 * ax + 1]),
                         fmaxf(acc[0][(2 * ay + 1) * 4 + 2 * ax], acc[0][(2 * ay + 1) * 4 + 2 * ax + 1]));
        float v1 = fmaxf(fmaxf(acc[1][(2 * ay) * 4 + 2 * ax], acc[1][(2 * ay) * 4 + 2 * ax + 1]),
                         fmaxf(acc[1][(2 * ay + 1) * 4 + 2 * ax], acc[1][(2 * ay + 1) * 4 + 2 * ax + 1]));
        v0 = fmaxf(v0 + b0, 0.f);
        v1 = fmaxf(v1 + b1, 0.f);
        unsigned pack = (unsigned)f2bf(v0) | ((unsigned)f2bf(v1) << 16);
        *(unsigned*)&op[(size_t)(((2 * gy + ay) * 32) + (2 * gx + ax)) * 8 + p2 * 2] = pack;
      }
  }
}

// =================== conv2: bf16 MFMA (unchanged) ===================
__global__ __launch_bounds__(256) void conv2_mfma(
    const u16* __restrict__ in, const float* __restrict__ w,
    const float* __restrict__ bias, u16* __restrict__ out) {
  constexpr int PW = 36, BS = 40;
  __shared__ __align__(16) u16 ins[PW * PW * 8];
  __shared__ __align__(16) u16 wls[7 * 16 * BS];
  __shared__ float bls[16];
  const int b = blockIdx.x, m = blockIdx.y, t = threadIdx.x;
  const size_t ibase = (size_t)(b * 3 + m) * 8192;
  for (int i = t; i < PW * PW; i += 256) {
    int y = i / PW, x = i % PW;
    uint4 v = {0u, 0u, 0u, 0u};
    if (y >= 2 && y < 34 && x >= 2 && x < 34)
      v = *(const uint4*)&in[ibase + (size_t)((y - 2) * 32 + (x - 2)) * 8];
    *(uint4*)&ins[i * 8] = v;
  }
  for (int i = t; i < 7 * 16 * 32; i += 256) {
    int k = i & 31, oc = (i >> 5) & 15, st = i >> 9;
    int sl = k >> 3, ci = k & 7, tap = st * 4 + sl;
    float v = (tap < 25) ? w[((size_t)(m * 16 + oc) * 8 + ci) * 25 + tap] : 0.f;
    wls[(st * 16 + oc) * BS + k] = f2bf(v);
  }
  if (t < 16) bls[t] = bias[m * 16 + t];
  __syncthreads();
  const int wv = t >> 6, lane = t & 63;
  const int oc = lane & 15, g = lane >> 4;
  const size_t obase = (size_t)(b * 3 + m) * 4096;
#pragma unroll 1
  for (int task = wv; task < 32; task += 4) {
    const int yp = task >> 1, xt = task & 1;
    const int y0 = 2 * yp, x = xt * 16 + oc;
    f32x4 acc0 = {0.f, 0.f, 0.f, 0.f}, acc1 = {0.f, 0.f, 0.f, 0.f};
#pragma unroll
    for (int st = 0; st < 7; ++st) {
      bf8v bvv = *(const bf8v*)&wls[(st * 16 + oc) * BS + g * 8];
      int tp = st * 4 + g; tp = tp > 24 ? 24 : tp;
      int ky = tp / 5, kx = tp % 5;
      bf8v a0 = *(const bf8v*)&ins[(size_t)((y0 + ky) * PW + x + kx) * 8];
      acc0 = __builtin_amdgcn_mfma_f32_16x16x32_bf16(a0, bvv, acc0, 0, 0, 0);
      bf8v a1 = *(const bf8v*)&ins[(size_t)((y0 + 1 + ky) * PW + x + kx) * 8];
      acc1 = __builtin_amdgcn_mfma_f32_16x16x32_bf16(a1, bvv, acc1, 0, 0, 0);
    }
    const float bb = bls[oc];
    const float v0 = fmaxf(fmaxf(fmaxf(acc0[0], acc0[1]), fmaxf(acc1[0], acc1[1])) + bb, 0.f);
    const float v1 = fmaxf(fmaxf(fmaxf(acc0[2], acc0[3]), fmaxf(acc1[2], acc1[3])) + bb, 0.f);
    const int px = xt * 8 + 2 * g;
    out[obase + (size_t)((yp * 16 + px) * 16 + oc)] = f2bf(v0);
    out[obase + (size_t)((yp * 16 + px + 1) * 16 + oc)] = f2bf(v1);
  }
}

// =================== conv3: bf16 MFMA, writes feat bf16 (unchanged) ===================
__global__ __launch_bounds__(256) void conv3_mfma(
    const u16* __restrict__ in, const float* __restrict__ w,
    const float* __restrict__ bias, u16* __restrict__ feat) {
  constexpr int PW = 20, BS = 40;
  __shared__ __align__(16) u16 ins[PW * PW * 16];
  __shared__ __align__(16) u16 wls[13 * 2 * 16 * BS];
  __shared__ float bls[32];
  const int b = blockIdx.x, m = blockIdx.y, t = threadIdx.x;
  const size_t ibase = (size_t)(b * 3 + m) * 4096;
  for (int i = t; i < PW * PW; i += 256) {
    int y = i / PW, x = i % PW;
    uint4 v0 = {0u, 0u, 0u, 0u}, v1 = {0u, 0u, 0u, 0u};
    if (y >= 2 && y < 18 && x >= 2 && x < 18) {
      const u16* p = &in[ibase + (size_t)((y - 2) * 16 + (x - 2)) * 16];
      v0 = *(const uint4*)p;
      v1 = *(const uint4*)(p + 8);
    }
    *(uint4*)&ins[i * 16] = v0;
    *(uint4*)&ins[i * 16 + 8] = v1;
  }
  for (int i = t; i < 13 * 2 * 16 * 32; i += 256) {
    int k = i & 31, oc16 = (i >> 5) & 15, half = (i >> 9) & 1, st = i >> 10;
    int sl = k >> 4, ci = k & 15, tap = st * 2 + sl;
    int oc = half * 16 + oc16;
    float v = (tap < 25) ? w[((size_t)(m * 32 + oc) * 16 + ci) * 25 + tap] : 0.f;
    wls[((st * 2 + half) * 16 + oc16) * BS + k] = f2bf(v);
  }
  if (t < 32) bls[t] = bias[m * 32 + t];
  __syncthreads();
  const int wv = t >> 6, lane = t & 63;
  const int oc = lane & 15, g = lane >> 4;
  const int sl = g >> 1, ch = (g & 1) * 8;
  u16* fb = feat + (size_t)b * 6144 + m * 2048;
#pragma unroll 1
  for (int task = wv; task < 16; task += 4) {
    const int yp = task >> 1, half = task & 1;
    const int y0 = 2 * yp, x = oc;
    f32x4 acc0 = {0.f, 0.f, 0.f, 0.f}, acc1 = {0.f, 0.f, 0.f, 0.f};
#pragma unroll
    for (int st = 0; st < 13; ++st) {
      bf8v bvv = *(const bf8v*)&wls[(size_t)((st * 2 + half) * 16 + oc) * BS + g * 8];
      int tp = st * 2 + sl; tp = tp > 24 ? 24 : tp;
      int ky = tp / 5, kx = tp % 5;
      bf8v a0 = *(const bf8v*)&ins[(size_t)((y0 + ky) * PW + x + kx) * 16 + ch];
      acc0 = __builtin_amdgcn_mfma_f32_16x16x32_bf16(a0, bvv, acc0, 0, 0, 0);
      bf8v a1 = *(const bf8v*)&ins[(size_t)((y0 + 1 + ky) * PW + x + kx) * 16 + ch];
      acc1 = __builtin_amdgcn_mfma_f32_16x16x32_bf16(a1, bvv, acc1, 0, 0, 0);
    }
    const int ocg = half * 16 + oc;
    const float bb = bls[ocg];
    const float v0 = fmaxf(fmaxf(fmaxf(acc0[0], acc0[1]), fmaxf(acc1[0], acc1[1])) + bb, 0.f);
    const float v1 = fmaxf(fmaxf(fmaxf(acc0[2], acc0[3]), fmaxf(acc1[2], acc1[3])) + bb, 0.f);
    unsigned pack = (unsigned)f2bf(v0) | ((unsigned)f2bf(v1) << 16);
    *(unsigned*)&fb[ocg * 64 + yp * 8 + 2 * g] = pack;
  }
}

// =================== wcvt (unchanged) ===================
__global__ __launch_bounds__(256) void wcvt_kernel(const float* __restrict__ W,
                                                   u16* __restrict__ wT) {
  __shared__ float tile[64][65];
  const int k0 = blockIdx.x * 64, c0 = blockIdx.y * 64, t = threadIdx.x;
  for (int i = t; i < 4096; i += 256) {
    int r = i >> 6, c = i & 63;
    tile[r][c] = W[(size_t)(k0 + r) * 256 + c0 + c];
  }
  __syncthreads();
  for (int i = t; i < 4096; i += 256) {
    int c = i >> 6, k = i & 63;
    wT[(size_t)(c0 + c) * 6144 + k0 + k] = f2bf(tile[k][c]);
  }
}

// =================== lin1: bf16 MFMA GEMM (unchanged) ===================
__global__ __launch_bounds__(256) void lin1_mfma(const u16* __restrict__ feat,
                                                 const u16* __restrict__ wT,
                                                 float* __restrict__ h1p) {
  constexpr int AS = 72;
  __shared__ __align__(16) u16 As[64 * AS];
  __shared__ __align__(16) u16 Bs[64 * AS];
  const int r0 = blockIdx.x * 64, c0 = blockIdx.y * 64, kb = blockIdx.z * 384;
  const int t = threadIdx.x;
  const int w = t >> 6, lane = t & 63;
  const int row16 = lane & 15, kg = lane >> 4;
  f32x4 acc[4] = {{0.f, 0.f, 0.f, 0.f}, {0.f, 0.f, 0.f, 0.f},
                  {0.f, 0.f, 0.f, 0.f}, {0.f, 0.f, 0.f, 0.f}};
  const int lr = t >> 2, lk = (t & 3) * 16;
#pragma unroll 1
  for (int st = 0; st < 6; ++st) {
    __syncthreads();
    const int ks = kb + st * 64;
    {
      const u16* srcA = feat + (size_t)(r0 + lr) * 6144 + ks + lk;
      uint4 a0 = *(const uint4*)srcA;
      uint4 a1 = *(const uint4*)(srcA + 8);
      *(uint4*)&As[lr * AS + lk] = a0;
      *(uint4*)&As[lr * AS + lk + 8] = a1;
      const u16* srcB = wT + (size_t)(c0 + lr) * 6144 + ks + lk;
      uint4 b0 = *(const uint4*)srcB;
      uint4 b1 = *(const uint4*)(srcB + 8);
      *(uint4*)&Bs[lr * AS + lk] = b0;
      *(uint4*)&Bs[lr * AS + lk + 8] = b1;
    }
    __syncthreads();
#pragma unroll
    for (int kk = 0; kk < 2; ++kk) {
      bf8v a = *(const bf8v*)&As[(w * 16 + row16) * AS + kk * 32 + kg * 8];
#pragma unroll
      for (int ct = 0; ct < 4; ++ct) {
        bf8v bb = *(const bf8v*)&Bs[(ct * 16 + row16) * AS + kk * 32 + kg * 8];
        acc[ct] = __builtin_amdgcn_mfma_f32_16x16x32_bf16(a, bb, acc[ct], 0, 0, 0);
      }
    }
  }
  float* out = h1p + (size_t)blockIdx.z * 131072;
#pragma unroll
  for (int ct = 0; ct < 4; ++ct)
#pragma unroll
    for (int j = 0; j < 4; ++j)
      out[(size_t)(r0 + w * 16 + kg * 4 + j) * 256 + c0 + ct * 16 + row16] = acc[ct][j];
}

// =================== head (unchanged) ===================
__global__ __launch_bounds__(256) void head_kernel(
    const float* __restrict__ h1p, const float* __restrict__ b1,
    const float* __restrict__ w2, const float* __restrict__ b2,
    const float* __restrict__ sw, const float* __restrict__ sb,
    float* __restrict__ out) {
  constexpr int HS = 260;
  __shared__ __align__(16) float h1s[16 * HS];
  __shared__ __align__(16) float w2s[256 * 16];
  const int r0 = blockIdx.x * 16, t = threadIdx.x;
  for (int i = t; i < 4096; i += 256) {
    int r = i >> 8, k = i & 255;
    float s = b1[k];
#pragma unroll
    for (int p = 0; p < 16; ++p) s += h1p[(size_t)p * 131072 + (size_t)(r0 + r) * 256 + k];
    h1s[r * HS + k] = s;
    w2s[i] = w2[i];
  }
  __syncthreads();
  const int j = t & 15, r = t >> 4;
  float acc = b2[j];
#pragma unroll 4
  for (int k4 = 0; k4 < 64; ++k4) {
    float4 hv = *(const float4*)&h1s[r * HS + 4 * k4];
    float h0 = fmaxf(hv.x, 0.f), h1v = fmaxf(hv.y, 0.f);
    float h2v = fmaxf(hv.z, 0.f), h3 = fmaxf(hv.w, 0.f);
    acc += h0 * w2s[(4 * k4 + 0) * 16 + j];
    acc += h1v * w2s[(4 * k4 + 1) * 16 + j];
    acc += h2v * w2s[(4 * k4 + 2) * 16 + j];
    acc += h3 * w2s[(4 * k4 + 3) * 16 + j];
  }
  float v = fmaxf(acc, 0.f) * sw[j];
#pragma unroll
  for (int off = 8; off; off >>= 1) v += __shfl_xor(v, off, 16);
  if (j == 0) out[r0 + r] = v + sb[0];
}

// =================== launcher ===================
extern "C" void kernel_launch(void* const* d_in, const int* in_sizes, int n_in,
                              void* d_out, int out_size, void* d_ws, size_t ws_size,
                              hipStream_t stream) {
  const float* x_q = (const float*)d_in[0];
  const float* x_c = (const float*)d_in[1];
  const int* edge_q = (const int*)d_in[2];
  const int* edge_c = (const int*)d_in[3];
  const float* gw1 = (const float*)d_in[4];
  const float* gb1 = (const float*)d_in[5];
  const float* gw2 = (const float*)d_in[6];
  const float* gb2 = (const float*)d_in[7];
  const float* gw3 = (const float*)d_in[8];
  const float* gb3 = (const float*)d_in[9];
  const float* cw1 = (const float*)d_in[10];
  const float* cb1 = (const float*)d_in[11];
  const float* cw2 = (const float*)d_in[12];
  const float* cb2 = (const float*)d_in[13];
  const float* cw3 = (const float*)d_in[14];
  const float* cb3 = (const float*)d_in[15];
  const float* lw1 = (const float*)d_in[16];
  const float* lb1 = (const float*)d_in[17];
  const float* lw2 = (const float*)d_in[18];
  const float* lb2 = (const float*)d_in[19];
  const float* swt = (const float*)d_in[20];
  const float* sbs = (const float*)d_in[21];
  float* ws = (float*)d_ws;

  const size_t o_f1q = 65536;
  const size_t o_f2q = o_f1q + 2097152;
  const size_t o_f3q = o_f2q + 1048576;
  const size_t o_f1c = o_f3q + 524288;
  const size_t o_f2c = o_f1c + 2097152;
  const size_t o_f3c = o_f2c + 1048576;
  const size_t o_sims = o_f3c + 524288;
  const size_t o_pm1 = o_sims + 6291456;
  const size_t o_pm2 = o_pm1 + 6291456;
  const size_t o_wT = o_pm2 + 3145728;
  const size_t o_feat = o_sims;           // bf16 feat
  const size_t o_h1p = o_f1q;             // reuse (f1q dead after simconv1)

  u16* f1q = (u16*)(ws + o_f1q); u16* f2q = (u16*)(ws + o_f2q); u16* f3q = (u16*)(ws + o_f3q);
  u16* f1c = (u16*)(ws + o_f1c); u16* f2c = (u16*)(ws + o_f2c); u16* f3c = (u16*)(ws + o_f3c);
  u16* pm1 = (u16*)(ws + o_pm1);
  u16* pm2 = (u16*)(ws + o_pm2);
  u16* wT = (u16*)(ws + o_wT);
  u16* feat = (u16*)(ws + o_feat);
  float* h1p = ws + o_h1p;

  wcvt_kernel<<<dim3(96, 4), 256, 0, stream>>>(lw1, wT);

  gcn_fused<<<dim3(B, 2), 512, 0, stream>>>(x_q, x_c, gw1, gb1, gw2, gb2, gw3, gb3,
                                            edge_q, edge_c, f1q, f1c, f2q, f2c, f3q, f3c);

  simconv1<<<dim3(B, 3), 256, 0, stream>>>(f1q, f1c, f2q, f2c, f3q, f3c, cw1, cb1, pm1);

  conv2_mfma<<<dim3(B, 3), 256, 0, stream>>>(pm1, cw2, cb2, pm2);
  conv3_mfma<<<dim3(B, 3), 256, 0, stream>>>(pm2, cw3, cb3, feat);

  lin1_mfma<<<dim3(8, 4, 16), 256, 0, stream>>>(feat, wT, h1p);
  head_kernel<<<32, 256, 0, stream>>>(h1p, lb1, lw2, lb2, swt, sbs, (float*)d_out);
}

// Round 10
// 138.327 us; speedup vs baseline: 7.4661x; 1.1717x over previous
//
#include <hip/hip_runtime.h>
#include <hip/hip_bf16.h>

constexpr int B = 512, N = 64, E = 512, NE = B * E;

typedef __attribute__((ext_vector_type(8))) short bf8v;
typedef __attribute__((ext_vector_type(4))) float f32x4;
typedef unsigned short u16;

__device__ __forceinline__ u16 f2bf(float f) {
  unsigned u = __builtin_bit_cast(unsigned, f);
  u += 0x7FFFu + ((u >> 16) & 1u);
  return (u16)(u >> 16);
}

__device__ __forceinline__ int cmin(int a, int b) { return a < b ? a : b; }

// =================== fused 3-layer GCN: 512 threads, bf16 feature output ===================
template <int DIN, int DOUT, bool STORE_NEXT>
__device__ __forceinline__ void gcn_layer(
    float* __restrict__ At, float* __restrict__ Xt, float* __restrict__ Hs,
    float* __restrict__ Wls, const float* __restrict__ W,
    const float* __restrict__ bias, u16* __restrict__ fout, int g, int t) {
  constexpr int XS = 68;
  for (int i = t; i < DIN * DOUT; i += 512) Wls[i] = W[i];
  __syncthreads();
  constexpr int CT = DOUT / 2;  // col-pairs
  const int ct = t % CT, nt = t / CT;
  if (nt < 16) {
    float acc[4][2] = {};
#pragma unroll 4
    for (int k = 0; k < DIN; ++k) {
      float4 xv = *(const float4*)&Xt[k * XS + 4 * nt];
      float2 wv = *(const float2*)&Wls[k * DOUT + 2 * ct];
      float xa[4] = {xv.x, xv.y, xv.z, xv.w};
#pragma unroll
      for (int i = 0; i < 4; ++i) {
        acc[i][0] += xa[i] * wv.x;
        acc[i][1] += xa[i] * wv.y;
      }
    }
#pragma unroll
    for (int i = 0; i < 4; ++i)
      *(float2*)&Hs[(4 * nt + i) * XS + 2 * ct] = make_float2(acc[i][0], acc[i][1]);
  }
  __syncthreads();
  if (nt < 16) {
    float acc[4][2] = {};
#pragma unroll 4
    for (int s = 0; s < N; ++s) {
      float4 av = *(const float4*)&At[s * XS + 4 * nt];
      float2 hv = *(const float2*)&Hs[s * XS + 2 * ct];
      float aa[4] = {av.x, av.y, av.z, av.w};
#pragma unroll
      for (int i = 0; i < 4; ++i) {
        acc[i][0] += aa[i] * hv.x;
        acc[i][1] += aa[i] * hv.y;
      }
    }
    const float2 bv = *(const float2*)&bias[2 * ct];
#pragma unroll
    for (int i = 0; i < 4; ++i) {
      float2 st = make_float2(acc[i][0] + bv.x, acc[i][1] + bv.y);
      unsigned pack = (unsigned)f2bf(st.x) | ((unsigned)f2bf(st.y) << 16);
      *(unsigned*)&fout[(size_t)g * N * DOUT + (size_t)(4 * nt + i) * DOUT + 2 * ct] = pack;
      if (STORE_NEXT) {
        Xt[(2 * ct + 0) * XS + 4 * nt + i] = fmaxf(st.x, 0.f);
        Xt[(2 * ct + 1) * XS + 4 * nt + i] = fmaxf(st.y, 0.f);
      }
    }
  }
  __syncthreads();
}

__global__ __launch_bounds__(512) void gcn_fused(
    const float* __restrict__ xq, const float* __restrict__ xc,
    const float* __restrict__ W1, const float* __restrict__ b1,
    const float* __restrict__ W2, const float* __restrict__ b2,
    const float* __restrict__ W3, const float* __restrict__ b3,
    const int* __restrict__ eq, const int* __restrict__ ec,
    u16* __restrict__ f1q, u16* __restrict__ f1c,
    u16* __restrict__ f2q, u16* __restrict__ f2c,
    u16* __restrict__ f3q, u16* __restrict__ f3c) {
  constexpr int XS = 68;
  __shared__ __align__(16) float At[N * XS];
  __shared__ __align__(16) float Xt[N * XS];
  __shared__ __align__(16) float Hs[N * XS];
  __shared__ __align__(16) float Wls[64 * 32];
  __shared__ float dl[N];
  __shared__ int cnt[N];
  const int g = blockIdx.x, t = threadIdx.x;
  const float* x = blockIdx.y ? xc : xq;
  const int* edges = blockIdx.y ? ec : eq;
  u16* o1 = blockIdx.y ? f1c : f1q;
  u16* o2 = blockIdx.y ? f2c : f2q;
  u16* o3 = blockIdx.y ? f3c : f3q;
  for (int i = t; i < N * 16; i += 512) {
    int n = i / 16, k = i % 16;
    Xt[k * XS + n] = x[(size_t)g * N * 16 + i];
  }
  for (int i = t; i < N * XS; i += 512) At[i] = 0.f;
  if (t < N) cnt[t] = 1;
  __syncthreads();
  const int* srcp = edges + (size_t)g * E;
  const int* dstp = edges + NE + (size_t)g * E;
  for (int j = t; j < E; j += 512) atomicAdd(&cnt[dstp[j] & 63], 1);
  __syncthreads();
  if (t < N) dl[t] = rsqrtf((float)cnt[t]);
  __syncthreads();
  for (int j = t; j < E; j += 512) {
    int s = srcp[j] & 63, d = dstp[j] & 63;
    atomicAdd(&At[s * XS + d], dl[s] * dl[d]);
  }
  if (t < N) atomicAdd(&At[t * XS + t], dl[t] * dl[t]);
  __syncthreads();
  gcn_layer<16, 64, true>(At, Xt, Hs, Wls, W1, b1, o1, g, t);
  gcn_layer<64, 32, true>(At, Xt, Hs, Wls, W2, b2, o2, g, t);
  gcn_layer<32, 16, false>(At, Xt, Hs, Wls, W3, b3, o3, g, t);
}

// =================== fused sim (bf16 MFMA) + conv1 (fp32 VALU, oc-pairs) ===================
__global__ __launch_bounds__(256, 4) void simconv1(
    const u16* __restrict__ f1q, const u16* __restrict__ f1c,
    const u16* __restrict__ f2q, const u16* __restrict__ f2c,
    const u16* __restrict__ f3q, const u16* __restrict__ f3c,
    const float* __restrict__ w, const float* __restrict__ bias,
    u16* __restrict__ out) {
  constexpr int PS = 68, QS = 72;
  __shared__ __align__(16) u16 Qs[64 * QS];
  __shared__ __align__(16) u16 Cs[64 * QS];
  __shared__ __align__(16) float simp[68 * 68];
  __shared__ float wls[25 * 8];  // [tap][oc]
  __shared__ float bls[8];
  const int b = blockIdx.x, m = blockIdx.y, t = threadIdx.x;
  for (int i = t; i < 68 * 68; i += 256) simp[i] = 0.f;
  if (t < 200) {
    int oc = t / 25, tap = t % 25;
    wls[tap * 8 + oc] = w[m * 200 + t];
  }
  if (t < 8) bls[t] = bias[m * 8 + t];
  const u16* fq = (m == 0) ? f1q : (m == 1) ? f2q : f3q;
  const u16* fc = (m == 0) ? f1c : (m == 1) ? f2c : f3c;
  const int D = 64 >> m;          // 64 / 32 / 16
  const int SEG = D >> 3;         // uint4 segments per row: 8/4/2
  for (int i = t; i < 64 * SEG; i += 256) {
    int n = i / SEG, s = i - n * SEG;
    *(uint4*)&Qs[n * QS + s * 8] = *(const uint4*)&fq[(size_t)b * 64 * D + n * D + s * 8];
    *(uint4*)&Cs[n * QS + s * 8] = *(const uint4*)&fc[(size_t)b * 64 * D + n * D + s * 8];
  }
  if (m == 2 && t < 128) {  // zero-pad k=16..31
    int n = t >> 1, s = t & 1;
    uint4 z = {0u, 0u, 0u, 0u};
    *(uint4*)&Qs[n * QS + 16 + s * 8] = z;
    *(uint4*)&Cs[n * QS + 16 + s * 8] = z;
  }
  __syncthreads();
  const int w4 = t >> 6, lane = t & 63;
  const int r16 = lane & 15, kg = lane >> 4;
  const int Kpad = (m == 0) ? 64 : 32;
#pragma unroll 1
  for (int ct = 0; ct < 4; ++ct) {
    f32x4 acc = {0.f, 0.f, 0.f, 0.f};
    for (int ks = 0; ks < Kpad; ks += 32) {
      bf8v a = *(const bf8v*)&Qs[(w4 * 16 + r16) * QS + ks + kg * 8];
      bf8v bb = *(const bf8v*)&Cs[(ct * 16 + r16) * QS + ks + kg * 8];
      acc = __builtin_amdgcn_mfma_f32_16x16x32_bf16(a, bb, acc, 0, 0, 0);
    }
#pragma unroll
    for (int j = 0; j < 4; ++j)
      simp[(w4 * 16 + kg * 4 + j + 2) * PS + ct * 16 + r16 + 2] = acc[j];
  }
  __syncthreads();
  const int gy = t >> 4, gx = t & 15;
  float pr[8][8];
#pragma unroll
  for (int yy = 0; yy < 8; ++yy) {
    float4 a = *(const float4*)&simp[(4 * gy + yy) * PS + 4 * gx];
    float4 bb = *(const float4*)&simp[(4 * gy + yy) * PS + 4 * gx + 4];
    pr[yy][0] = a.x; pr[yy][1] = a.y; pr[yy][2] = a.z; pr[yy][3] = a.w;
    pr[yy][4] = bb.x; pr[yy][5] = bb.y; pr[yy][6] = bb.z; pr[yy][7] = bb.w;
  }
  u16* op = out + (size_t)(b * 3 + m) * 8192;
#pragma unroll 1
  for (int p2 = 0; p2 < 4; ++p2) {
    float acc[2][16];
#pragma unroll
    for (int p = 0; p < 16; ++p) { acc[0][p] = 0.f; acc[1][p] = 0.f; }
#pragma unroll
    for (int ky = 0; ky < 5; ++ky)
#pragma unroll
      for (int kx = 0; kx < 5; ++kx) {
        float2 wv = *(const float2*)&wls[(ky * 5 + kx) * 8 + p2 * 2];
#pragma unroll
        for (int dy = 0; dy < 4; ++dy)
#pragma unroll
          for (int dx = 0; dx < 4; ++dx) {
            float rv = pr[ky + dy][kx + dx];
            acc[0][dy * 4 + dx] += rv * wv.x;
            acc[1][dy * 4 + dx] += rv * wv.y;
          }
      }
    float b0 = bls[p2 * 2], b1 = bls[p2 * 2 + 1];
#pragma unroll
    for (int ay = 0; ay < 2; ++ay)
#pragma unroll
      for (int ax = 0; ax < 2; ++ax) {
        float v0 = fmaxf(fmaxf(acc[0][(2 * ay) * 4 + 2 * ax], acc[0][(2 * ay) * 4 + 2 * ax + 1]),
                         fmaxf(acc[0][(2 * ay + 1) * 4 + 2 * ax], acc[0][(2 * ay + 1) * 4 + 2 * ax + 1]));
        float v1 = fmaxf(fmaxf(acc[1][(2 * ay) * 4 + 2 * ax], acc[1][(2 * ay) * 4 + 2 * ax + 1]),
                         fmaxf(acc[1][(2 * ay + 1) * 4 + 2 * ax], acc[1][(2 * ay + 1) * 4 + 2 * ax + 1]));
        v0 = fmaxf(v0 + b0, 0.f);
        v1 = fmaxf(v1 + b1, 0.f);
        unsigned pack = (unsigned)f2bf(v0) | ((unsigned)f2bf(v1) << 16);
        *(unsigned*)&op[(size_t)(((2 * gy + ay) * 32) + (2 * gx + ax)) * 8 + p2 * 2] = pack;
      }
  }
}

// =================== wprep: conv2/conv3 weights -> bf16, LDS-layout, one-time ===================
__global__ __launch_bounds__(256) void wprep_kernel(const float* __restrict__ cw2,
                                                    const float* __restrict__ cw3,
                                                    u16* __restrict__ w2p,
                                                    u16* __restrict__ w3p) {
  int i = blockIdx.x * 256 + threadIdx.x;
  if (i < 3 * 7 * 16 * 40) {  // w2p: [m][(st*16+oc)*40 + k]
    int m = i / 4480, r = i % 4480;
    int k = r % 40, rest = r / 40, oc = rest & 15, st = rest >> 4;
    u16 v = 0;
    if (k < 32) {
      int sl = k >> 3, ci = k & 7, tap = st * 4 + sl;
      if (tap < 25) v = f2bf(cw2[((size_t)(m * 16 + oc) * 8 + ci) * 25 + tap]);
    }
    w2p[i] = v;
  }
  if (i < 3 * 26 * 16 * 40) {  // w3p: [m][((st*2+half)*16+oc16)*40 + k]
    int m = i / 16640, r = i % 16640;
    int k = r % 40, rest = r / 40, oc16 = rest & 15, sthalf = rest >> 4;
    int half = sthalf & 1, st = sthalf >> 1;
    u16 v = 0;
    if (k < 32) {
      int sl = k >> 4, ci = k & 15, tap = st * 2 + sl;
      int oc = half * 16 + oc16;
      if (tap < 25) v = f2bf(cw3[((size_t)(m * 32 + oc) * 16 + ci) * 25 + tap]);
    }
    w3p[i] = v;
  }
}

// =================== conv2: bf16 MFMA, weight-hoisted, div-free ===================
__global__ __launch_bounds__(256) void conv2_mfma(
    const u16* __restrict__ in, const u16* __restrict__ w2p,
    const float* __restrict__ bias, u16* __restrict__ out) {
  constexpr int PW = 36, BS = 40;
  __shared__ __align__(16) u16 ins[PW * PW * 8];
  __shared__ __align__(16) u16 wls[7 * 16 * BS];
  __shared__ float bls[16];
  const int b = blockIdx.x, m = blockIdx.y, t = threadIdx.x;
  const size_t ibase = (size_t)(b * 3 + m) * 8192;
  for (int i = t; i < PW * PW; i += 256) {
    int y = i / PW, x = i % PW;
    uint4 v = {0u, 0u, 0u, 0u};
    if (y >= 2 && y < 34 && x >= 2 && x < 34)
      v = *(const uint4*)&in[ibase + (size_t)((y - 2) * 32 + (x - 2)) * 8];
    *(uint4*)&ins[i * 8] = v;
  }
  {
    const u16* wsrc = w2p + m * 4480;
    for (int i = t; i < 560; i += 256) *(uint4*)&wls[i * 8] = *(const uint4*)&wsrc[i * 8];
  }
  if (t < 16) bls[t] = bias[m * 16 + t];
  __syncthreads();
  const int wv = t >> 6, lane = t & 63;
  const int oc = lane & 15, g = lane >> 4;
  const int xt = wv & 1, ypb = wv >> 1;  // tasks: yp_j = ypb + 2j, j = 0..7
  const int x = xt * 16 + oc;
  const size_t obase = (size_t)(b * 3 + m) * 4096;
#pragma unroll 1
  for (int grp = 0; grp < 2; ++grp) {
    f32x4 acc[4][2];
#pragma unroll
    for (int i = 0; i < 4; ++i) {
      acc[i][0] = (f32x4){0.f, 0.f, 0.f, 0.f};
      acc[i][1] = (f32x4){0.f, 0.f, 0.f, 0.f};
    }
#pragma unroll
    for (int st = 0; st < 7; ++st) {
      bf8v bvv = *(const bf8v*)&wls[(st * 16 + oc) * BS + g * 8];
      const int c0 = cmin(st * 4 + 0, 24), c1 = cmin(st * 4 + 1, 24);
      const int c2 = cmin(st * 4 + 2, 24), c3 = cmin(st * 4 + 3, 24);
      const int k0 = (c0 / 5) * PW + c0 % 5, k1 = (c1 / 5) * PW + c1 % 5;
      const int k2 = (c2 / 5) * PW + c2 % 5, k3 = (c3 / 5) * PW + c3 % 5;
      const int koff = (g == 0) ? k0 : (g == 1) ? k1 : (g == 2) ? k2 : k3;
#pragma unroll
      for (int i = 0; i < 4; ++i) {
        const int y0 = 2 * ypb + 4 * (grp * 4 + i);
        const int abase = (y0 * PW + x + koff) * 8;
        bf8v a0 = *(const bf8v*)&ins[abase];
        acc[i][0] = __builtin_amdgcn_mfma_f32_16x16x32_bf16(a0, bvv, acc[i][0], 0, 0, 0);
        bf8v a1 = *(const bf8v*)&ins[abase + PW * 8];
        acc[i][1] = __builtin_amdgcn_mfma_f32_16x16x32_bf16(a1, bvv, acc[i][1], 0, 0, 0);
      }
    }
    const float bb = bls[oc];
#pragma unroll
    for (int i = 0; i < 4; ++i) {
      const int yp = ypb + 2 * (grp * 4 + i);
      const float v0 = fmaxf(fmaxf(fmaxf(acc[i][0][0], acc[i][0][1]),
                                   fmaxf(acc[i][1][0], acc[i][1][1])) + bb, 0.f);
      const float v1 = fmaxf(fmaxf(fmaxf(acc[i][0][2], acc[i][0][3]),
                                   fmaxf(acc[i][1][2], acc[i][1][3])) + bb, 0.f);
      const int px = xt * 8 + 2 * g;
      out[obase + (size_t)((yp * 16 + px) * 16 + oc)] = f2bf(v0);
      out[obase + (size_t)((yp * 16 + px + 1) * 16 + oc)] = f2bf(v1);
    }
  }
}

// =================== conv3: bf16 MFMA, weight-hoisted, div-free ===================
__global__ __launch_bounds__(256) void conv3_mfma(
    const u16* __restrict__ in, const u16* __restrict__ w3p,
    const float* __restrict__ bias, u16* __restrict__ feat) {
  constexpr int PW = 20, BS = 40;
  __shared__ __align__(16) u16 ins[PW * PW * 16];
  __shared__ __align__(16) u16 wls[26 * 16 * BS];
  __shared__ float bls[32];
  const int b = blockIdx.x, m = blockIdx.y, t = threadIdx.x;
  const size_t ibase = (size_t)(b * 3 + m) * 4096;
  for (int i = t; i < PW * PW; i += 256) {
    int y = i / PW, x = i % PW;
    uint4 v0 = {0u, 0u, 0u, 0u}, v1 = {0u, 0u, 0u, 0u};
    if (y >= 2 && y < 18 && x >= 2 && x < 18) {
      const u16* p = &in[ibase + (size_t)((y - 2) * 16 + (x - 2)) * 16];
      v0 = *(const uint4*)p;
      v1 = *(const uint4*)(p + 8);
    }
    *(uint4*)&ins[i * 16] = v0;
    *(uint4*)&ins[i * 16 + 8] = v1;
  }
  {
    const u16* wsrc = w3p + m * 16640;
    for (int i = t; i < 2080; i += 256) *(uint4*)&wls[i * 8] = *(const uint4*)&wsrc[i * 8];
  }
  if (t < 32) bls[t] = bias[m * 32 + t];
  __syncthreads();
  const int wv = t >> 6, lane = t & 63;
  const int oc = lane & 15, g = lane >> 4;
  const int sl = g >> 1, ch = (g & 1) * 8;
  const int half = wv & 1, ypb = wv >> 1;  // tasks: yp_i = ypb + 2i, i = 0..3
  u16* fb = feat + (size_t)b * 6144 + m * 2048;
  f32x4 acc[4][2];
#pragma unroll
  for (int i = 0; i < 4; ++i) {
    acc[i][0] = (f32x4){0.f, 0.f, 0.f, 0.f};
    acc[i][1] = (f32x4){0.f, 0.f, 0.f, 0.f};
  }
#pragma unroll
  for (int st = 0; st < 13; ++st) {
    bf8v bvv = *(const bf8v*)&wls[(size_t)((st * 2 + half) * 16 + oc) * BS + g * 8];
    const int c0 = cmin(st * 2 + 0, 24), c1 = cmin(st * 2 + 1, 24);
    const int k0 = (c0 / 5) * PW + c0 % 5, k1 = (c1 / 5) * PW + c1 % 5;
    const int koff = sl ? k1 : k0;
#pragma unroll
    for (int i = 0; i < 4; ++i) {
      const int y0 = 2 * ypb + 4 * i;
      const int abase = (y0 * PW + oc + koff) * 16 + ch;
      bf8v a0 = *(const bf8v*)&ins[abase];
      acc[i][0] = __builtin_amdgcn_mfma_f32_16x16x32_bf16(a0, bvv, acc[i][0], 0, 0, 0);
      bf8v a1 = *(const bf8v*)&ins[abase + PW * 16];
      acc[i][1] = __builtin_amdgcn_mfma_f32_16x16x32_bf16(a1, bvv, acc[i][1], 0, 0, 0);
    }
  }
  const int ocg = half * 16 + oc;
  const float bb = bls[ocg];
#pragma unroll
  for (int i = 0; i < 4; ++i) {
    const int yp = ypb + 2 * i;
    const float v0 = fmaxf(fmaxf(fmaxf(acc[i][0][0], acc[i][0][1]),
                                 fmaxf(acc[i][1][0], acc[i][1][1])) + bb, 0.f);
    const float v1 = fmaxf(fmaxf(fmaxf(acc[i][0][2], acc[i][0][3]),
                                 fmaxf(acc[i][1][2], acc[i][1][3])) + bb, 0.f);
    unsigned pack = (unsigned)f2bf(v0) | ((unsigned)f2bf(v1) << 16);
    *(unsigned*)&fb[ocg * 64 + yp * 8 + 2 * g] = pack;
  }
}

// =================== wcvt (unchanged) ===================
__global__ __launch_bounds__(256) void wcvt_kernel(const float* __restrict__ W,
                                                   u16* __restrict__ wT) {
  __shared__ float tile[64][65];
  const int k0 = blockIdx.x * 64, c0 = blockIdx.y * 64, t = threadIdx.x;
  for (int i = t; i < 4096; i += 256) {
    int r = i >> 6, c = i & 63;
    tile[r][c] = W[(size_t)(k0 + r) * 256 + c0 + c];
  }
  __syncthreads();
  for (int i = t; i < 4096; i += 256) {
    int c = i >> 6, k = i & 63;
    wT[(size_t)(c0 + c) * 6144 + k0 + k] = f2bf(tile[k][c]);
  }
}

// =================== lin1: bf16 MFMA GEMM (unchanged) ===================
__global__ __launch_bounds__(256) void lin1_mfma(const u16* __restrict__ feat,
                                                 const u16* __restrict__ wT,
                                                 float* __restrict__ h1p) {
  constexpr int AS = 72;
  __shared__ __align__(16) u16 As[64 * AS];
  __shared__ __align__(16) u16 Bs[64 * AS];
  const int r0 = blockIdx.x * 64, c0 = blockIdx.y * 64, kb = blockIdx.z * 384;
  const int t = threadIdx.x;
  const int w = t >> 6, lane = t & 63;
  const int row16 = lane & 15, kg = lane >> 4;
  f32x4 acc[4] = {{0.f, 0.f, 0.f, 0.f}, {0.f, 0.f, 0.f, 0.f},
                  {0.f, 0.f, 0.f, 0.f}, {0.f, 0.f, 0.f, 0.f}};
  const int lr = t >> 2, lk = (t & 3) * 16;
#pragma unroll 1
  for (int st = 0; st < 6; ++st) {
    __syncthreads();
    const int ks = kb + st * 64;
    {
      const u16* srcA = feat + (size_t)(r0 + lr) * 6144 + ks + lk;
      uint4 a0 = *(const uint4*)srcA;
      uint4 a1 = *(const uint4*)(srcA + 8);
      *(uint4*)&As[lr * AS + lk] = a0;
      *(uint4*)&As[lr * AS + lk + 8] = a1;
      const u16* srcB = wT + (size_t)(c0 + lr) * 6144 + ks + lk;
      uint4 b0 = *(const uint4*)srcB;
      uint4 b1 = *(const uint4*)(srcB + 8);
      *(uint4*)&Bs[lr * AS + lk] = b0;
      *(uint4*)&Bs[lr * AS + lk + 8] = b1;
    }
    __syncthreads();
#pragma unroll
    for (int kk = 0; kk < 2; ++kk) {
      bf8v a = *(const bf8v*)&As[(w * 16 + row16) * AS + kk * 32 + kg * 8];
#pragma unroll
      for (int ct = 0; ct < 4; ++ct) {
        bf8v bb = *(const bf8v*)&Bs[(ct * 16 + row16) * AS + kk * 32 + kg * 8];
        acc[ct] = __builtin_amdgcn_mfma_f32_16x16x32_bf16(a, bb, acc[ct], 0, 0, 0);
      }
    }
  }
  float* out = h1p + (size_t)blockIdx.z * 131072;
#pragma unroll
  for (int ct = 0; ct < 4; ++ct)
#pragma unroll
    for (int j = 0; j < 4; ++j)
      out[(size_t)(r0 + w * 16 + kg * 4 + j) * 256 + c0 + ct * 16 + row16] = acc[ct][j];
}

// =================== head (unchanged) ===================
__global__ __launch_bounds__(256) void head_kernel(
    const float* __restrict__ h1p, const float* __restrict__ b1,
    const float* __restrict__ w2, const float* __restrict__ b2,
    const float* __restrict__ sw, const float* __restrict__ sb,
    float* __restrict__ out) {
  constexpr int HS = 260;
  __shared__ __align__(16) float h1s[16 * HS];
  __shared__ __align__(16) float w2s[256 * 16];
  const int r0 = blockIdx.x * 16, t = threadIdx.x;
  for (int i = t; i < 4096; i += 256) {
    int r = i >> 8, k = i & 255;
    float s = b1[k];
#pragma unroll
    for (int p = 0; p < 16; ++p) s += h1p[(size_t)p * 131072 + (size_t)(r0 + r) * 256 + k];
    h1s[r * HS + k] = s;
    w2s[i] = w2[i];
  }
  __syncthreads();
  const int j = t & 15, r = t >> 4;
  float acc = b2[j];
#pragma unroll 4
  for (int k4 = 0; k4 < 64; ++k4) {
    float4 hv = *(const float4*)&h1s[r * HS + 4 * k4];
    float h0 = fmaxf(hv.x, 0.f), h1v = fmaxf(hv.y, 0.f);
    float h2v = fmaxf(hv.z, 0.f), h3 = fmaxf(hv.w, 0.f);
    acc += h0 * w2s[(4 * k4 + 0) * 16 + j];
    acc += h1v * w2s[(4 * k4 + 1) * 16 + j];
    acc += h2v * w2s[(4 * k4 + 2) * 16 + j];
    acc += h3 * w2s[(4 * k4 + 3) * 16 + j];
  }
  float v = fmaxf(acc, 0.f) * sw[j];
#pragma unroll
  for (int off = 8; off; off >>= 1) v += __shfl_xor(v, off, 16);
  if (j == 0) out[r0 + r] = v + sb[0];
}

// =================== launcher ===================
extern "C" void kernel_launch(void* const* d_in, const int* in_sizes, int n_in,
                              void* d_out, int out_size, void* d_ws, size_t ws_size,
                              hipStream_t stream) {
  const float* x_q = (const float*)d_in[0];
  const float* x_c = (const float*)d_in[1];
  const int* edge_q = (const int*)d_in[2];
  const int* edge_c = (const int*)d_in[3];
  const float* gw1 = (const float*)d_in[4];
  const float* gb1 = (const float*)d_in[5];
  const float* gw2 = (const float*)d_in[6];
  const float* gb2 = (const float*)d_in[7];
  const float* gw3 = (const float*)d_in[8];
  const float* gb3 = (const float*)d_in[9];
  const float* cw1 = (const float*)d_in[10];
  const float* cb1 = (const float*)d_in[11];
  const float* cw2 = (const float*)d_in[12];
  const float* cb2 = (const float*)d_in[13];
  const float* cw3 = (const float*)d_in[14];
  const float* cb3 = (const float*)d_in[15];
  const float* lw1 = (const float*)d_in[16];
  const float* lb1 = (const float*)d_in[17];
  const float* lw2 = (const float*)d_in[18];
  const float* lb2 = (const float*)d_in[19];
  const float* swt = (const float*)d_in[20];
  const float* sbs = (const float*)d_in[21];
  float* ws = (float*)d_ws;

  const size_t o_f1q = 65536;
  const size_t o_f2q = o_f1q + 2097152;
  const size_t o_f3q = o_f2q + 1048576;
  const size_t o_f1c = o_f3q + 524288;
  const size_t o_f2c = o_f1c + 2097152;
  const size_t o_f3c = o_f2c + 1048576;
  const size_t o_sims = o_f3c + 524288;
  const size_t o_pm1 = o_sims + 6291456;
  const size_t o_pm2 = o_pm1 + 6291456;
  const size_t o_wT = o_pm2 + 3145728;
  const size_t o_w2p = o_wT + 786432;     // 13440 u16 -> 6720 floats (pad 8192)
  const size_t o_w3p = o_w2p + 8192;      // 49920 u16 -> 24960 floats (pad 32768)
  const size_t o_feat = o_sims;           // bf16 feat
  const size_t o_h1p = o_f1q;             // reuse (f1q dead after simconv1)

  u16* f1q = (u16*)(ws + o_f1q); u16* f2q = (u16*)(ws + o_f2q); u16* f3q = (u16*)(ws + o_f3q);
  u16* f1c = (u16*)(ws + o_f1c); u16* f2c = (u16*)(ws + o_f2c); u16* f3c = (u16*)(ws + o_f3c);
  u16* pm1 = (u16*)(ws + o_pm1);
  u16* pm2 = (u16*)(ws + o_pm2);
  u16* wT = (u16*)(ws + o_wT);
  u16* w2p = (u16*)(ws + o_w2p);
  u16* w3p = (u16*)(ws + o_w3p);
  u16* feat = (u16*)(ws + o_feat);
  float* h1p = ws + o_h1p;

  wcvt_kernel<<<dim3(96, 4), 256, 0, stream>>>(lw1, wT);
  wprep_kernel<<<196, 256, 0, stream>>>(cw2, cw3, w2p, w3p);

  gcn_fused<<<dim3(B, 2), 512, 0, stream>>>(x_q, x_c, gw1, gb1, gw2, gb2, gw3, gb3,
                                            edge_q, edge_c, f1q, f1c, f2q, f2c, f3q, f3c);

  simconv1<<<dim3(B, 3), 256, 0, stream>>>(f1q, f1c, f2q, f2c, f3q, f3c, cw1, cb1, pm1);

  conv2_mfma<<<dim3(B, 3), 256, 0, stream>>>(pm1, w2p, cb2, pm2);
  conv3_mfma<<<dim3(B, 3), 256, 0, stream>>>(pm2, w3p, cb3, feat);

  lin1_mfma<<<dim3(8, 4, 16), 256, 0, stream>>>(feat, wT, h1p);
  head_kernel<<<32, 256, 0, stream>>>(h1p, lb1, lw2, lb2, swt, sbs, (float*)d_out);
}

// Round 11
// 136.693 us; speedup vs baseline: 7.5553x; 1.0120x over previous
//
#include <hip/hip_runtime.h>
#include <hip/hip_bf16.h>

constexpr int B = 512, N = 64, E = 512, NE = B * E;

typedef __attribute__((ext_vector_type(8))) short bf8v;
typedef __attribute__((ext_vector_type(4))) float f32x4;
typedef unsigned short u16;

__device__ __forceinline__ u16 f2bf(float f) {
  unsigned u = __builtin_bit_cast(unsigned, f);
  u += 0x7FFFu + ((u >> 16) & 1u);
  return (u16)(u >> 16);
}

__device__ __forceinline__ int cmin(int a, int b) { return a < b ? a : b; }

// =================== fused 3-layer GCN: 512 threads, all-thread layers, no Wls ===================
template <int DIN, int DOUT, int NR, int NC, bool STORE_NEXT>
__device__ __forceinline__ void gcn_layer(
    float* __restrict__ At, float* __restrict__ Xt, float* __restrict__ Hs,
    const float* __restrict__ W, const float* __restrict__ bias,
    u16* __restrict__ fout, int g, int t) {
  constexpr int XS = 68;
  constexpr int CT = DOUT / NC;
  static_assert((64 / NR) * CT == 512, "thread mapping");
  const int ct = t % CT, nt = t / CT;
  const int n0 = NR * nt, c0 = NC * ct;
  // mm1: Hs[n][c] = sum_k Xt[k][n] * W[k][c]
  {
    float acc[NR][NC] = {};
#pragma unroll 4
    for (int k = 0; k < DIN; ++k) {
      float xa[NR];
      if constexpr (NR == 4) {
        float4 xv = *(const float4*)&Xt[k * XS + n0];
        xa[0] = xv.x; xa[1] = xv.y; xa[2] = xv.z; xa[3] = xv.w;
      } else {
        float2 xv = *(const float2*)&Xt[k * XS + n0];
        xa[0] = xv.x; xa[1] = xv.y;
      }
      float wa[NC];
      if constexpr (NC == 2) {
        float2 wv = *(const float2*)&W[k * DOUT + c0];
        wa[0] = wv.x; wa[1] = wv.y;
      } else {
        wa[0] = W[k * DOUT + c0];
      }
#pragma unroll
      for (int i = 0; i < NR; ++i)
#pragma unroll
        for (int j = 0; j < NC; ++j) acc[i][j] += xa[i] * wa[j];
    }
#pragma unroll
    for (int i = 0; i < NR; ++i) {
      if constexpr (NC == 2)
        *(float2*)&Hs[(n0 + i) * XS + c0] = make_float2(acc[i][0], acc[i][1]);
      else
        Hs[(n0 + i) * XS + c0] = acc[i][0];
    }
  }
  __syncthreads();
  // mm2: out[d][c] = sum_s At[s][d] * Hs[s][c] + bias[c]
  {
    float acc[NR][NC] = {};
#pragma unroll 4
    for (int s = 0; s < N; ++s) {
      float aa[NR];
      if constexpr (NR == 4) {
        float4 av = *(const float4*)&At[s * XS + n0];
        aa[0] = av.x; aa[1] = av.y; aa[2] = av.z; aa[3] = av.w;
      } else {
        float2 av = *(const float2*)&At[s * XS + n0];
        aa[0] = av.x; aa[1] = av.y;
      }
      float ha[NC];
      if constexpr (NC == 2) {
        float2 hv = *(const float2*)&Hs[s * XS + c0];
        ha[0] = hv.x; ha[1] = hv.y;
      } else {
        ha[0] = Hs[s * XS + c0];
      }
#pragma unroll
      for (int i = 0; i < NR; ++i)
#pragma unroll
        for (int j = 0; j < NC; ++j) acc[i][j] += aa[i] * ha[j];
    }
    float bv[NC];
#pragma unroll
    for (int j = 0; j < NC; ++j) bv[j] = bias[c0 + j];
#pragma unroll
    for (int i = 0; i < NR; ++i) {
      float st[NC];
#pragma unroll
      for (int j = 0; j < NC; ++j) st[j] = acc[i][j] + bv[j];
      if constexpr (NC == 2) {
        unsigned pack = (unsigned)f2bf(st[0]) | ((unsigned)f2bf(st[1]) << 16);
        *(unsigned*)&fout[(size_t)g * N * DOUT + (size_t)(n0 + i) * DOUT + c0] = pack;
      } else {
        fout[(size_t)g * N * DOUT + (size_t)(n0 + i) * DOUT + c0] = f2bf(st[0]);
      }
      if (STORE_NEXT) {
#pragma unroll
        for (int j = 0; j < NC; ++j)
          Xt[(c0 + j) * XS + n0 + i] = fmaxf(st[j], 0.f);
      }
    }
  }
  __syncthreads();
}

__global__ __launch_bounds__(512) void gcn_fused(
    const float* __restrict__ xq, const float* __restrict__ xc,
    const float* __restrict__ W1, const float* __restrict__ b1,
    const float* __restrict__ W2, const float* __restrict__ b2,
    const float* __restrict__ W3, const float* __restrict__ b3,
    const int* __restrict__ eq, const int* __restrict__ ec,
    u16* __restrict__ f1q, u16* __restrict__ f1c,
    u16* __restrict__ f2q, u16* __restrict__ f2c,
    u16* __restrict__ f3q, u16* __restrict__ f3c) {
  constexpr int XS = 68;
  __shared__ __align__(16) float At[N * XS];
  __shared__ __align__(16) float Xt[N * XS];
  __shared__ __align__(16) float Hs[N * XS];
  __shared__ float dl[N];
  __shared__ int cnt[N];
  const int g = blockIdx.x, t = threadIdx.x;
  const float* x = blockIdx.y ? xc : xq;
  const int* edges = blockIdx.y ? ec : eq;
  u16* o1 = blockIdx.y ? f1c : f1q;
  u16* o2 = blockIdx.y ? f2c : f2q;
  u16* o3 = blockIdx.y ? f3c : f3q;
  for (int i = t; i < N * 16; i += 512) {
    int n = i / 16, k = i % 16;
    Xt[k * XS + n] = x[(size_t)g * N * 16 + i];
  }
  for (int i = t; i < N * XS; i += 512) At[i] = 0.f;
  if (t < N) cnt[t] = 1;
  __syncthreads();
  const int* srcp = edges + (size_t)g * E;
  const int* dstp = edges + NE + (size_t)g * E;
  for (int j = t; j < E; j += 512) atomicAdd(&cnt[dstp[j] & 63], 1);
  __syncthreads();
  if (t < N) dl[t] = rsqrtf((float)cnt[t]);
  __syncthreads();
  for (int j = t; j < E; j += 512) {
    int s = srcp[j] & 63, d = dstp[j] & 63;
    atomicAdd(&At[s * XS + d], dl[s] * dl[d]);
  }
  if (t < N) atomicAdd(&At[t * XS + t], dl[t] * dl[t]);
  __syncthreads();
  gcn_layer<16, 64, 4, 2, true>(At, Xt, Hs, W1, b1, o1, g, t);
  gcn_layer<64, 32, 4, 1, true>(At, Xt, Hs, W2, b2, o2, g, t);
  gcn_layer<32, 16, 2, 1, false>(At, Xt, Hs, W3, b3, o3, g, t);
}

// =================== fused sim (bf16 MFMA) + conv1 (fp32 VALU, oc-pairs) ===================
__global__ __launch_bounds__(256, 4) void simconv1(
    const u16* __restrict__ f1q, const u16* __restrict__ f1c,
    const u16* __restrict__ f2q, const u16* __restrict__ f2c,
    const u16* __restrict__ f3q, const u16* __restrict__ f3c,
    const float* __restrict__ w, const float* __restrict__ bias,
    u16* __restrict__ out) {
  constexpr int PS = 68, QS = 72;
  __shared__ __align__(16) u16 Qs[64 * QS];
  __shared__ __align__(16) u16 Cs[64 * QS];
  __shared__ __align__(16) float simp[68 * 68];
  __shared__ float wls[25 * 8];  // [tap][oc]
  __shared__ float bls[8];
  const int b = blockIdx.x, m = blockIdx.y, t = threadIdx.x;
  for (int i = t; i < 68 * 68; i += 256) simp[i] = 0.f;
  if (t < 200) {
    int oc = t / 25, tap = t % 25;
    wls[tap * 8 + oc] = w[m * 200 + t];
  }
  if (t < 8) bls[t] = bias[m * 8 + t];
  const u16* fq = (m == 0) ? f1q : (m == 1) ? f2q : f3q;
  const u16* fc = (m == 0) ? f1c : (m == 1) ? f2c : f3c;
  const int D = 64 >> m;
  const int SEG = D >> 3;
  for (int i = t; i < 64 * SEG; i += 256) {
    int n = i / SEG, s = i - n * SEG;
    *(uint4*)&Qs[n * QS + s * 8] = *(const uint4*)&fq[(size_t)b * 64 * D + n * D + s * 8];
    *(uint4*)&Cs[n * QS + s * 8] = *(const uint4*)&fc[(size_t)b * 64 * D + n * D + s * 8];
  }
  if (m == 2 && t < 128) {
    int n = t >> 1, s = t & 1;
    uint4 z = {0u, 0u, 0u, 0u};
    *(uint4*)&Qs[n * QS + 16 + s * 8] = z;
    *(uint4*)&Cs[n * QS + 16 + s * 8] = z;
  }
  __syncthreads();
  const int w4 = t >> 6, lane = t & 63;
  const int r16 = lane & 15, kg = lane >> 4;
  const int Kpad = (m == 0) ? 64 : 32;
#pragma unroll 1
  for (int ct = 0; ct < 4; ++ct) {
    f32x4 acc = {0.f, 0.f, 0.f, 0.f};
    for (int ks = 0; ks < Kpad; ks += 32) {
      bf8v a = *(const bf8v*)&Qs[(w4 * 16 + r16) * QS + ks + kg * 8];
      bf8v bb = *(const bf8v*)&Cs[(ct * 16 + r16) * QS + ks + kg * 8];
      acc = __builtin_amdgcn_mfma_f32_16x16x32_bf16(a, bb, acc, 0, 0, 0);
    }
#pragma unroll
    for (int j = 0; j < 4; ++j)
      simp[(w4 * 16 + kg * 4 + j + 2) * PS + ct * 16 + r16 + 2] = acc[j];
  }
  __syncthreads();
  const int gy = t >> 4, gx = t & 15;
  float pr[8][8];
#pragma unroll
  for (int yy = 0; yy < 8; ++yy) {
    float4 a = *(const float4*)&simp[(4 * gy + yy) * PS + 4 * gx];
    float4 bb = *(const float4*)&simp[(4 * gy + yy) * PS + 4 * gx + 4];
    pr[yy][0] = a.x; pr[yy][1] = a.y; pr[yy][2] = a.z; pr[yy][3] = a.w;
    pr[yy][4] = bb.x; pr[yy][5] = bb.y; pr[yy][6] = bb.z; pr[yy][7] = bb.w;
  }
  u16* op = out + (size_t)(b * 3 + m) * 8192;
#pragma unroll 1
  for (int p2 = 0; p2 < 4; ++p2) {
    float acc[2][16];
#pragma unroll
    for (int p = 0; p < 16; ++p) { acc[0][p] = 0.f; acc[1][p] = 0.f; }
#pragma unroll
    for (int ky = 0; ky < 5; ++ky)
#pragma unroll
      for (int kx = 0; kx < 5; ++kx) {
        float2 wv = *(const float2*)&wls[(ky * 5 + kx) * 8 + p2 * 2];
#pragma unroll
        for (int dy = 0; dy < 4; ++dy)
#pragma unroll
          for (int dx = 0; dx < 4; ++dx) {
            float rv = pr[ky + dy][kx + dx];
            acc[0][dy * 4 + dx] += rv * wv.x;
            acc[1][dy * 4 + dx] += rv * wv.y;
          }
      }
    float b0 = bls[p2 * 2], b1 = bls[p2 * 2 + 1];
#pragma unroll
    for (int ay = 0; ay < 2; ++ay)
#pragma unroll
      for (int ax = 0; ax < 2; ++ax) {
        float v0 = fmaxf(fmaxf(acc[0][(2 * ay) * 4 + 2 * ax], acc[0][(2 * ay) * 4 + 2 * ax + 1]),
                         fmaxf(acc[0][(2 * ay + 1) * 4 + 2 * ax], acc[0][(2 * ay + 1) * 4 + 2 * ax + 1]));
        float v1 = fmaxf(fmaxf(acc[1][(2 * ay) * 4 + 2 * ax], acc[1][(2 * ay) * 4 + 2 * ax + 1]),
                         fmaxf(acc[1][(2 * ay + 1) * 4 + 2 * ax], acc[1][(2 * ay + 1) * 4 + 2 * ax + 1]));
        v0 = fmaxf(v0 + b0, 0.f);
        v1 = fmaxf(v1 + b1, 0.f);
        unsigned pack = (unsigned)f2bf(v0) | ((unsigned)f2bf(v1) << 16);
        *(unsigned*)&op[(size_t)(((2 * gy + ay) * 32) + (2 * gx + ax)) * 8 + p2 * 2] = pack;
      }
  }
}

// =================== prep: wcvt (blocks 0..383) + wprep (blocks 384..579) ===================
__global__ __launch_bounds__(256) void prep_kernel(
    const float* __restrict__ lw1, const float* __restrict__ cw2,
    const float* __restrict__ cw3, u16* __restrict__ wT,
    u16* __restrict__ w2p, u16* __restrict__ w3p) {
  const int t = threadIdx.x;
  if (blockIdx.x < 384) {
    __shared__ float tile[64][65];
    const int k0 = (blockIdx.x % 96) * 64, c0 = (blockIdx.x / 96) * 64;
    for (int i = t; i < 4096; i += 256) {
      int r = i >> 6, c = i & 63;
      tile[r][c] = lw1[(size_t)(k0 + r) * 256 + c0 + c];
    }
    __syncthreads();
    for (int i = t; i < 4096; i += 256) {
      int c = i >> 6, k = i & 63;
      wT[(size_t)(c0 + c) * 6144 + k0 + k] = f2bf(tile[k][c]);
    }
    return;
  }
  int i = (blockIdx.x - 384) * 256 + t;
  if (i < 3 * 7 * 16 * 40) {  // w2p: [m][(st*16+oc)*40 + k]
    int m = i / 4480, r = i % 4480;
    int k = r % 40, rest = r / 40, oc = rest & 15, st = rest >> 4;
    u16 v = 0;
    if (k < 32) {
      int sl = k >> 3, ci = k & 7, tap = st * 4 + sl;
      if (tap < 25) v = f2bf(cw2[((size_t)(m * 16 + oc) * 8 + ci) * 25 + tap]);
    }
    w2p[i] = v;
  }
  if (i < 3 * 26 * 16 * 40) {  // w3p: [m][((st*2+half)*16+oc16)*40 + k]
    int m = i / 16640, r = i % 16640;
    int k = r % 40, rest = r / 40, oc16 = rest & 15, sthalf = rest >> 4;
    int half = sthalf & 1, st = sthalf >> 1;
    u16 v = 0;
    if (k < 32) {
      int sl = k >> 4, ci = k & 15, tap = st * 2 + sl;
      int oc = half * 16 + oc16;
      if (tap < 25) v = f2bf(cw3[((size_t)(m * 32 + oc) * 16 + ci) * 25 + tap]);
    }
    w3p[i] = v;
  }
}

// =================== conv2: bf16 MFMA, weight-hoisted, div-free (unchanged) ===================
__global__ __launch_bounds__(256) void conv2_mfma(
    const u16* __restrict__ in, const u16* __restrict__ w2p,
    const float* __restrict__ bias, u16* __restrict__ out) {
  constexpr int PW = 36, BS = 40;
  __shared__ __align__(16) u16 ins[PW * PW * 8];
  __shared__ __align__(16) u16 wls[7 * 16 * BS];
  __shared__ float bls[16];
  const int b = blockIdx.x, m = blockIdx.y, t = threadIdx.x;
  const size_t ibase = (size_t)(b * 3 + m) * 8192;
  for (int i = t; i < PW * PW; i += 256) {
    int y = i / PW, x = i % PW;
    uint4 v = {0u, 0u, 0u, 0u};
    if (y >= 2 && y < 34 && x >= 2 && x < 34)
      v = *(const uint4*)&in[ibase + (size_t)((y - 2) * 32 + (x - 2)) * 8];
    *(uint4*)&ins[i * 8] = v;
  }
  {
    const u16* wsrc = w2p + m * 4480;
    for (int i = t; i < 560; i += 256) *(uint4*)&wls[i * 8] = *(const uint4*)&wsrc[i * 8];
  }
  if (t < 16) bls[t] = bias[m * 16 + t];
  __syncthreads();
  const int wv = t >> 6, lane = t & 63;
  const int oc = lane & 15, g = lane >> 4;
  const int xt = wv & 1, ypb = wv >> 1;
  const int x = xt * 16 + oc;
  const size_t obase = (size_t)(b * 3 + m) * 4096;
#pragma unroll 1
  for (int grp = 0; grp < 2; ++grp) {
    f32x4 acc[4][2];
#pragma unroll
    for (int i = 0; i < 4; ++i) {
      acc[i][0] = (f32x4){0.f, 0.f, 0.f, 0.f};
      acc[i][1] = (f32x4){0.f, 0.f, 0.f, 0.f};
    }
#pragma unroll
    for (int st = 0; st < 7; ++st) {
      bf8v bvv = *(const bf8v*)&wls[(st * 16 + oc) * BS + g * 8];
      const int c0 = cmin(st * 4 + 0, 24), c1 = cmin(st * 4 + 1, 24);
      const int c2 = cmin(st * 4 + 2, 24), c3 = cmin(st * 4 + 3, 24);
      const int k0 = (c0 / 5) * PW + c0 % 5, k1 = (c1 / 5) * PW + c1 % 5;
      const int k2 = (c2 / 5) * PW + c2 % 5, k3 = (c3 / 5) * PW + c3 % 5;
      const int koff = (g == 0) ? k0 : (g == 1) ? k1 : (g == 2) ? k2 : k3;
#pragma unroll
      for (int i = 0; i < 4; ++i) {
        const int y0 = 2 * ypb + 4 * (grp * 4 + i);
        const int abase = (y0 * PW + x + koff) * 8;
        bf8v a0 = *(const bf8v*)&ins[abase];
        acc[i][0] = __builtin_amdgcn_mfma_f32_16x16x32_bf16(a0, bvv, acc[i][0], 0, 0, 0);
        bf8v a1 = *(const bf8v*)&ins[abase + PW * 8];
        acc[i][1] = __builtin_amdgcn_mfma_f32_16x16x32_bf16(a1, bvv, acc[i][1], 0, 0, 0);
      }
    }
    const float bb = bls[oc];
#pragma unroll
    for (int i = 0; i < 4; ++i) {
      const int yp = ypb + 2 * (grp * 4 + i);
      const float v0 = fmaxf(fmaxf(fmaxf(acc[i][0][0], acc[i][0][1]),
                                   fmaxf(acc[i][1][0], acc[i][1][1])) + bb, 0.f);
      const float v1 = fmaxf(fmaxf(fmaxf(acc[i][0][2], acc[i][0][3]),
                                   fmaxf(acc[i][1][2], acc[i][1][3])) + bb, 0.f);
      const int px = xt * 8 + 2 * g;
      out[obase + (size_t)((yp * 16 + px) * 16 + oc)] = f2bf(v0);
      out[obase + (size_t)((yp * 16 + px + 1) * 16 + oc)] = f2bf(v1);
    }
  }
}

// =================== conv3: bf16 MFMA, weight-hoisted, div-free (unchanged) ===================
__global__ __launch_bounds__(256) void conv3_mfma(
    const u16* __restrict__ in, const u16* __restrict__ w3p,
    const float* __restrict__ bias, u16* __restrict__ feat) {
  constexpr int PW = 20, BS = 40;
  __shared__ __align__(16) u16 ins[PW * PW * 16];
  __shared__ __align__(16) u16 wls[26 * 16 * BS];
  __shared__ float bls[32];
  const int b = blockIdx.x, m = blockIdx.y, t = threadIdx.x;
  const size_t ibase = (size_t)(b * 3 + m) * 4096;
  for (int i = t; i < PW * PW; i += 256) {
    int y = i / PW, x = i % PW;
    uint4 v0 = {0u, 0u, 0u, 0u}, v1 = {0u, 0u, 0u, 0u};
    if (y >= 2 && y < 18 && x >= 2 && x < 18) {
      const u16* p = &in[ibase + (size_t)((y - 2) * 16 + (x - 2)) * 16];
      v0 = *(const uint4*)p;
      v1 = *(const uint4*)(p + 8);
    }
    *(uint4*)&ins[i * 16] = v0;
    *(uint4*)&ins[i * 16 + 8] = v1;
  }
  {
    const u16* wsrc = w3p + m * 16640;
    for (int i = t; i < 2080; i += 256) *(uint4*)&wls[i * 8] = *(const uint4*)&wsrc[i * 8];
  }
  if (t < 32) bls[t] = bias[m * 32 + t];
  __syncthreads();
  const int wv = t >> 6, lane = t & 63;
  const int oc = lane & 15, g = lane >> 4;
  const int sl = g >> 1, ch = (g & 1) * 8;
  const int half = wv & 1, ypb = wv >> 1;
  u16* fb = feat + (size_t)b * 6144 + m * 2048;
  f32x4 acc[4][2];
#pragma unroll
  for (int i = 0; i < 4; ++i) {
    acc[i][0] = (f32x4){0.f, 0.f, 0.f, 0.f};
    acc[i][1] = (f32x4){0.f, 0.f, 0.f, 0.f};
  }
#pragma unroll
  for (int st = 0; st < 13; ++st) {
    bf8v bvv = *(const bf8v*)&wls[(size_t)((st * 2 + half) * 16 + oc) * BS + g * 8];
    const int c0 = cmin(st * 2 + 0, 24), c1 = cmin(st * 2 + 1, 24);
    const int k0 = (c0 / 5) * PW + c0 % 5, k1 = (c1 / 5) * PW + c1 % 5;
    const int koff = sl ? k1 : k0;
#pragma unroll
    for (int i = 0; i < 4; ++i) {
      const int y0 = 2 * ypb + 4 * i;
      const int abase = (y0 * PW + oc + koff) * 16 + ch;
      bf8v a0 = *(const bf8v*)&ins[abase];
      acc[i][0] = __builtin_amdgcn_mfma_f32_16x16x32_bf16(a0, bvv, acc[i][0], 0, 0, 0);
      bf8v a1 = *(const bf8v*)&ins[abase + PW * 16];
      acc[i][1] = __builtin_amdgcn_mfma_f32_16x16x32_bf16(a1, bvv, acc[i][1], 0, 0, 0);
    }
  }
  const int ocg = half * 16 + oc;
  const float bb = bls[ocg];
#pragma unroll
  for (int i = 0; i < 4; ++i) {
    const int yp = ypb + 2 * i;
    const float v0 = fmaxf(fmaxf(fmaxf(acc[i][0][0], acc[i][0][1]),
                                 fmaxf(acc[i][1][0], acc[i][1][1])) + bb, 0.f);
    const float v1 = fmaxf(fmaxf(fmaxf(acc[i][0][2], acc[i][0][3]),
                                 fmaxf(acc[i][1][2], acc[i][1][3])) + bb, 0.f);
    unsigned pack = (unsigned)f2bf(v0) | ((unsigned)f2bf(v1) << 16);
    *(unsigned*)&fb[ocg * 64 + yp * 8 + 2 * g] = pack;
  }
}

// =================== lin1: bf16 MFMA GEMM (unchanged) ===================
__global__ __launch_bounds__(256) void lin1_mfma(const u16* __restrict__ feat,
                                                 const u16* __restrict__ wT,
                                                 float* __restrict__ h1p) {
  constexpr int AS = 72;
  __shared__ __align__(16) u16 As[64 * AS];
  __shared__ __align__(16) u16 Bs[64 * AS];
  const int r0 = blockIdx.x * 64, c0 = blockIdx.y * 64, kb = blockIdx.z * 384;
  const int t = threadIdx.x;
  const int w = t >> 6, lane = t & 63;
  const int row16 = lane & 15, kg = lane >> 4;
  f32x4 acc[4] = {{0.f, 0.f, 0.f, 0.f}, {0.f, 0.f, 0.f, 0.f},
                  {0.f, 0.f, 0.f, 0.f}, {0.f, 0.f, 0.f, 0.f}};
  const int lr = t >> 2, lk = (t & 3) * 16;
#pragma unroll 1
  for (int st = 0; st < 6; ++st) {
    __syncthreads();
    const int ks = kb + st * 64;
    {
      const u16* srcA = feat + (size_t)(r0 + lr) * 6144 + ks + lk;
      uint4 a0 = *(const uint4*)srcA;
      uint4 a1 = *(const uint4*)(srcA + 8);
      *(uint4*)&As[lr * AS + lk] = a0;
      *(uint4*)&As[lr * AS + lk + 8] = a1;
      const u16* srcB = wT + (size_t)(c0 + lr) * 6144 + ks + lk;
      uint4 b0 = *(const uint4*)srcB;
      uint4 b1 = *(const uint4*)(srcB + 8);
      *(uint4*)&Bs[lr * AS + lk] = b0;
      *(uint4*)&Bs[lr * AS + lk + 8] = b1;
    }
    __syncthreads();
#pragma unroll
    for (int kk = 0; kk < 2; ++kk) {
      bf8v a = *(const bf8v*)&As[(w * 16 + row16) * AS + kk * 32 + kg * 8];
#pragma unroll
      for (int ct = 0; ct < 4; ++ct) {
        bf8v bb = *(const bf8v*)&Bs[(ct * 16 + row16) * AS + kk * 32 + kg * 8];
        acc[ct] = __builtin_amdgcn_mfma_f32_16x16x32_bf16(a, bb, acc[ct], 0, 0, 0);
      }
    }
  }
  float* out = h1p + (size_t)blockIdx.z * 131072;
#pragma unroll
  for (int ct = 0; ct < 4; ++ct)
#pragma unroll
    for (int j = 0; j < 4; ++j)
      out[(size_t)(r0 + w * 16 + kg * 4 + j) * 256 + c0 + ct * 16 + row16] = acc[ct][j];
}

// =================== head (unchanged) ===================
__global__ __launch_bounds__(256) void head_kernel(
    const float* __restrict__ h1p, const float* __restrict__ b1,
    const float* __restrict__ w2, const float* __restrict__ b2,
    const float* __restrict__ sw, const float* __restrict__ sb,
    float* __restrict__ out) {
  constexpr int HS = 260;
  __shared__ __align__(16) float h1s[16 * HS];
  __shared__ __align__(16) float w2s[256 * 16];
  const int r0 = blockIdx.x * 16, t = threadIdx.x;
  for (int i = t; i < 4096; i += 256) {
    int r = i >> 8, k = i & 255;
    float s = b1[k];
#pragma unroll
    for (int p = 0; p < 16; ++p) s += h1p[(size_t)p * 131072 + (size_t)(r0 + r) * 256 + k];
    h1s[r * HS + k] = s;
    w2s[i] = w2[i];
  }
  __syncthreads();
  const int j = t & 15, r = t >> 4;
  float acc = b2[j];
#pragma unroll 4
  for (int k4 = 0; k4 < 64; ++k4) {
    float4 hv = *(const float4*)&h1s[r * HS + 4 * k4];
    float h0 = fmaxf(hv.x, 0.f), h1v = fmaxf(hv.y, 0.f);
    float h2v = fmaxf(hv.z, 0.f), h3 = fmaxf(hv.w, 0.f);
    acc += h0 * w2s[(4 * k4 + 0) * 16 + j];
    acc += h1v * w2s[(4 * k4 + 1) * 16 + j];
    acc += h2v * w2s[(4 * k4 + 2) * 16 + j];
    acc += h3 * w2s[(4 * k4 + 3) * 16 + j];
  }
  float v = fmaxf(acc, 0.f) * sw[j];
#pragma unroll
  for (int off = 8; off; off >>= 1) v += __shfl_xor(v, off, 16);
  if (j == 0) out[r0 + r] = v + sb[0];
}

// =================== launcher ===================
extern "C" void kernel_launch(void* const* d_in, const int* in_sizes, int n_in,
                              void* d_out, int out_size, void* d_ws, size_t ws_size,
                              hipStream_t stream) {
  const float* x_q = (const float*)d_in[0];
  const float* x_c = (const float*)d_in[1];
  const int* edge_q = (const int*)d_in[2];
  const int* edge_c = (const int*)d_in[3];
  const float* gw1 = (const float*)d_in[4];
  const float* gb1 = (const float*)d_in[5];
  const float* gw2 = (const float*)d_in[6];
  const float* gb2 = (const float*)d_in[7];
  const float* gw3 = (const float*)d_in[8];
  const float* gb3 = (const float*)d_in[9];
  const float* cw1 = (const float*)d_in[10];
  const float* cb1 = (const float*)d_in[11];
  const float* cw2 = (const float*)d_in[12];
  const float* cb2 = (const float*)d_in[13];
  const float* cw3 = (const float*)d_in[14];
  const float* cb3 = (const float*)d_in[15];
  const float* lw1 = (const float*)d_in[16];
  const float* lb1 = (const float*)d_in[17];
  const float* lw2 = (const float*)d_in[18];
  const float* lb2 = (const float*)d_in[19];
  const float* swt = (const float*)d_in[20];
  const float* sbs = (const float*)d_in[21];
  float* ws = (float*)d_ws;

  const size_t o_f1q = 65536;
  const size_t o_f2q = o_f1q + 2097152;
  const size_t o_f3q = o_f2q + 1048576;
  const size_t o_f1c = o_f3q + 524288;
  const size_t o_f2c = o_f1c + 2097152;
  const size_t o_f3c = o_f2c + 1048576;
  const size_t o_sims = o_f3c + 524288;
  const size_t o_pm1 = o_sims + 6291456;
  const size_t o_pm2 = o_pm1 + 6291456;
  const size_t o_wT = o_pm2 + 3145728;
  const size_t o_w2p = o_wT + 786432;
  const size_t o_w3p = o_w2p + 8192;
  const size_t o_feat = o_sims;           // bf16 feat
  const size_t o_h1p = o_f1q;             // reuse (f1q dead after simconv1)

  u16* f1q = (u16*)(ws + o_f1q); u16* f2q = (u16*)(ws + o_f2q); u16* f3q = (u16*)(ws + o_f3q);
  u16* f1c = (u16*)(ws + o_f1c); u16* f2c = (u16*)(ws + o_f2c); u16* f3c = (u16*)(ws + o_f3c);
  u16* pm1 = (u16*)(ws + o_pm1);
  u16* pm2 = (u16*)(ws + o_pm2);
  u16* wT = (u16*)(ws + o_wT);
  u16* w2p = (u16*)(ws + o_w2p);
  u16* w3p = (u16*)(ws + o_w3p);
  u16* feat = (u16*)(ws + o_feat);
  float* h1p = ws + o_h1p;

  prep_kernel<<<580, 256, 0, stream>>>(lw1, cw2, cw3, wT, w2p, w3p);

  gcn_fused<<<dim3(B, 2), 512, 0, stream>>>(x_q, x_c, gw1, gb1, gw2, gb2, gw3, gb3,
                                            edge_q, edge_c, f1q, f1c, f2q, f2c, f3q, f3c);

  simconv1<<<dim3(B, 3), 256, 0, stream>>>(f1q, f1c, f2q, f2c, f3q, f3c, cw1, cb1, pm1);

  conv2_mfma<<<dim3(B, 3), 256, 0, stream>>>(pm1, w2p, cb2, pm2);
  conv3_mfma<<<dim3(B, 3), 256, 0, stream>>>(pm2, w3p, cb3, feat);

  lin1_mfma<<<dim3(8, 4, 16), 256, 0, stream>>>(feat, wT, h1p);
  head_kernel<<<32, 256, 0, stream>>>(h1p, lb1, lw2, lb2, swt, sbs, (float*)d_out);
}